// Round 1
// baseline (874.770 us; speedup 1.0000x reference)
//
#include <hip/hip_runtime.h>
#include <math.h>

#define BLK 256

// ---------------------------------------------------------------------------
// Probe whether edge_index arrived as int64 (reference dtype) or int32.
// If int64: values < 50000 so every high dword is 0. Sample 64 spread
// positions in the first half; all-zero => int64 layout.
// Also zero the scalar accumulator here (ws is poisoned each call).
__global__ void detect_i64_kernel(const int* __restrict__ idx, int E,
                                  int* __restrict__ flag, float* __restrict__ acc) {
    int t = threadIdx.x;                 // 64 threads
    long long j = (long long)t * (E / 64);
    int hi = idx[2 * j + 1];
    unsigned long long b = __ballot(hi != 0);
    if (t == 0) { *flag = (b == 0ULL) ? 1 : 0; *acc = 0.f; }
}

// deg[n] = 1.0 (self-loop weight)
__global__ void init_deg_kernel(float* __restrict__ deg, int N) {
    int n = blockIdx.x * BLK + threadIdx.x;
    if (n < N) deg[n] = 1.0f;
}

__global__ void edge_deg_kernel(const int* __restrict__ idx, const float* __restrict__ ew,
                                const int* __restrict__ flag, float* __restrict__ deg, int E) {
    int e = blockIdx.x * BLK + threadIdx.x;
    if (e >= E) return;
    int d = (*flag) ? idx[2 * (E + e)] : idx[E + e];
    atomicAdd(&deg[d], ew[e]);
}

// deg -> rsqrt(deg)  (deg >= 1 always: self-loop)
__global__ void dinv_kernel(float* __restrict__ deg, int N) {
    int n = blockIdx.x * BLK + threadIdx.x;
    if (n < N) deg[n] = rsqrtf(deg[n]);
}

// ---------------------------------------------------------------------------
// GEMM1: Y[N,64] = X[N,128] @ W[128,64]
// block = 16 rows x 16 col-quads; W as float4 in LDS, X tile in LDS (pad 132)
__global__ __launch_bounds__(256) void mm1_kernel(const float* __restrict__ X,
                                                  const float* __restrict__ W,
                                                  float* __restrict__ Y, int N) {
    __shared__ float Xs[16 * 132];
    __shared__ float4 Ws[128 * 16];
    const float4* Wg = (const float4*)W;
    for (int i = threadIdx.x; i < 128 * 16; i += 256) Ws[i] = Wg[i];
    int row0 = blockIdx.x * 16;
    for (int i = threadIdx.x; i < 16 * 128; i += 256) {
        int r = i >> 7, k = i & 127;
        int row = row0 + r;
        Xs[r * 132 + k] = (row < N) ? X[row * 128 + k] : 0.f;
    }
    __syncthreads();
    int r = threadIdx.x >> 4;   // 0..15
    int c4 = threadIdx.x & 15;  // 0..15
    int row = row0 + r;
    float4 acc = {0.f, 0.f, 0.f, 0.f};
#pragma unroll 4
    for (int k = 0; k < 128; ++k) {
        float xv = Xs[r * 132 + k];
        float4 wv = Ws[k * 16 + c4];
        acc.x = fmaf(xv, wv.x, acc.x);
        acc.y = fmaf(xv, wv.y, acc.y);
        acc.z = fmaf(xv, wv.z, acc.z);
        acc.w = fmaf(xv, wv.w, acc.w);
    }
    if (row < N) ((float4*)Y)[row * 16 + c4] = acc;
}

// GEMM2: Y[N,32] = relu(H[N,64]) @ W[64,32]   (relu fused into staging)
__global__ __launch_bounds__(256) void mm2_kernel(const float* __restrict__ H,
                                                  const float* __restrict__ W,
                                                  float* __restrict__ Y, int N) {
    __shared__ float Xs[32 * 68];
    __shared__ float4 Ws[64 * 8];
    const float4* Wg = (const float4*)W;
    for (int i = threadIdx.x; i < 64 * 8; i += 256) Ws[i] = Wg[i];
    int row0 = blockIdx.x * 32;
    for (int i = threadIdx.x; i < 32 * 64; i += 256) {
        int r = i >> 6, k = i & 63;
        int row = row0 + r;
        Xs[r * 68 + k] = (row < N) ? fmaxf(H[row * 64 + k], 0.f) : 0.f;
    }
    __syncthreads();
    int r = threadIdx.x >> 3;  // 0..31
    int c4 = threadIdx.x & 7;  // 0..7
    int row = row0 + r;
    float4 acc = {0.f, 0.f, 0.f, 0.f};
#pragma unroll 4
    for (int k = 0; k < 64; ++k) {
        float xv = Xs[r * 68 + k];
        float4 wv = Ws[k * 8 + c4];
        acc.x = fmaf(xv, wv.x, acc.x);
        acc.y = fmaf(xv, wv.y, acc.y);
        acc.z = fmaf(xv, wv.z, acc.z);
        acc.w = fmaf(xv, wv.w, acc.w);
    }
    if (row < N) ((float4*)Y)[row * 8 + c4] = acc;
}

// Discriminator GEMM, fully fused:
// x[n,c] = tanh(Z[n, c&31]) + F[n,c];  Y[n,0..1] = x[n,:] @ Wd[128,2]
__global__ __launch_bounds__(256) void disc_mm_kernel(const float* __restrict__ Z,
                                                      const float* __restrict__ F,
                                                      const float* __restrict__ Wd,
                                                      float* __restrict__ Y, int N) {
    __shared__ float Ws[256];
    if (threadIdx.x < 256) Ws[threadIdx.x] = Wd[threadIdx.x];
    __syncthreads();
    int n = blockIdx.x * 256 + threadIdx.x;
    if (n >= N) return;
    float zt[32];
#pragma unroll
    for (int j = 0; j < 32; ++j) zt[j] = tanhf(Z[n * 32 + j]);
    float a0 = 0.f, a1 = 0.f;
    const float* fr = F + (size_t)n * 128;
#pragma unroll 4
    for (int c = 0; c < 128; ++c) {
        float xv = zt[c & 31] + fr[c];
        a0 = fmaf(xv, Ws[c * 2 + 0], a0);
        a1 = fmaf(xv, Ws[c * 2 + 1], a1);
    }
    Y[n * 2 + 0] = a0;
    Y[n * 2 + 1] = a1;
}

// ---------------------------------------------------------------------------
// Aggregation: agg[n,:] = bias + dinv[n]^2 * h[n,:]  (self-loop term)
template <int WD>
__global__ void init_agg_kernel(const float* __restrict__ h, const float* __restrict__ dinv,
                                const float* __restrict__ bias, float* __restrict__ agg, int N) {
    int i = blockIdx.x * BLK + threadIdx.x;
    if (i >= N * WD) return;
    int n = i / WD, o = i % WD;
    float di = dinv[n];
    agg[i] = bias[o] + di * di * h[i];
}

// agg[dst,:] += dinv[src]*w*dinv[dst] * h[src,:]
template <int WD>
__global__ void edge_agg_kernel(const int* __restrict__ idx, const float* __restrict__ ew,
                                const int* __restrict__ flag, const float* __restrict__ dinv,
                                const float* __restrict__ h, float* __restrict__ agg, int E) {
    int gid = blockIdx.x * BLK + threadIdx.x;  // up to E*64 = 102.4M < 2^31
    if (gid >= E * WD) return;
    int e = gid / WD;
    int o = gid % WD;
    int s, d;
    if (*flag) { s = idx[2 * e]; d = idx[2 * (E + e)]; }
    else       { s = idx[e];     d = idx[E + e]; }
    float nrm = dinv[s] * ew[e] * dinv[d];
    atomicAdd(&agg[d * WD + o], nrm * h[s * WD + o]);
}

// ---------------------------------------------------------------------------
// logit partial sums: sum( relu(d_flat) * w_fc )
__global__ void reduce_kernel(const float* __restrict__ dmat, const float* __restrict__ wfc,
                              float* __restrict__ acc, int M) {
    int i = blockIdx.x * BLK + threadIdx.x;
    float v = 0.f;
    if (i < M) v = fmaxf(dmat[i], 0.f) * wfc[i];
#pragma unroll
    for (int off = 32; off > 0; off >>= 1) v += __shfl_down(v, off, 64);
    if ((threadIdx.x & 63) == 0) atomicAdd(acc, v);
}

__global__ void final_kernel(const float* __restrict__ acc, const float* __restrict__ bfc,
                             float* __restrict__ out) {
    float x = *acc + *bfc;
    out[0] = 1.f / (1.f + expf(-x));
}

// ---------------------------------------------------------------------------
extern "C" void kernel_launch(void* const* d_in, const int* in_sizes, int n_in,
                              void* d_out, int out_size, void* d_ws, size_t ws_size,
                              hipStream_t stream) {
    const float* feat = (const float*)d_in[0];
    const int*   eidx = (const int*)d_in[1];
    const float* ew   = (const float*)d_in[2];
    const float* W1   = (const float*)d_in[3];
    const float* b1   = (const float*)d_in[4];
    const float* W2   = (const float*)d_in[5];
    const float* b2   = (const float*)d_in[6];
    const float* Wd   = (const float*)d_in[7];
    const float* bd   = (const float*)d_in[8];
    const float* wfc  = (const float*)d_in[9];
    const float* bfc  = (const float*)d_in[10];

    const int N = in_sizes[0] / 128;  // 50000
    const int E = in_sizes[2];        // 1600000

    float* ws  = (float*)d_ws;
    float* deg = ws;                        // N floats (becomes dinv)
    float* h   = ws + N;                    // N*64 floats (h1 / h2 / dpre)
    float* agg = h + (size_t)N * 64;        // N*64 floats (agg1 / z / d)
    float* acc = agg + (size_t)N * 64;      // 1 float
    int*   flag = (int*)(acc + 1);          // 1 int

    float* out = (float*)d_out;

    const int gN   = (N + BLK - 1) / BLK;
    const int gE   = (E + BLK - 1) / BLK;

    // normalization (shared by all 3 GCN layers)
    hipLaunchKernelGGL(detect_i64_kernel, dim3(1), dim3(64), 0, stream, eidx, E, flag, acc);
    hipLaunchKernelGGL(init_deg_kernel, dim3(gN), dim3(BLK), 0, stream, deg, N);
    hipLaunchKernelGGL(edge_deg_kernel, dim3(gE), dim3(BLK), 0, stream, eidx, ew, flag, deg, E);
    hipLaunchKernelGGL(dinv_kernel, dim3(gN), dim3(BLK), 0, stream, deg, N);

    // layer 1: h = feat @ W1 ; agg1 = A_norm h + b1
    hipLaunchKernelGGL(mm1_kernel, dim3((N + 15) / 16), dim3(256), 0, stream, feat, W1, h, N);
    hipLaunchKernelGGL((init_agg_kernel<64>), dim3((N * 64 + BLK - 1) / BLK), dim3(BLK), 0, stream,
                       h, deg, b1, agg, N);
    hipLaunchKernelGGL((edge_agg_kernel<64>), dim3((E / BLK) * 64 + 64), dim3(BLK), 0, stream,
                       eidx, ew, flag, deg, h, agg, E);

    // layer 2: h2 = relu(agg1) @ W2 ; agg2 = A_norm h2 + b2  (z = tanh fused later)
    hipLaunchKernelGGL(mm2_kernel, dim3((N + 31) / 32), dim3(256), 0, stream, agg, W2, h, N);
    hipLaunchKernelGGL((init_agg_kernel<32>), dim3((N * 32 + BLK - 1) / BLK), dim3(BLK), 0, stream,
                       h, deg, b2, agg, N);
    hipLaunchKernelGGL((edge_agg_kernel<32>), dim3((E / BLK) * 32 + 32), dim3(BLK), 0, stream,
                       eidx, ew, flag, deg, h, agg, E);

    // discriminator: x = tile(tanh(agg2),4)+feat ; dpre = x @ Wd ; d = A_norm dpre + bd
    hipLaunchKernelGGL(disc_mm_kernel, dim3((N + 255) / 256), dim3(256), 0, stream,
                       agg, feat, Wd, h, N);
    hipLaunchKernelGGL((init_agg_kernel<2>), dim3((N * 2 + BLK - 1) / BLK), dim3(BLK), 0, stream,
                       h, deg, bd, agg, N);
    hipLaunchKernelGGL((edge_agg_kernel<2>), dim3((E * 2 + BLK - 1) / BLK), dim3(BLK), 0, stream,
                       eidx, ew, flag, deg, h, agg, E);

    // logit = sum(relu(d)*w_fc) + b_fc ; out = sigmoid(logit)
    hipLaunchKernelGGL(reduce_kernel, dim3((N * 2 + BLK - 1) / BLK), dim3(BLK), 0, stream,
                       agg, wfc, acc, N * 2);
    hipLaunchKernelGGL(final_kernel, dim3(1), dim3(1), 0, stream, acc, bfc, out);
}

// Round 2
// 575.894 us; speedup vs baseline: 1.5190x; 1.5190x over previous
//
#include <hip/hip_runtime.h>
#include <math.h>

#define BLK 256

// ---------------------------------------------------------------------------
// Zero counts/fill (2N ints), zero acc, and probe int64-vs-int32 edge_index.
__global__ void zero_detect_kernel(const int* __restrict__ idx, int E,
                                   int* __restrict__ flag, float* __restrict__ acc,
                                   int* __restrict__ zbase, int M) {
    int i = blockIdx.x * BLK + threadIdx.x;
    if (i < M) zbase[i] = 0;
    if (blockIdx.x == 0 && threadIdx.x < 64) {
        int t = threadIdx.x;
        long long j = (long long)t * (E / 64);
        int hi = idx[2 * j + 1];
        unsigned long long b = __ballot(hi != 0);
        if (t == 0) { *flag = (b == 0ULL) ? 1 : 0; *acc = 0.f; }
    }
}

// counts[dst]++
__global__ void hist_kernel(const int* __restrict__ idx, const int* __restrict__ flag,
                            int* __restrict__ count, int E) {
    int e = blockIdx.x * BLK + threadIdx.x;
    if (e >= E) return;
    int d = (*flag) ? idx[2 * (E + e)] : idx[E + e];
    atomicAdd(&count[d], 1);
}

// block sums of counts
__global__ void scan_block_kernel(const int* __restrict__ count, int* __restrict__ bsum, int N) {
    __shared__ int s[256];
    int i = blockIdx.x * 256 + threadIdx.x;
    int v = (i < N) ? count[i] : 0;
    s[threadIdx.x] = v;
    __syncthreads();
    for (int off = 128; off > 0; off >>= 1) {
        if (threadIdx.x < off) s[threadIdx.x] += s[threadIdx.x + off];
        __syncthreads();
    }
    if (threadIdx.x == 0) bsum[blockIdx.x] = s[0];
}

// exclusive scan of bsum (nb <= 256) in place
__global__ void scan_top_kernel(int* __restrict__ bsum, int nb) {
    __shared__ int s[256];
    int t = threadIdx.x;
    int v = (t < nb) ? bsum[t] : 0;
    s[t] = v;
    __syncthreads();
    for (int off = 1; off < 256; off <<= 1) {
        int t2 = (t >= off) ? s[t - off] : 0;
        __syncthreads();
        s[t] += t2;
        __syncthreads();
    }
    if (t < nb) bsum[t] = s[t] - v;  // exclusive
}

// row[i] = block-exclusive-prefix + bsum[block]; row[N] = E
__global__ void scan_fin_kernel(const int* __restrict__ count, const int* __restrict__ bsum,
                                int* __restrict__ row, int N) {
    __shared__ int s[256];
    int t = threadIdx.x;
    int i = blockIdx.x * 256 + t;
    int v = (i < N) ? count[i] : 0;
    s[t] = v;
    __syncthreads();
    for (int off = 1; off < 256; off <<= 1) {
        int t2 = (t >= off) ? s[t - off] : 0;
        __syncthreads();
        s[t] += t2;
        __syncthreads();
    }
    int excl = s[t] - v + bsum[blockIdx.x];
    if (i < N) row[i] = excl;
    if (i == N - 1) row[N] = excl + v;
}

// fill CSR: csrc[p]=src, cw[p]=edge weight
__global__ void scatter_kernel(const int* __restrict__ idx, const float* __restrict__ ew,
                               const int* __restrict__ flag, const int* __restrict__ row,
                               int* __restrict__ fill, int* __restrict__ csrc,
                               float* __restrict__ cw, int E) {
    int e = blockIdx.x * BLK + threadIdx.x;
    if (e >= E) return;
    int s, d;
    if (*flag) { s = idx[2 * e]; d = idx[2 * (E + e)]; }
    else       { s = idx[e];     d = idx[E + e]; }
    int p = row[d] + atomicAdd(&fill[d], 1);
    csrc[p] = s;
    cw[p] = ew[e];
}

// dinv[n] = rsqrt(1 + sum of incoming weights)  — one wave per node
__global__ __launch_bounds__(256) void dinv_csr_kernel(const int* __restrict__ row,
                                                       const float* __restrict__ cw,
                                                       float* __restrict__ dinv, int N) {
    int wid = (blockIdx.x * 256 + threadIdx.x) >> 6;
    int lane = threadIdx.x & 63;
    if (wid >= N) return;
    int p0 = row[wid], p1 = row[wid + 1];
    float s = 0.f;
    for (int p = p0 + lane; p < p1; p += 64) s += cw[p];
    for (int off = 32; off > 0; off >>= 1) s += __shfl_down(s, off, 64);
    if (lane == 0) dinv[wid] = rsqrtf(1.0f + s);
}

// cw[p] <- dinv[src]*w*dinv[dst]   (needs all dinv done)
__global__ __launch_bounds__(256) void norm_csr_kernel(const int* __restrict__ row,
                                                       const int* __restrict__ csrc,
                                                       float* __restrict__ cw,
                                                       const float* __restrict__ dinv, int N) {
    int wid = (blockIdx.x * 256 + threadIdx.x) >> 6;
    int lane = threadIdx.x & 63;
    if (wid >= N) return;
    int p0 = row[wid], p1 = row[wid + 1];
    float dd = dinv[wid];
    for (int p = p0 + lane; p < p1; p += 64)
        cw[p] = dinv[csrc[p]] * cw[p] * dd;
}

// ---------------------------------------------------------------------------
// gather aggregation: out[n,o] = bias[o] + dinv[n]^2*h[n,o] + sum norm*h[src,o]
// one wave per node, lane o = feature (WD=64)
__global__ __launch_bounds__(256) void gather64_kernel(const int* __restrict__ row,
                                                       const int* __restrict__ csrc,
                                                       const float* __restrict__ cw,
                                                       const float* __restrict__ h,
                                                       const float* __restrict__ dinv,
                                                       const float* __restrict__ bias,
                                                       float* __restrict__ out, int N) {
    int wid = (blockIdx.x * 256 + threadIdx.x) >> 6;
    int o = threadIdx.x & 63;
    if (wid >= N) return;
    float di = dinv[wid];
    float acc = bias[o] + di * di * h[wid * 64 + o];
    int p0 = row[wid], p1 = row[wid + 1];
    for (int p = p0; p < p1; p += 64) {
        int q = p + o;
        int sj = (q < p1) ? csrc[q] : 0;
        float nj = (q < p1) ? cw[q] : 0.f;
        int m = min(64, p1 - p);
        for (int j = 0; j < m; ++j) {
            int s = __shfl(sj, j, 64);
            float nr = __shfl(nj, j, 64);
            acc = fmaf(nr, h[s * 64 + o], acc);
        }
    }
    out[wid * 64 + o] = acc;
}

// WD=32: lanes 0..31 = features of edge-half 0, lanes 32..63 = edge-half 1
__global__ __launch_bounds__(256) void gather32_kernel(const int* __restrict__ row,
                                                       const int* __restrict__ csrc,
                                                       const float* __restrict__ cw,
                                                       const float* __restrict__ h,
                                                       const float* __restrict__ dinv,
                                                       const float* __restrict__ bias,
                                                       float* __restrict__ out, int N) {
    int wid = (blockIdx.x * 256 + threadIdx.x) >> 6;
    int lane = threadIdx.x & 63;
    int o = lane & 31;
    int g = lane >> 5;
    if (wid >= N) return;
    float di = dinv[wid];
    float acc = (g == 0) ? bias[o] + di * di * h[wid * 32 + o] : 0.f;
    int p0 = row[wid], p1 = row[wid + 1];
    for (int p = p0; p < p1; p += 64) {
        int q = p + lane;
        int sj = (q < p1) ? csrc[q] : 0;
        float nj = (q < p1) ? cw[q] : 0.f;
        int m = min(64, p1 - p);
        for (int j = g; j < m; j += 2) {
            int s = __shfl(sj, j, 64);
            float nr = __shfl(nj, j, 64);
            acc = fmaf(nr, h[s * 32 + o], acc);
        }
    }
    acc += __shfl_down(acc, 32, 64);
    if (g == 0) out[wid * 32 + o] = acc;
}

// WD=2: 32 edges per iteration; o = lane&1, edge slot = lane>>1
__global__ __launch_bounds__(256) void gather2_kernel(const int* __restrict__ row,
                                                      const int* __restrict__ csrc,
                                                      const float* __restrict__ cw,
                                                      const float* __restrict__ h,
                                                      const float* __restrict__ dinv,
                                                      const float* __restrict__ bias,
                                                      float* __restrict__ out, int N) {
    int wid = (blockIdx.x * 256 + threadIdx.x) >> 6;
    int lane = threadIdx.x & 63;
    int o = lane & 1;
    if (wid >= N) return;
    float di = dinv[wid];
    float acc = (lane < 2) ? bias[o] + di * di * h[wid * 2 + o] : 0.f;
    int p0 = row[wid], p1 = row[wid + 1];
    for (int p = p0; p < p1; p += 64) {
        int q = p + lane;
        int sj = (q < p1) ? csrc[q] : 0;
        float nj = (q < p1) ? cw[q] : 0.f;
        int m = min(64, p1 - p);
        for (int base = 0; base < m; base += 32) {
            int j = base + (lane >> 1);
            int s = __shfl(sj, j, 64);
            float nr = __shfl(nj, j, 64);  // 0 beyond edge count
            acc = fmaf(nr, h[s * 2 + o], acc);
        }
    }
    for (int off = 2; off < 64; off <<= 1) acc += __shfl_xor(acc, off, 64);
    if (lane < 2) out[wid * 2 + o] = acc;
}

// ---------------------------------------------------------------------------
// Dense kernels (unchanged from R1)
__global__ __launch_bounds__(256) void mm1_kernel(const float* __restrict__ X,
                                                  const float* __restrict__ W,
                                                  float* __restrict__ Y, int N) {
    __shared__ float Xs[16 * 132];
    __shared__ float4 Ws[128 * 16];
    const float4* Wg = (const float4*)W;
    for (int i = threadIdx.x; i < 128 * 16; i += 256) Ws[i] = Wg[i];
    int row0 = blockIdx.x * 16;
    for (int i = threadIdx.x; i < 16 * 128; i += 256) {
        int r = i >> 7, k = i & 127;
        int row = row0 + r;
        Xs[r * 132 + k] = (row < N) ? X[row * 128 + k] : 0.f;
    }
    __syncthreads();
    int r = threadIdx.x >> 4;
    int c4 = threadIdx.x & 15;
    int row = row0 + r;
    float4 acc = {0.f, 0.f, 0.f, 0.f};
#pragma unroll 4
    for (int k = 0; k < 128; ++k) {
        float xv = Xs[r * 132 + k];
        float4 wv = Ws[k * 16 + c4];
        acc.x = fmaf(xv, wv.x, acc.x);
        acc.y = fmaf(xv, wv.y, acc.y);
        acc.z = fmaf(xv, wv.z, acc.z);
        acc.w = fmaf(xv, wv.w, acc.w);
    }
    if (row < N) ((float4*)Y)[row * 16 + c4] = acc;
}

__global__ __launch_bounds__(256) void mm2_kernel(const float* __restrict__ H,
                                                  const float* __restrict__ W,
                                                  float* __restrict__ Y, int N) {
    __shared__ float Xs[32 * 68];
    __shared__ float4 Ws[64 * 8];
    const float4* Wg = (const float4*)W;
    for (int i = threadIdx.x; i < 64 * 8; i += 256) Ws[i] = Wg[i];
    int row0 = blockIdx.x * 32;
    for (int i = threadIdx.x; i < 32 * 64; i += 256) {
        int r = i >> 6, k = i & 63;
        int row = row0 + r;
        Xs[r * 68 + k] = (row < N) ? fmaxf(H[row * 64 + k], 0.f) : 0.f;
    }
    __syncthreads();
    int r = threadIdx.x >> 3;
    int c4 = threadIdx.x & 7;
    int row = row0 + r;
    float4 acc = {0.f, 0.f, 0.f, 0.f};
#pragma unroll 4
    for (int k = 0; k < 64; ++k) {
        float xv = Xs[r * 68 + k];
        float4 wv = Ws[k * 8 + c4];
        acc.x = fmaf(xv, wv.x, acc.x);
        acc.y = fmaf(xv, wv.y, acc.y);
        acc.z = fmaf(xv, wv.z, acc.z);
        acc.w = fmaf(xv, wv.w, acc.w);
    }
    if (row < N) ((float4*)Y)[row * 8 + c4] = acc;
}

__global__ __launch_bounds__(256) void disc_mm_kernel(const float* __restrict__ Z,
                                                      const float* __restrict__ F,
                                                      const float* __restrict__ Wd,
                                                      float* __restrict__ Y, int N) {
    __shared__ float Ws[256];
    if (threadIdx.x < 256) Ws[threadIdx.x] = Wd[threadIdx.x];
    __syncthreads();
    int n = blockIdx.x * 256 + threadIdx.x;
    if (n >= N) return;
    float zt[32];
#pragma unroll
    for (int j = 0; j < 32; ++j) zt[j] = tanhf(Z[n * 32 + j]);
    float a0 = 0.f, a1 = 0.f;
    const float* fr = F + (size_t)n * 128;
#pragma unroll 4
    for (int c = 0; c < 128; ++c) {
        float xv = zt[c & 31] + fr[c];
        a0 = fmaf(xv, Ws[c * 2 + 0], a0);
        a1 = fmaf(xv, Ws[c * 2 + 1], a1);
    }
    Y[n * 2 + 0] = a0;
    Y[n * 2 + 1] = a1;
}

// ---------------------------------------------------------------------------
// Fallback (R1 atomic path) kernels
__global__ void detect_i64_kernel(const int* __restrict__ idx, int E,
                                  int* __restrict__ flag, float* __restrict__ acc) {
    int t = threadIdx.x;
    long long j = (long long)t * (E / 64);
    int hi = idx[2 * j + 1];
    unsigned long long b = __ballot(hi != 0);
    if (t == 0) { *flag = (b == 0ULL) ? 1 : 0; *acc = 0.f; }
}

__global__ void init_deg_kernel(float* __restrict__ deg, int N) {
    int n = blockIdx.x * BLK + threadIdx.x;
    if (n < N) deg[n] = 1.0f;
}

__global__ void edge_deg_kernel(const int* __restrict__ idx, const float* __restrict__ ew,
                                const int* __restrict__ flag, float* __restrict__ deg, int E) {
    int e = blockIdx.x * BLK + threadIdx.x;
    if (e >= E) return;
    int d = (*flag) ? idx[2 * (E + e)] : idx[E + e];
    atomicAdd(&deg[d], ew[e]);
}

__global__ void dinv_kernel(float* __restrict__ deg, int N) {
    int n = blockIdx.x * BLK + threadIdx.x;
    if (n < N) deg[n] = rsqrtf(deg[n]);
}

template <int WD>
__global__ void init_agg_kernel(const float* __restrict__ h, const float* __restrict__ dinv,
                                const float* __restrict__ bias, float* __restrict__ agg, int N) {
    int i = blockIdx.x * BLK + threadIdx.x;
    if (i >= N * WD) return;
    int n = i / WD, o = i % WD;
    float di = dinv[n];
    agg[i] = bias[o] + di * di * h[i];
}

template <int WD>
__global__ void edge_agg_kernel(const int* __restrict__ idx, const float* __restrict__ ew,
                                const int* __restrict__ flag, const float* __restrict__ dinv,
                                const float* __restrict__ h, float* __restrict__ agg, int E) {
    int gid = blockIdx.x * BLK + threadIdx.x;
    if (gid >= E * WD) return;
    int e = gid / WD;
    int o = gid % WD;
    int s, d;
    if (*flag) { s = idx[2 * e]; d = idx[2 * (E + e)]; }
    else       { s = idx[e];     d = idx[E + e]; }
    float nrm = dinv[s] * ew[e] * dinv[d];
    atomicAdd(&agg[d * WD + o], nrm * h[s * WD + o]);
}

// ---------------------------------------------------------------------------
__global__ void reduce_kernel(const float* __restrict__ dmat, const float* __restrict__ wfc,
                              float* __restrict__ acc, int M) {
    int i = blockIdx.x * BLK + threadIdx.x;
    float v = 0.f;
    if (i < M) v = fmaxf(dmat[i], 0.f) * wfc[i];
#pragma unroll
    for (int off = 32; off > 0; off >>= 1) v += __shfl_down(v, off, 64);
    if ((threadIdx.x & 63) == 0) atomicAdd(acc, v);
}

__global__ void final_kernel(const float* __restrict__ acc, const float* __restrict__ bfc,
                             float* __restrict__ out) {
    float x = *acc + *bfc;
    out[0] = 1.f / (1.f + expf(-x));
}

// ---------------------------------------------------------------------------
extern "C" void kernel_launch(void* const* d_in, const int* in_sizes, int n_in,
                              void* d_out, int out_size, void* d_ws, size_t ws_size,
                              hipStream_t stream) {
    const float* feat = (const float*)d_in[0];
    const int*   eidx = (const int*)d_in[1];
    const float* ew   = (const float*)d_in[2];
    const float* W1   = (const float*)d_in[3];
    const float* b1   = (const float*)d_in[4];
    const float* W2   = (const float*)d_in[5];
    const float* b2   = (const float*)d_in[6];
    const float* Wd   = (const float*)d_in[7];
    const float* bd   = (const float*)d_in[8];
    const float* wfc  = (const float*)d_in[9];
    const float* bfc  = (const float*)d_in[10];

    const int N = in_sizes[0] / 128;  // 50000
    const int E = in_sizes[2];        // 1600000

    float* ws   = (float*)d_ws;
    float* dinv = ws;                        // N
    float* h    = ws + N;                    // N*64
    float* agg  = h + (size_t)N * 64;        // N*64
    float* acc  = agg + (size_t)N * 64;      // 1
    int*   flag = (int*)(acc + 1);           // 1
    int*   cnts = flag + 1;                  // N
    int*   fill = cnts + N;                  // N
    int*   row  = fill + N;                  // N+1
    int*   bsum = row + N + 1;               // 256
    int*   csrc = bsum + 256;                // E
    float* cw   = (float*)(csrc + E);        // E
    size_t need = (size_t)((char*)(cw + E) - (char*)d_ws);

    float* out = (float*)d_out;

    const int gN  = (N + BLK - 1) / BLK;
    const int gE  = (E + BLK - 1) / BLK;
    const int nb  = (N + 255) / 256;          // scan blocks (<=256)
    const int gW  = (N * 64 + 255) / 256;     // wave-per-node grids (4 nodes/block)

    if (ws_size >= need) {
        // ---- CSR gather path ----
        hipLaunchKernelGGL(zero_detect_kernel, dim3((2 * N + BLK - 1) / BLK), dim3(BLK), 0, stream,
                           eidx, E, flag, acc, cnts, 2 * N);
        hipLaunchKernelGGL(hist_kernel, dim3(gE), dim3(BLK), 0, stream, eidx, flag, cnts, E);
        hipLaunchKernelGGL(scan_block_kernel, dim3(nb), dim3(256), 0, stream, cnts, bsum, N);
        hipLaunchKernelGGL(scan_top_kernel, dim3(1), dim3(256), 0, stream, bsum, nb);
        hipLaunchKernelGGL(scan_fin_kernel, dim3(nb), dim3(256), 0, stream, cnts, bsum, row, N);
        hipLaunchKernelGGL(scatter_kernel, dim3(gE), dim3(BLK), 0, stream,
                           eidx, ew, flag, row, fill, csrc, cw, E);
        hipLaunchKernelGGL(dinv_csr_kernel, dim3(gW), dim3(256), 0, stream, row, cw, dinv, N);
        hipLaunchKernelGGL(norm_csr_kernel, dim3(gW), dim3(256), 0, stream, row, csrc, cw, dinv, N);

        hipLaunchKernelGGL(mm1_kernel, dim3((N + 15) / 16), dim3(256), 0, stream, feat, W1, h, N);
        hipLaunchKernelGGL(gather64_kernel, dim3(gW), dim3(256), 0, stream,
                           row, csrc, cw, h, dinv, b1, agg, N);
        hipLaunchKernelGGL(mm2_kernel, dim3((N + 31) / 32), dim3(256), 0, stream, agg, W2, h, N);
        hipLaunchKernelGGL(gather32_kernel, dim3(gW), dim3(256), 0, stream,
                           row, csrc, cw, h, dinv, b2, agg, N);
        hipLaunchKernelGGL(disc_mm_kernel, dim3((N + 255) / 256), dim3(256), 0, stream,
                           agg, feat, Wd, h, N);
        hipLaunchKernelGGL(gather2_kernel, dim3(gW), dim3(256), 0, stream,
                           row, csrc, cw, h, dinv, bd, agg, N);
    } else {
        // ---- fallback: R1 atomic scatter path ----
        hipLaunchKernelGGL(detect_i64_kernel, dim3(1), dim3(64), 0, stream, eidx, E, flag, acc);
        hipLaunchKernelGGL(init_deg_kernel, dim3(gN), dim3(BLK), 0, stream, dinv, N);
        hipLaunchKernelGGL(edge_deg_kernel, dim3(gE), dim3(BLK), 0, stream, eidx, ew, flag, dinv, E);
        hipLaunchKernelGGL(dinv_kernel, dim3(gN), dim3(BLK), 0, stream, dinv, N);

        hipLaunchKernelGGL(mm1_kernel, dim3((N + 15) / 16), dim3(256), 0, stream, feat, W1, h, N);
        hipLaunchKernelGGL((init_agg_kernel<64>), dim3((N * 64 + BLK - 1) / BLK), dim3(BLK), 0, stream,
                           h, dinv, b1, agg, N);
        hipLaunchKernelGGL((edge_agg_kernel<64>), dim3((E / BLK) * 64 + 64), dim3(BLK), 0, stream,
                           eidx, ew, flag, dinv, h, agg, E);
        hipLaunchKernelGGL(mm2_kernel, dim3((N + 31) / 32), dim3(256), 0, stream, agg, W2, h, N);
        hipLaunchKernelGGL((init_agg_kernel<32>), dim3((N * 32 + BLK - 1) / BLK), dim3(BLK), 0, stream,
                           h, dinv, b2, agg, N);
        hipLaunchKernelGGL((edge_agg_kernel<32>), dim3((E / BLK) * 32 + 32), dim3(BLK), 0, stream,
                           eidx, ew, flag, dinv, h, agg, E);
        hipLaunchKernelGGL(disc_mm_kernel, dim3((N + 255) / 256), dim3(256), 0, stream,
                           agg, feat, Wd, h, N);
        hipLaunchKernelGGL((init_agg_kernel<2>), dim3((N * 2 + BLK - 1) / BLK), dim3(BLK), 0, stream,
                           h, dinv, bd, agg, N);
        hipLaunchKernelGGL((edge_agg_kernel<2>), dim3((E * 2 + BLK - 1) / BLK), dim3(BLK), 0, stream,
                           eidx, ew, flag, dinv, h, agg, E);
    }

    hipLaunchKernelGGL(reduce_kernel, dim3((N * 2 + BLK - 1) / BLK), dim3(BLK), 0, stream,
                       agg, wfc, acc, N * 2);
    hipLaunchKernelGGL(final_kernel, dim3(1), dim3(1), 0, stream, acc, bfc, out);
}

// Round 3
// 422.193 us; speedup vs baseline: 2.0720x; 1.3641x over previous
//
#include <hip/hip_runtime.h>
#include <math.h>

#define BLK 256
#define CHUNK 4096
#define BSH 9
#define BNODES 512
#define MAXNB 128

// ---------------------------------------------------------------------------
// Probe int64-vs-int32 edge_index layout; zero the scalar accumulator.
__global__ void detect_kernel(const int* __restrict__ idx, int E,
                              int* __restrict__ flag, float* __restrict__ acc) {
    int t = threadIdx.x;  // 64 threads
    long long j = (long long)t * (E / 64);
    int hi = idx[2 * j + 1];
    unsigned long long b = __ballot(hi != 0);
    if (t == 0) { *flag = (b == 0ULL) ? 1 : 0; *acc = 0.f; }
}

// ---------------------------------------------------------------------------
// K1: per-block bucket histogram (bucket = dst >> BSH), coalesced count rows.
__global__ __launch_bounds__(256) void bucket_hist_kernel(const int* __restrict__ idx,
                                                          const int* __restrict__ flag,
                                                          int* __restrict__ blockCnt,
                                                          int E, int NB) {
    __shared__ int hist[MAXNB];
    int t = threadIdx.x;
    if (t < NB) hist[t] = 0;
    __syncthreads();
    bool i64 = (*flag) != 0;
    int e0 = blockIdx.x * CHUNK;
    int e1 = min(e0 + CHUNK, E);
    for (int e = e0 + t; e < e1; e += 256) {
        int d = i64 ? idx[2 * (E + e)] : idx[E + e];
        atomicAdd(&hist[d >> BSH], 1);
    }
    __syncthreads();
    if (t < NB) blockCnt[blockIdx.x * NB + t] = hist[t];
}

// K2: column-wise exclusive scan over blocks (one block per bucket)
__global__ __launch_bounds__(256) void col_scan_kernel(const int* __restrict__ blockCnt,
                                                       int* __restrict__ blockBase,
                                                       int* __restrict__ bucketTotal,
                                                       int NBLK, int NB) {
    __shared__ int s[256];
    __shared__ int carry;
    int bkt = blockIdx.x;
    int t = threadIdx.x;
    if (t == 0) carry = 0;
    __syncthreads();
    for (int base = 0; base < NBLK; base += 256) {
        int i = base + t;
        int v = (i < NBLK) ? blockCnt[i * NB + bkt] : 0;
        s[t] = v;
        __syncthreads();
        for (int off = 1; off < 256; off <<= 1) {
            int x = (t >= off) ? s[t - off] : 0;
            __syncthreads();
            s[t] += x;
            __syncthreads();
        }
        if (i < NBLK) blockBase[i * NB + bkt] = carry + s[t] - v;
        __syncthreads();
        if (t == 0) carry += s[255];
        __syncthreads();
    }
    if (t == 0) bucketTotal[bkt] = carry;
}

// K2b: exclusive scan of bucket totals (NB <= 128)
__global__ void bucket_scan_kernel(const int* __restrict__ bucketTotal,
                                   int* __restrict__ bucketBase, int NB) {
    __shared__ int s[128];
    int t = threadIdx.x;  // 128 threads
    int v = (t < NB) ? bucketTotal[t] : 0;
    s[t] = v;
    __syncthreads();
    for (int off = 1; off < 128; off <<= 1) {
        int x = (t >= off) ? s[t - off] : 0;
        __syncthreads();
        s[t] += x;
        __syncthreads();
    }
    if (t < NB) bucketBase[t] = s[t] - v;
}

// K3: scatter edges into bucket-partitioned temp as contiguous runs.
// payload: (src | dlocal<<16, bits(w))
__global__ __launch_bounds__(256) void bucket_scatter_kernel(const int* __restrict__ idx,
                                                             const float* __restrict__ ew,
                                                             const int* __restrict__ flag,
                                                             const int* __restrict__ bucketBase,
                                                             const int* __restrict__ blockBase,
                                                             int2* __restrict__ temp,
                                                             int E, int NB) {
    __shared__ int base[MAXNB];
    __shared__ int fill[MAXNB];
    int t = threadIdx.x;
    if (t < NB) {
        base[t] = bucketBase[t] + blockBase[blockIdx.x * NB + t];
        fill[t] = 0;
    }
    __syncthreads();
    bool i64 = (*flag) != 0;
    int e0 = blockIdx.x * CHUNK;
    int e1 = min(e0 + CHUNK, E);
    for (int e = e0 + t; e < e1; e += 256) {
        int s_, d;
        if (i64) { s_ = idx[2 * e]; d = idx[2 * (E + e)]; }
        else     { s_ = idx[e];     d = idx[E + e]; }
        float w = ew[e];
        int b = d >> BSH;
        int pos = base[b] + atomicAdd(&fill[b], 1);
        temp[pos] = make_int2(s_ | ((d & (BNODES - 1)) << 16), __float_as_int(w));
    }
}

// K4: per-bucket counting sort into final CSR + deg/dinv + row (one block/bucket)
__global__ __launch_bounds__(256) void csr_build_kernel(const int2* __restrict__ temp,
                                                        const int* __restrict__ bucketBase,
                                                        int2* __restrict__ csrw,
                                                        int* __restrict__ row,
                                                        float* __restrict__ dinv,
                                                        int N, int NB, int E) {
    __shared__ int cnt[BNODES];
    __shared__ float dw[BNODES];
    __shared__ int offs[BNODES];
    __shared__ int sc[256];
    __shared__ int carry;
    int bkt = blockIdx.x;
    int t = threadIdx.x;
    int node0 = bkt << BSH;
    int nn = min(BNODES, N - node0);
    for (int i = t; i < nn; i += 256) { cnt[i] = 0; dw[i] = 0.f; }
    if (t == 0) carry = 0;
    __syncthreads();
    int p0 = bucketBase[bkt];
    int p1 = (bkt + 1 < NB) ? bucketBase[bkt + 1] : E;
    for (int p = p0 + t; p < p1; p += 256) {
        int2 v = temp[p];
        int dl = (v.x >> 16) & (BNODES - 1);
        atomicAdd(&cnt[dl], 1);
        atomicAdd(&dw[dl], __int_as_float(v.y));
    }
    __syncthreads();
    // exclusive scan cnt[0..nn) -> offs (512 elems, 2 chunks of 256)
    for (int base = 0; base < BNODES; base += 256) {
        int i = base + t;
        int v = (i < nn) ? cnt[i] : 0;
        sc[t] = v;
        __syncthreads();
        for (int off = 1; off < 256; off <<= 1) {
            int x = (t >= off) ? sc[t - off] : 0;
            __syncthreads();
            sc[t] += x;
            __syncthreads();
        }
        offs[i] = carry + sc[t] - v;
        __syncthreads();
        if (t == 0) carry += sc[255];
        __syncthreads();
    }
    for (int i = t; i < nn; i += 256) {
        row[node0 + i] = p0 + offs[i];
        dinv[node0 + i] = rsqrtf(1.f + dw[i]);
    }
    if (bkt == NB - 1 && t == 0) row[N] = E;
    __syncthreads();
    for (int i = t; i < nn; i += 256) cnt[i] = 0;  // reuse as fill
    __syncthreads();
    for (int p = p0 + t; p < p1; p += 256) {
        int2 v = temp[p];
        int dl = (v.x >> 16) & (BNODES - 1);
        int pos = p0 + offs[dl] + atomicAdd(&cnt[dl], 1);
        csrw[pos] = make_int2(v.x & 0xFFFF, v.y);
    }
}

// K5: fold dinv[src] into edge weight (dinv[dst] applied in gather)
__global__ void norm_kernel(int2* __restrict__ csrw, const float* __restrict__ dinv, int E) {
    int e = blockIdx.x * BLK + threadIdx.x;
    if (e >= E) return;
    int2 v = csrw[e];
    float w = __int_as_float(v.y) * dinv[v.x];
    csrw[e] = make_int2(v.x, __float_as_int(w));
}

// ---------------------------------------------------------------------------
// gathers: out[n,o] = bias[o] + dinv[n]*(dinv[n]*h[n,o] + sum w'*h[src,o])
__global__ __launch_bounds__(256) void gather64_kernel(const int* __restrict__ row,
                                                       const int2* __restrict__ csrw,
                                                       const float* __restrict__ h,
                                                       const float* __restrict__ dinv,
                                                       const float* __restrict__ bias,
                                                       float* __restrict__ out, int N) {
    int wid = (blockIdx.x * 256 + threadIdx.x) >> 6;
    int o = threadIdx.x & 63;
    if (wid >= N) return;
    float di = dinv[wid];
    int p0 = row[wid], p1 = row[wid + 1];
    float es = 0.f;
    for (int p = p0; p < p1; p += 64) {
        int q = p + o;
        int2 v = (q < p1) ? csrw[q] : make_int2(0, 0);
        int m = min(64, p1 - p);
        for (int j = 0; j < m; ++j) {
            int s = __shfl(v.x, j, 64);
            int wb = __shfl(v.y, j, 64);
            es = fmaf(__int_as_float(wb), h[s * 64 + o], es);
        }
    }
    out[wid * 64 + o] = bias[o] + di * (di * h[wid * 64 + o] + es);
}

__global__ __launch_bounds__(256) void gather32_kernel(const int* __restrict__ row,
                                                       const int2* __restrict__ csrw,
                                                       const float* __restrict__ h,
                                                       const float* __restrict__ dinv,
                                                       const float* __restrict__ bias,
                                                       float* __restrict__ out, int N) {
    int wid = (blockIdx.x * 256 + threadIdx.x) >> 6;
    int lane = threadIdx.x & 63;
    int o = lane & 31;
    int g = lane >> 5;
    if (wid >= N) return;
    float di = dinv[wid];
    int p0 = row[wid], p1 = row[wid + 1];
    float es = 0.f;
    for (int p = p0; p < p1; p += 64) {
        int q = p + lane;
        int2 v = (q < p1) ? csrw[q] : make_int2(0, 0);
        int m = min(64, p1 - p);
        for (int j = g; j < m; j += 2) {
            int s = __shfl(v.x, j, 64);
            int wb = __shfl(v.y, j, 64);
            es = fmaf(__int_as_float(wb), h[s * 32 + o], es);
        }
    }
    es += __shfl_down(es, 32, 64);
    if (g == 0) out[wid * 32 + o] = bias[o] + di * (di * h[wid * 32 + o] + es);
}

__global__ __launch_bounds__(256) void gather2_kernel(const int* __restrict__ row,
                                                      const int2* __restrict__ csrw,
                                                      const float* __restrict__ h,
                                                      const float* __restrict__ dinv,
                                                      const float* __restrict__ bias,
                                                      float* __restrict__ out, int N) {
    int wid = (blockIdx.x * 256 + threadIdx.x) >> 6;
    int lane = threadIdx.x & 63;
    int o = lane & 1;
    if (wid >= N) return;
    float di = dinv[wid];
    int p0 = row[wid], p1 = row[wid + 1];
    float es = 0.f;
    for (int p = p0; p < p1; p += 64) {
        int q = p + lane;
        int2 v = (q < p1) ? csrw[q] : make_int2(0, 0);
        int m = min(64, p1 - p);
        for (int base = 0; base < m; base += 32) {
            int j = base + (lane >> 1);
            int s = __shfl(v.x, j, 64);
            int wb = __shfl(v.y, j, 64);  // 0 beyond edge count
            es = fmaf(__int_as_float(wb), h[s * 2 + o], es);
        }
    }
    for (int off = 2; off < 64; off <<= 1) es += __shfl_xor(es, off, 64);
    if (lane < 2) out[wid * 2 + o] = bias[o] + di * (di * h[wid * 2 + o] + es);
}

// ---------------------------------------------------------------------------
// Dense kernels
__global__ __launch_bounds__(256) void mm1_kernel(const float* __restrict__ X,
                                                  const float* __restrict__ W,
                                                  float* __restrict__ Y, int N) {
    __shared__ float Xs[16 * 132];
    __shared__ float4 Ws[128 * 16];
    const float4* Wg = (const float4*)W;
    for (int i = threadIdx.x; i < 128 * 16; i += 256) Ws[i] = Wg[i];
    int row0 = blockIdx.x * 16;
    for (int i = threadIdx.x; i < 16 * 128; i += 256) {
        int r = i >> 7, k = i & 127;
        int row = row0 + r;
        Xs[r * 132 + k] = (row < N) ? X[row * 128 + k] : 0.f;
    }
    __syncthreads();
    int r = threadIdx.x >> 4;
    int c4 = threadIdx.x & 15;
    int row = row0 + r;
    float4 acc = {0.f, 0.f, 0.f, 0.f};
#pragma unroll 4
    for (int k = 0; k < 128; ++k) {
        float xv = Xs[r * 132 + k];
        float4 wv = Ws[k * 16 + c4];
        acc.x = fmaf(xv, wv.x, acc.x);
        acc.y = fmaf(xv, wv.y, acc.y);
        acc.z = fmaf(xv, wv.z, acc.z);
        acc.w = fmaf(xv, wv.w, acc.w);
    }
    if (row < N) ((float4*)Y)[row * 16 + c4] = acc;
}

__global__ __launch_bounds__(256) void mm2_kernel(const float* __restrict__ H,
                                                  const float* __restrict__ W,
                                                  float* __restrict__ Y, int N) {
    __shared__ float Xs[32 * 68];
    __shared__ float4 Ws[64 * 8];
    const float4* Wg = (const float4*)W;
    for (int i = threadIdx.x; i < 64 * 8; i += 256) Ws[i] = Wg[i];
    int row0 = blockIdx.x * 32;
    for (int i = threadIdx.x; i < 32 * 64; i += 256) {
        int r = i >> 6, k = i & 63;
        int row = row0 + r;
        Xs[r * 68 + k] = (row < N) ? fmaxf(H[row * 64 + k], 0.f) : 0.f;
    }
    __syncthreads();
    int r = threadIdx.x >> 3;
    int c4 = threadIdx.x & 7;
    int row = row0 + r;
    float4 acc = {0.f, 0.f, 0.f, 0.f};
#pragma unroll 4
    for (int k = 0; k < 64; ++k) {
        float xv = Xs[r * 68 + k];
        float4 wv = Ws[k * 8 + c4];
        acc.x = fmaf(xv, wv.x, acc.x);
        acc.y = fmaf(xv, wv.y, acc.y);
        acc.z = fmaf(xv, wv.z, acc.z);
        acc.w = fmaf(xv, wv.w, acc.w);
    }
    if (row < N) ((float4*)Y)[row * 8 + c4] = acc;
}

__global__ __launch_bounds__(256) void disc_mm_kernel(const float* __restrict__ Z,
                                                      const float* __restrict__ F,
                                                      const float* __restrict__ Wd,
                                                      float* __restrict__ Y, int N) {
    __shared__ float Ws[256];
    if (threadIdx.x < 256) Ws[threadIdx.x] = Wd[threadIdx.x];
    __syncthreads();
    int n = blockIdx.x * 256 + threadIdx.x;
    if (n >= N) return;
    float zt[32];
#pragma unroll
    for (int j = 0; j < 32; ++j) zt[j] = tanhf(Z[n * 32 + j]);
    float a0 = 0.f, a1 = 0.f;
    const float* fr = F + (size_t)n * 128;
#pragma unroll 4
    for (int c = 0; c < 128; ++c) {
        float xv = zt[c & 31] + fr[c];
        a0 = fmaf(xv, Ws[c * 2 + 0], a0);
        a1 = fmaf(xv, Ws[c * 2 + 1], a1);
    }
    Y[n * 2 + 0] = a0;
    Y[n * 2 + 1] = a1;
}

// ---------------------------------------------------------------------------
// Fallback (atomic scatter) kernels
__global__ void init_deg_kernel(float* __restrict__ deg, int N) {
    int n = blockIdx.x * BLK + threadIdx.x;
    if (n < N) deg[n] = 1.0f;
}

__global__ void edge_deg_kernel(const int* __restrict__ idx, const float* __restrict__ ew,
                                const int* __restrict__ flag, float* __restrict__ deg, int E) {
    int e = blockIdx.x * BLK + threadIdx.x;
    if (e >= E) return;
    int d = (*flag) ? idx[2 * (E + e)] : idx[E + e];
    atomicAdd(&deg[d], ew[e]);
}

__global__ void dinv_kernel(float* __restrict__ deg, int N) {
    int n = blockIdx.x * BLK + threadIdx.x;
    if (n < N) deg[n] = rsqrtf(deg[n]);
}

template <int WD>
__global__ void init_agg_kernel(const float* __restrict__ h, const float* __restrict__ dinv,
                                const float* __restrict__ bias, float* __restrict__ agg, int N) {
    int i = blockIdx.x * BLK + threadIdx.x;
    if (i >= N * WD) return;
    int n = i / WD, o = i % WD;
    float di = dinv[n];
    agg[i] = bias[o] + di * di * h[i];
}

template <int WD>
__global__ void edge_agg_kernel(const int* __restrict__ idx, const float* __restrict__ ew,
                                const int* __restrict__ flag, const float* __restrict__ dinv,
                                const float* __restrict__ h, float* __restrict__ agg, int E) {
    int gid = blockIdx.x * BLK + threadIdx.x;
    if (gid >= E * WD) return;
    int e = gid / WD;
    int o = gid % WD;
    int s, d;
    if (*flag) { s = idx[2 * e]; d = idx[2 * (E + e)]; }
    else       { s = idx[e];     d = idx[E + e]; }
    float nrm = dinv[s] * ew[e] * dinv[d];
    atomicAdd(&agg[d * WD + o], nrm * h[s * WD + o]);
}

// ---------------------------------------------------------------------------
__global__ void reduce_kernel(const float* __restrict__ dmat, const float* __restrict__ wfc,
                              float* __restrict__ acc, int M) {
    int i = blockIdx.x * BLK + threadIdx.x;
    float v = 0.f;
    if (i < M) v = fmaxf(dmat[i], 0.f) * wfc[i];
#pragma unroll
    for (int off = 32; off > 0; off >>= 1) v += __shfl_down(v, off, 64);
    if ((threadIdx.x & 63) == 0) atomicAdd(acc, v);
}

__global__ void final_kernel(const float* __restrict__ acc, const float* __restrict__ bfc,
                             float* __restrict__ out) {
    float x = *acc + *bfc;
    out[0] = 1.f / (1.f + expf(-x));
}

// ---------------------------------------------------------------------------
extern "C" void kernel_launch(void* const* d_in, const int* in_sizes, int n_in,
                              void* d_out, int out_size, void* d_ws, size_t ws_size,
                              hipStream_t stream) {
    const float* feat = (const float*)d_in[0];
    const int*   eidx = (const int*)d_in[1];
    const float* ew   = (const float*)d_in[2];
    const float* W1   = (const float*)d_in[3];
    const float* b1   = (const float*)d_in[4];
    const float* W2   = (const float*)d_in[5];
    const float* b2   = (const float*)d_in[6];
    const float* Wd   = (const float*)d_in[7];
    const float* bd   = (const float*)d_in[8];
    const float* wfc  = (const float*)d_in[9];
    const float* bfc  = (const float*)d_in[10];

    const int N = in_sizes[0] / 128;  // 50000
    const int E = in_sizes[2];        // 1600000

    const int NB   = (N + BNODES - 1) >> BSH;       // buckets (98)
    const int NBLK = (E + CHUNK - 1) / CHUNK;       // edge blocks (391)

    // workspace layout (units: 4B words)
    float* ws = (float*)d_ws;
    size_t u = 0;
    float* dinv = ws + u; u += N;
    if (u & 1) u++;
    size_t M1 = ((size_t)N * 64 > (size_t)E * 2) ? (size_t)N * 64 : (size_t)E * 2;
    float* h = ws + u; int2* temp = (int2*)h; u += M1;          // temp aliases h
    if (u & 1) u++;
    float* agg = ws + u; u += (size_t)N * 64;
    float* acc = ws + u; u += 1;
    int* flag = (int*)(ws + u); u += 1;
    int* row  = (int*)(ws + u); u += (size_t)N + 1;
    int* bucketTotal = (int*)(ws + u); u += NB;
    int* bucketBase  = (int*)(ws + u); u += NB + 1;
    int* blockCnt    = (int*)(ws + u); u += (size_t)NBLK * NB;
    int* blockBase   = (int*)(ws + u); u += (size_t)NBLK * NB;
    if (u & 1) u++;
    int2* csrw = (int2*)(ws + u); u += (size_t)E * 2;
    size_t need = u * 4;

    float* out = (float*)d_out;

    const int gN = (N + BLK - 1) / BLK;
    const int gE = (E + BLK - 1) / BLK;
    const int gW = (N + 3) / 4;  // wave-per-node grids (4 nodes / 256-thr block)

    if (ws_size >= need && N <= 65536 && NB <= MAXNB) {
        // ---- deterministic bucket-sort CSR build ----
        hipLaunchKernelGGL(detect_kernel, dim3(1), dim3(64), 0, stream, eidx, E, flag, acc);
        hipLaunchKernelGGL(bucket_hist_kernel, dim3(NBLK), dim3(256), 0, stream,
                           eidx, flag, blockCnt, E, NB);
        hipLaunchKernelGGL(col_scan_kernel, dim3(NB), dim3(256), 0, stream,
                           blockCnt, blockBase, bucketTotal, NBLK, NB);
        hipLaunchKernelGGL(bucket_scan_kernel, dim3(1), dim3(128), 0, stream,
                           bucketTotal, bucketBase, NB);
        hipLaunchKernelGGL(bucket_scatter_kernel, dim3(NBLK), dim3(256), 0, stream,
                           eidx, ew, flag, bucketBase, blockBase, temp, E, NB);
        hipLaunchKernelGGL(csr_build_kernel, dim3(NB), dim3(256), 0, stream,
                           temp, bucketBase, csrw, row, dinv, N, NB, E);
        hipLaunchKernelGGL(norm_kernel, dim3(gE), dim3(BLK), 0, stream, csrw, dinv, E);

        // ---- layers ----
        hipLaunchKernelGGL(mm1_kernel, dim3((N + 15) / 16), dim3(256), 0, stream, feat, W1, h, N);
        hipLaunchKernelGGL(gather64_kernel, dim3(gW), dim3(256), 0, stream,
                           row, csrw, h, dinv, b1, agg, N);
        hipLaunchKernelGGL(mm2_kernel, dim3((N + 31) / 32), dim3(256), 0, stream, agg, W2, h, N);
        hipLaunchKernelGGL(gather32_kernel, dim3(gW), dim3(256), 0, stream,
                           row, csrw, h, dinv, b2, agg, N);
        hipLaunchKernelGGL(disc_mm_kernel, dim3((N + 255) / 256), dim3(256), 0, stream,
                           agg, feat, Wd, h, N);
        hipLaunchKernelGGL(gather2_kernel, dim3(gW), dim3(256), 0, stream,
                           row, csrw, h, dinv, bd, agg, N);
    } else {
        // ---- fallback: atomic scatter path ----
        hipLaunchKernelGGL(detect_kernel, dim3(1), dim3(64), 0, stream, eidx, E, flag, acc);
        hipLaunchKernelGGL(init_deg_kernel, dim3(gN), dim3(BLK), 0, stream, dinv, N);
        hipLaunchKernelGGL(edge_deg_kernel, dim3(gE), dim3(BLK), 0, stream, eidx, ew, flag, dinv, E);
        hipLaunchKernelGGL(dinv_kernel, dim3(gN), dim3(BLK), 0, stream, dinv, N);

        hipLaunchKernelGGL(mm1_kernel, dim3((N + 15) / 16), dim3(256), 0, stream, feat, W1, h, N);
        hipLaunchKernelGGL((init_agg_kernel<64>), dim3((N * 64 + BLK - 1) / BLK), dim3(BLK), 0, stream,
                           h, dinv, b1, agg, N);
        hipLaunchKernelGGL((edge_agg_kernel<64>), dim3((E / BLK) * 64 + 64), dim3(BLK), 0, stream,
                           eidx, ew, flag, dinv, h, agg, E);
        hipLaunchKernelGGL(mm2_kernel, dim3((N + 31) / 32), dim3(256), 0, stream, agg, W2, h, N);
        hipLaunchKernelGGL((init_agg_kernel<32>), dim3((N * 32 + BLK - 1) / BLK), dim3(BLK), 0, stream,
                           h, dinv, b2, agg, N);
        hipLaunchKernelGGL((edge_agg_kernel<32>), dim3((E / BLK) * 32 + 32), dim3(BLK), 0, stream,
                           eidx, ew, flag, dinv, h, agg, E);
        hipLaunchKernelGGL(disc_mm_kernel, dim3((N + 255) / 256), dim3(256), 0, stream,
                           agg, feat, Wd, h, N);
        hipLaunchKernelGGL((init_agg_kernel<2>), dim3((N * 2 + BLK - 1) / BLK), dim3(BLK), 0, stream,
                           h, dinv, bd, agg, N);
        hipLaunchKernelGGL((edge_agg_kernel<2>), dim3((E * 2 + BLK - 1) / BLK), dim3(BLK), 0, stream,
                           eidx, ew, flag, dinv, h, agg, E);
    }

    hipLaunchKernelGGL(reduce_kernel, dim3((N * 2 + BLK - 1) / BLK), dim3(BLK), 0, stream,
                       agg, wfc, acc, N * 2);
    hipLaunchKernelGGL(final_kernel, dim3(1), dim3(1), 0, stream, acc, bfc, out);
}

// Round 4
// 400.436 us; speedup vs baseline: 2.1845x; 1.0543x over previous
//
#include <hip/hip_runtime.h>
#include <math.h>

#define BLK 256
#define CHUNK 4096
#define BSH 9
#define BNODES 512
#define MAXNB 128

// ---------------------------------------------------------------------------
__device__ __forceinline__ unsigned short f2bf(float f) {
    unsigned u = __float_as_uint(f);
    u += 0x7FFFu + ((u >> 16) & 1u);
    return (unsigned short)(u >> 16);
}
__device__ __forceinline__ float bf2f(unsigned short b) {
    return __uint_as_float(((unsigned)b) << 16);
}

// ---------------------------------------------------------------------------
// Probe int64-vs-int32 edge_index layout; zero the scalar accumulator.
__global__ void detect_kernel(const int* __restrict__ idx, int E,
                              int* __restrict__ flag, float* __restrict__ acc) {
    int t = threadIdx.x;  // 64 threads
    long long j = (long long)t * (E / 64);
    int hi = idx[2 * j + 1];
    unsigned long long b = __ballot(hi != 0);
    if (t == 0) { *flag = (b == 0ULL) ? 1 : 0; *acc = 0.f; }
}

// ---------------------------------------------------------------------------
// K1: per-block bucket histogram (bucket = dst >> BSH), coalesced count rows.
__global__ __launch_bounds__(256) void bucket_hist_kernel(const int* __restrict__ idx,
                                                          const int* __restrict__ flag,
                                                          int* __restrict__ blockCnt,
                                                          int E, int NB) {
    __shared__ int hist[MAXNB];
    int t = threadIdx.x;
    if (t < NB) hist[t] = 0;
    __syncthreads();
    bool i64 = (*flag) != 0;
    int e0 = blockIdx.x * CHUNK;
    int e1 = min(e0 + CHUNK, E);
    for (int e = e0 + t; e < e1; e += 256) {
        int d = i64 ? idx[2 * (E + e)] : idx[E + e];
        atomicAdd(&hist[d >> BSH], 1);
    }
    __syncthreads();
    if (t < NB) blockCnt[blockIdx.x * NB + t] = hist[t];
}

// K2: column-wise exclusive scan over blocks (one block per bucket)
__global__ __launch_bounds__(256) void col_scan_kernel(const int* __restrict__ blockCnt,
                                                       int* __restrict__ blockBase,
                                                       int* __restrict__ bucketTotal,
                                                       int NBLK, int NB) {
    __shared__ int s[256];
    __shared__ int carry;
    int bkt = blockIdx.x;
    int t = threadIdx.x;
    if (t == 0) carry = 0;
    __syncthreads();
    for (int base = 0; base < NBLK; base += 256) {
        int i = base + t;
        int v = (i < NBLK) ? blockCnt[i * NB + bkt] : 0;
        s[t] = v;
        __syncthreads();
        for (int off = 1; off < 256; off <<= 1) {
            int x = (t >= off) ? s[t - off] : 0;
            __syncthreads();
            s[t] += x;
            __syncthreads();
        }
        if (i < NBLK) blockBase[i * NB + bkt] = carry + s[t] - v;
        __syncthreads();
        if (t == 0) carry += s[255];
        __syncthreads();
    }
    if (t == 0) bucketTotal[bkt] = carry;
}

// K2b: exclusive scan of bucket totals (NB <= 128)
__global__ void bucket_scan_kernel(const int* __restrict__ bucketTotal,
                                   int* __restrict__ bucketBase, int NB) {
    __shared__ int s[128];
    int t = threadIdx.x;  // 128 threads
    int v = (t < NB) ? bucketTotal[t] : 0;
    s[t] = v;
    __syncthreads();
    for (int off = 1; off < 128; off <<= 1) {
        int x = (t >= off) ? s[t - off] : 0;
        __syncthreads();
        s[t] += x;
        __syncthreads();
    }
    if (t < NB) bucketBase[t] = s[t] - v;
}

// K3: scatter edges into bucket-partitioned temp as contiguous runs.
// payload: (src | dlocal<<16, bits(w fp32))
__global__ __launch_bounds__(256) void bucket_scatter_kernel(const int* __restrict__ idx,
                                                             const float* __restrict__ ew,
                                                             const int* __restrict__ flag,
                                                             const int* __restrict__ bucketBase,
                                                             const int* __restrict__ blockBase,
                                                             int2* __restrict__ temp,
                                                             int E, int NB) {
    __shared__ int base[MAXNB];
    __shared__ int fill[MAXNB];
    int t = threadIdx.x;
    if (t < NB) {
        base[t] = bucketBase[t] + blockBase[blockIdx.x * NB + t];
        fill[t] = 0;
    }
    __syncthreads();
    bool i64 = (*flag) != 0;
    int e0 = blockIdx.x * CHUNK;
    int e1 = min(e0 + CHUNK, E);
    for (int e = e0 + t; e < e1; e += 256) {
        int s_, d;
        if (i64) { s_ = idx[2 * e]; d = idx[2 * (E + e)]; }
        else     { s_ = idx[e];     d = idx[E + e]; }
        float w = ew[e];
        int b = d >> BSH;
        int pos = base[b] + atomicAdd(&fill[b], 1);
        temp[pos] = make_int2(s_ | ((d & (BNODES - 1)) << 16), __float_as_int(w));
    }
}

// K4: per-bucket counting sort into packed CSR + dinv + row (one block/bucket)
// csrw[p] = src(16b) | bf16(w)<<16
__global__ __launch_bounds__(256) void csr_build_kernel(const int2* __restrict__ temp,
                                                        const int* __restrict__ bucketBase,
                                                        unsigned* __restrict__ csrw,
                                                        int* __restrict__ row,
                                                        float* __restrict__ dinv,
                                                        int N, int NB, int E) {
    __shared__ int cnt[BNODES];
    __shared__ float dw[BNODES];
    __shared__ int offs[BNODES];
    __shared__ int sc[256];
    __shared__ int carry;
    int bkt = blockIdx.x;
    int t = threadIdx.x;
    int node0 = bkt << BSH;
    int nn = min(BNODES, N - node0);
    for (int i = t; i < nn; i += 256) { cnt[i] = 0; dw[i] = 0.f; }
    if (t == 0) carry = 0;
    __syncthreads();
    int p0 = bucketBase[bkt];
    int p1 = (bkt + 1 < NB) ? bucketBase[bkt + 1] : E;
    for (int p = p0 + t; p < p1; p += 256) {
        int2 v = temp[p];
        int dl = (v.x >> 16) & (BNODES - 1);
        atomicAdd(&cnt[dl], 1);
        atomicAdd(&dw[dl], __int_as_float(v.y));
    }
    __syncthreads();
    for (int base = 0; base < BNODES; base += 256) {
        int i = base + t;
        int v = (i < nn) ? cnt[i] : 0;
        sc[t] = v;
        __syncthreads();
        for (int off = 1; off < 256; off <<= 1) {
            int x = (t >= off) ? sc[t - off] : 0;
            __syncthreads();
            sc[t] += x;
            __syncthreads();
        }
        offs[i] = carry + sc[t] - v;
        __syncthreads();
        if (t == 0) carry += sc[255];
        __syncthreads();
    }
    for (int i = t; i < nn; i += 256) {
        row[node0 + i] = p0 + offs[i];
        dinv[node0 + i] = rsqrtf(1.f + dw[i]);
    }
    if (bkt == NB - 1 && t == 0) row[N] = E;
    __syncthreads();
    for (int i = t; i < nn; i += 256) cnt[i] = 0;  // reuse as fill
    __syncthreads();
    for (int p = p0 + t; p < p1; p += 256) {
        int2 v = temp[p];
        int dl = (v.x >> 16) & (BNODES - 1);
        int pos = p0 + offs[dl] + atomicAdd(&cnt[dl], 1);
        unsigned wb = (unsigned)v.y;
        wb += 0x7FFFu + ((wb >> 16) & 1u);
        csrw[pos] = ((unsigned)v.x & 0xFFFFu) | (wb & 0xFFFF0000u);
    }
}

// K5: fold dinv[src] into packed bf16 edge weight
__global__ void norm_kernel(unsigned* __restrict__ csrw, const float* __restrict__ dinv, int E) {
    int e = blockIdx.x * BLK + threadIdx.x;
    if (e >= E) return;
    unsigned pe = csrw[e];
    float w = __uint_as_float(pe & 0xFFFF0000u) * dinv[pe & 0xFFFFu];
    unsigned wb = __float_as_uint(w);
    wb += 0x7FFFu + ((wb >> 16) & 1u);
    csrw[e] = (pe & 0xFFFFu) | (wb & 0xFFFF0000u);
}

// ---------------------------------------------------------------------------
// gathers: out[n,o] = bias[o] + dinv[n]*(dinv[n]*h[n,o] + sum w'*h[src,o])
// h is bf16 (ushort); out fp32.
__global__ __launch_bounds__(256) void gather64_kernel(const int* __restrict__ row,
                                                       const unsigned* __restrict__ csrw,
                                                       const unsigned short* __restrict__ h,
                                                       const float* __restrict__ dinv,
                                                       const float* __restrict__ bias,
                                                       float* __restrict__ out, int N) {
    int wid = (blockIdx.x * 256 + threadIdx.x) >> 6;
    int o = threadIdx.x & 63;
    if (wid >= N) return;
    float di = dinv[wid];
    int p0 = row[wid], p1 = row[wid + 1];
    float es = 0.f;
    for (int p = p0; p < p1; p += 64) {
        int q = p + o;
        unsigned pe = (q < p1) ? csrw[q] : 0u;
        int m = min(64, p1 - p);
        for (int j = 0; j < m; ++j) {
            unsigned e = (unsigned)__shfl((int)pe, j, 64);
            float w = __uint_as_float(e & 0xFFFF0000u);
            int s = e & 0xFFFF;
            es = fmaf(w, bf2f(h[s * 64 + o]), es);
        }
    }
    out[wid * 64 + o] = bias[o] + di * (di * bf2f(h[wid * 64 + o]) + es);
}

__global__ __launch_bounds__(256) void gather32_kernel(const int* __restrict__ row,
                                                       const unsigned* __restrict__ csrw,
                                                       const unsigned short* __restrict__ h,
                                                       const float* __restrict__ dinv,
                                                       const float* __restrict__ bias,
                                                       float* __restrict__ out, int N) {
    int wid = (blockIdx.x * 256 + threadIdx.x) >> 6;
    int lane = threadIdx.x & 63;
    int o = lane & 31;
    int g = lane >> 5;
    if (wid >= N) return;
    float di = dinv[wid];
    int p0 = row[wid], p1 = row[wid + 1];
    float es = 0.f;
    for (int p = p0; p < p1; p += 64) {
        int q = p + lane;
        unsigned pe = (q < p1) ? csrw[q] : 0u;
        int m = min(64, p1 - p);
        for (int j = g; j < m; j += 2) {
            unsigned e = (unsigned)__shfl((int)pe, j, 64);
            float w = __uint_as_float(e & 0xFFFF0000u);
            int s = e & 0xFFFF;
            es = fmaf(w, bf2f(h[s * 32 + o]), es);
        }
    }
    es += __shfl_down(es, 32, 64);
    if (g == 0) out[wid * 32 + o] = bias[o] + di * (di * bf2f(h[wid * 32 + o]) + es);
}

// WD=2: one edge per lane; h row packed in one uint (2 bf16)
__global__ __launch_bounds__(256) void gather2_kernel(const int* __restrict__ row,
                                                      const unsigned* __restrict__ csrw,
                                                      const unsigned short* __restrict__ h,
                                                      const float* __restrict__ dinv,
                                                      const float* __restrict__ bias,
                                                      float* __restrict__ out, int N) {
    const unsigned* hp = (const unsigned*)h;
    int wid = (blockIdx.x * 256 + threadIdx.x) >> 6;
    int lane = threadIdx.x & 63;
    if (wid >= N) return;
    float di = dinv[wid];
    int p0 = row[wid], p1 = row[wid + 1];
    float a0 = 0.f, a1 = 0.f;
    for (int p = p0 + lane; p < p1; p += 64) {
        unsigned pe = csrw[p];
        float w = __uint_as_float(pe & 0xFFFF0000u);
        unsigned hw = hp[pe & 0xFFFFu];
        a0 = fmaf(w, __uint_as_float(hw << 16), a0);
        a1 = fmaf(w, __uint_as_float(hw & 0xFFFF0000u), a1);
    }
#pragma unroll
    for (int off = 32; off > 0; off >>= 1) {
        a0 += __shfl_down(a0, off, 64);
        a1 += __shfl_down(a1, off, 64);
    }
    if (lane == 0) {
        unsigned hw = hp[wid];
        out[wid * 2 + 0] = bias[0] + di * (di * __uint_as_float(hw << 16) + a0);
        out[wid * 2 + 1] = bias[1] + di * (di * __uint_as_float(hw & 0xFFFF0000u) + a1);
    }
}

// ---------------------------------------------------------------------------
// Dense kernels: fp32 in, bf16 out
__global__ __launch_bounds__(256) void mm1_kernel(const float* __restrict__ X,
                                                  const float* __restrict__ W,
                                                  unsigned short* __restrict__ Y, int N) {
    __shared__ float Xs[16 * 132];
    __shared__ float4 Ws[128 * 16];
    const float4* Wg = (const float4*)W;
    for (int i = threadIdx.x; i < 128 * 16; i += 256) Ws[i] = Wg[i];
    int row0 = blockIdx.x * 16;
    for (int i = threadIdx.x; i < 16 * 128; i += 256) {
        int r = i >> 7, k = i & 127;
        int row = row0 + r;
        Xs[r * 132 + k] = (row < N) ? X[row * 128 + k] : 0.f;
    }
    __syncthreads();
    int r = threadIdx.x >> 4;
    int c4 = threadIdx.x & 15;
    int row = row0 + r;
    float4 acc = {0.f, 0.f, 0.f, 0.f};
#pragma unroll 4
    for (int k = 0; k < 128; ++k) {
        float xv = Xs[r * 132 + k];
        float4 wv = Ws[k * 16 + c4];
        acc.x = fmaf(xv, wv.x, acc.x);
        acc.y = fmaf(xv, wv.y, acc.y);
        acc.z = fmaf(xv, wv.z, acc.z);
        acc.w = fmaf(xv, wv.w, acc.w);
    }
    if (row < N) {
        ushort4 o;
        o.x = f2bf(acc.x); o.y = f2bf(acc.y); o.z = f2bf(acc.z); o.w = f2bf(acc.w);
        ((ushort4*)Y)[row * 16 + c4] = o;
    }
}

__global__ __launch_bounds__(256) void mm2_kernel(const float* __restrict__ H,
                                                  const float* __restrict__ W,
                                                  unsigned short* __restrict__ Y, int N) {
    __shared__ float Xs[32 * 68];
    __shared__ float4 Ws[64 * 8];
    const float4* Wg = (const float4*)W;
    for (int i = threadIdx.x; i < 64 * 8; i += 256) Ws[i] = Wg[i];
    int row0 = blockIdx.x * 32;
    for (int i = threadIdx.x; i < 32 * 64; i += 256) {
        int r = i >> 6, k = i & 63;
        int row = row0 + r;
        Xs[r * 68 + k] = (row < N) ? fmaxf(H[row * 64 + k], 0.f) : 0.f;
    }
    __syncthreads();
    int r = threadIdx.x >> 3;
    int c4 = threadIdx.x & 7;
    int row = row0 + r;
    float4 acc = {0.f, 0.f, 0.f, 0.f};
#pragma unroll 4
    for (int k = 0; k < 64; ++k) {
        float xv = Xs[r * 68 + k];
        float4 wv = Ws[k * 8 + c4];
        acc.x = fmaf(xv, wv.x, acc.x);
        acc.y = fmaf(xv, wv.y, acc.y);
        acc.z = fmaf(xv, wv.z, acc.z);
        acc.w = fmaf(xv, wv.w, acc.w);
    }
    if (row < N) {
        ushort4 o;
        o.x = f2bf(acc.x); o.y = f2bf(acc.y); o.z = f2bf(acc.z); o.w = f2bf(acc.w);
        ((ushort4*)Y)[row * 8 + c4] = o;
    }
}

__global__ __launch_bounds__(256) void disc_mm_kernel(const float* __restrict__ Z,
                                                      const float* __restrict__ F,
                                                      const float* __restrict__ Wd,
                                                      unsigned short* __restrict__ Y, int N) {
    __shared__ float Ws[256];
    if (threadIdx.x < 256) Ws[threadIdx.x] = Wd[threadIdx.x];
    __syncthreads();
    int n = blockIdx.x * 256 + threadIdx.x;
    if (n >= N) return;
    float zt[32];
#pragma unroll
    for (int j = 0; j < 32; ++j) zt[j] = tanhf(Z[n * 32 + j]);
    float a0 = 0.f, a1 = 0.f;
    const float* fr = F + (size_t)n * 128;
#pragma unroll 4
    for (int c = 0; c < 128; ++c) {
        float xv = zt[c & 31] + fr[c];
        a0 = fmaf(xv, Ws[c * 2 + 0], a0);
        a1 = fmaf(xv, Ws[c * 2 + 1], a1);
    }
    ushort2 o;
    o.x = f2bf(a0); o.y = f2bf(a1);
    ((ushort2*)Y)[n] = o;
}

// ---------------------------------------------------------------------------
// Fallback (atomic scatter) kernels — bf16 h
__global__ void init_deg_kernel(float* __restrict__ deg, int N) {
    int n = blockIdx.x * BLK + threadIdx.x;
    if (n < N) deg[n] = 1.0f;
}

__global__ void edge_deg_kernel(const int* __restrict__ idx, const float* __restrict__ ew,
                                const int* __restrict__ flag, float* __restrict__ deg, int E) {
    int e = blockIdx.x * BLK + threadIdx.x;
    if (e >= E) return;
    int d = (*flag) ? idx[2 * (E + e)] : idx[E + e];
    atomicAdd(&deg[d], ew[e]);
}

__global__ void dinv_kernel(float* __restrict__ deg, int N) {
    int n = blockIdx.x * BLK + threadIdx.x;
    if (n < N) deg[n] = rsqrtf(deg[n]);
}

template <int WD>
__global__ void init_agg_kernel(const unsigned short* __restrict__ h, const float* __restrict__ dinv,
                                const float* __restrict__ bias, float* __restrict__ agg, int N) {
    int i = blockIdx.x * BLK + threadIdx.x;
    if (i >= N * WD) return;
    int n = i / WD, o = i % WD;
    float di = dinv[n];
    agg[i] = bias[o] + di * di * bf2f(h[i]);
}

template <int WD>
__global__ void edge_agg_kernel(const int* __restrict__ idx, const float* __restrict__ ew,
                                const int* __restrict__ flag, const float* __restrict__ dinv,
                                const unsigned short* __restrict__ h, float* __restrict__ agg, int E) {
    int gid = blockIdx.x * BLK + threadIdx.x;
    if (gid >= E * WD) return;
    int e = gid / WD;
    int o = gid % WD;
    int s, d;
    if (*flag) { s = idx[2 * e]; d = idx[2 * (E + e)]; }
    else       { s = idx[e];     d = idx[E + e]; }
    float nrm = dinv[s] * ew[e] * dinv[d];
    atomicAdd(&agg[d * WD + o], nrm * bf2f(h[s * WD + o]));
}

// ---------------------------------------------------------------------------
__global__ void reduce_kernel(const float* __restrict__ dmat, const float* __restrict__ wfc,
                              float* __restrict__ acc, int M) {
    int i = blockIdx.x * BLK + threadIdx.x;
    float v = 0.f;
    if (i < M) v = fmaxf(dmat[i], 0.f) * wfc[i];
#pragma unroll
    for (int off = 32; off > 0; off >>= 1) v += __shfl_down(v, off, 64);
    if ((threadIdx.x & 63) == 0) atomicAdd(acc, v);
}

__global__ void final_kernel(const float* __restrict__ acc, const float* __restrict__ bfc,
                             float* __restrict__ out) {
    float x = *acc + *bfc;
    out[0] = 1.f / (1.f + expf(-x));
}

// ---------------------------------------------------------------------------
extern "C" void kernel_launch(void* const* d_in, const int* in_sizes, int n_in,
                              void* d_out, int out_size, void* d_ws, size_t ws_size,
                              hipStream_t stream) {
    const float* feat = (const float*)d_in[0];
    const int*   eidx = (const int*)d_in[1];
    const float* ew   = (const float*)d_in[2];
    const float* W1   = (const float*)d_in[3];
    const float* b1   = (const float*)d_in[4];
    const float* W2   = (const float*)d_in[5];
    const float* b2   = (const float*)d_in[6];
    const float* Wd   = (const float*)d_in[7];
    const float* bd   = (const float*)d_in[8];
    const float* wfc  = (const float*)d_in[9];
    const float* bfc  = (const float*)d_in[10];

    const int N = in_sizes[0] / 128;  // 50000
    const int E = in_sizes[2];        // 1600000

    const int NB   = (N + BNODES - 1) >> BSH;       // buckets (98)
    const int NBLK = (E + CHUNK - 1) / CHUNK;       // edge blocks (391)

    // workspace layout (units: 4B words)
    float* ws = (float*)d_ws;
    size_t u = 0;
    float* dinv = ws + u; u += N;
    if (u & 1) u++;
    // region1: temp(int2,E) aliases h(bf16, up to N*64 ushorts = N*32 words)
    size_t M1 = ((size_t)N * 32 > (size_t)E * 2) ? (size_t)N * 32 : (size_t)E * 2;
    unsigned short* h = (unsigned short*)(ws + u); int2* temp = (int2*)h; u += M1;
    if (u & 1) u++;
    float* agg = ws + u; u += (size_t)N * 64;
    float* acc = ws + u; u += 1;
    int* flag = (int*)(ws + u); u += 1;
    int* row  = (int*)(ws + u); u += (size_t)N + 1;
    int* bucketTotal = (int*)(ws + u); u += NB;
    int* bucketBase  = (int*)(ws + u); u += NB + 1;
    int* blockCnt    = (int*)(ws + u); u += (size_t)NBLK * NB;
    int* blockBase   = (int*)(ws + u); u += (size_t)NBLK * NB;
    unsigned* csrw   = (unsigned*)(ws + u); u += (size_t)E;
    size_t need = u * 4;

    float* out = (float*)d_out;

    const int gN = (N + BLK - 1) / BLK;
    const int gE = (E + BLK - 1) / BLK;
    const int gW = (N + 3) / 4;  // wave-per-node grids (4 nodes / 256-thr block)

    if (ws_size >= need && N <= 65536 && NB <= MAXNB) {
        // ---- deterministic bucket-sort CSR build ----
        hipLaunchKernelGGL(detect_kernel, dim3(1), dim3(64), 0, stream, eidx, E, flag, acc);
        hipLaunchKernelGGL(bucket_hist_kernel, dim3(NBLK), dim3(256), 0, stream,
                           eidx, flag, blockCnt, E, NB);
        hipLaunchKernelGGL(col_scan_kernel, dim3(NB), dim3(256), 0, stream,
                           blockCnt, blockBase, bucketTotal, NBLK, NB);
        hipLaunchKernelGGL(bucket_scan_kernel, dim3(1), dim3(128), 0, stream,
                           bucketTotal, bucketBase, NB);
        hipLaunchKernelGGL(bucket_scatter_kernel, dim3(NBLK), dim3(256), 0, stream,
                           eidx, ew, flag, bucketBase, blockBase, temp, E, NB);
        hipLaunchKernelGGL(csr_build_kernel, dim3(NB), dim3(256), 0, stream,
                           temp, bucketBase, csrw, row, dinv, N, NB, E);
        hipLaunchKernelGGL(norm_kernel, dim3(gE), dim3(BLK), 0, stream, csrw, dinv, E);

        // ---- layers ----
        hipLaunchKernelGGL(mm1_kernel, dim3((N + 15) / 16), dim3(256), 0, stream, feat, W1, h, N);
        hipLaunchKernelGGL(gather64_kernel, dim3(gW), dim3(256), 0, stream,
                           row, csrw, h, dinv, b1, agg, N);
        hipLaunchKernelGGL(mm2_kernel, dim3((N + 31) / 32), dim3(256), 0, stream, agg, W2, h, N);
        hipLaunchKernelGGL(gather32_kernel, dim3(gW), dim3(256), 0, stream,
                           row, csrw, h, dinv, b2, agg, N);
        hipLaunchKernelGGL(disc_mm_kernel, dim3((N + 255) / 256), dim3(256), 0, stream,
                           agg, feat, Wd, h, N);
        hipLaunchKernelGGL(gather2_kernel, dim3(gW), dim3(256), 0, stream,
                           row, csrw, h, dinv, bd, agg, N);
    } else {
        // ---- fallback: atomic scatter path ----
        hipLaunchKernelGGL(detect_kernel, dim3(1), dim3(64), 0, stream, eidx, E, flag, acc);
        hipLaunchKernelGGL(init_deg_kernel, dim3(gN), dim3(BLK), 0, stream, dinv, N);
        hipLaunchKernelGGL(edge_deg_kernel, dim3(gE), dim3(BLK), 0, stream, eidx, ew, flag, dinv, E);
        hipLaunchKernelGGL(dinv_kernel, dim3(gN), dim3(BLK), 0, stream, dinv, N);

        hipLaunchKernelGGL(mm1_kernel, dim3((N + 15) / 16), dim3(256), 0, stream, feat, W1, h, N);
        hipLaunchKernelGGL((init_agg_kernel<64>), dim3((N * 64 + BLK - 1) / BLK), dim3(BLK), 0, stream,
                           h, dinv, b1, agg, N);
        hipLaunchKernelGGL((edge_agg_kernel<64>), dim3((E / BLK) * 64 + 64), dim3(BLK), 0, stream,
                           eidx, ew, flag, dinv, h, agg, E);
        hipLaunchKernelGGL(mm2_kernel, dim3((N + 31) / 32), dim3(256), 0, stream, agg, W2, h, N);
        hipLaunchKernelGGL((init_agg_kernel<32>), dim3((N * 32 + BLK - 1) / BLK), dim3(BLK), 0, stream,
                           h, dinv, b2, agg, N);
        hipLaunchKernelGGL((edge_agg_kernel<32>), dim3((E / BLK) * 32 + 32), dim3(BLK), 0, stream,
                           eidx, ew, flag, dinv, h, agg, E);
        hipLaunchKernelGGL(disc_mm_kernel, dim3((N + 255) / 256), dim3(256), 0, stream,
                           agg, feat, Wd, h, N);
        hipLaunchKernelGGL((init_agg_kernel<2>), dim3((N * 2 + BLK - 1) / BLK), dim3(BLK), 0, stream,
                           h, dinv, bd, agg, N);
        hipLaunchKernelGGL((edge_agg_kernel<2>), dim3((E * 2 + BLK - 1) / BLK), dim3(BLK), 0, stream,
                           eidx, ew, flag, dinv, h, agg, E);
    }

    hipLaunchKernelGGL(reduce_kernel, dim3((N * 2 + BLK - 1) / BLK), dim3(BLK), 0, stream,
                       agg, wfc, acc, N * 2);
    hipLaunchKernelGGL(final_kernel, dim3(1), dim3(1), 0, stream, acc, bfc, out);
}

// Round 6
// 331.448 us; speedup vs baseline: 2.6392x; 1.2081x over previous
//
#include <hip/hip_runtime.h>
#include <math.h>

#define BLK 256
#define CHUNK 4096
#define BSH 9
#define BNODES 512
#define MAXNB 128

// ---------------------------------------------------------------------------
__device__ __forceinline__ unsigned short f2bf(float f) {
    unsigned u = __float_as_uint(f);
    u += 0x7FFFu + ((u >> 16) & 1u);
    return (unsigned short)(u >> 16);
}
__device__ __forceinline__ float bf2f(unsigned short b) {
    return __uint_as_float(((unsigned)b) << 16);
}

// ---------------------------------------------------------------------------
// Probe int64-vs-int32 edge_index layout; zero the scalar accumulator.
__global__ void detect_kernel(const int* __restrict__ idx, int E,
                              int* __restrict__ flag, float* __restrict__ acc) {
    int t = threadIdx.x;  // 64 threads
    long long j = (long long)t * (E / 64);
    int hi = idx[2 * j + 1];
    unsigned long long b = __ballot(hi != 0);
    if (t == 0) { *flag = (b == 0ULL) ? 1 : 0; *acc = 0.f; }
}

// ---------------------------------------------------------------------------
// K1: per-block bucket histogram (bucket = dst >> BSH), coalesced count rows.
__global__ __launch_bounds__(256) void bucket_hist_kernel(const int* __restrict__ idx,
                                                          const int* __restrict__ flag,
                                                          int* __restrict__ blockCnt,
                                                          int E, int NB) {
    __shared__ int hist[MAXNB];
    int t = threadIdx.x;
    if (t < NB) hist[t] = 0;
    __syncthreads();
    bool i64 = (*flag) != 0;
    int e0 = blockIdx.x * CHUNK;
    int e1 = min(e0 + CHUNK, E);
    for (int e = e0 + t; e < e1; e += 256) {
        int d = i64 ? idx[2 * (E + e)] : idx[E + e];
        atomicAdd(&hist[d >> BSH], 1);
    }
    __syncthreads();
    if (t < NB) blockCnt[blockIdx.x * NB + t] = hist[t];
}

// K2: column-wise exclusive scan over blocks (one block per bucket)
__global__ __launch_bounds__(256) void col_scan_kernel(const int* __restrict__ blockCnt,
                                                       int* __restrict__ blockBase,
                                                       int* __restrict__ bucketTotal,
                                                       int NBLK, int NB) {
    __shared__ int s[256];
    __shared__ int carry;
    int bkt = blockIdx.x;
    int t = threadIdx.x;
    if (t == 0) carry = 0;
    __syncthreads();
    for (int base = 0; base < NBLK; base += 256) {
        int i = base + t;
        int v = (i < NBLK) ? blockCnt[i * NB + bkt] : 0;
        s[t] = v;
        __syncthreads();
        for (int off = 1; off < 256; off <<= 1) {
            int x = (t >= off) ? s[t - off] : 0;
            __syncthreads();
            s[t] += x;
            __syncthreads();
        }
        if (i < NBLK) blockBase[i * NB + bkt] = carry + s[t] - v;
        __syncthreads();
        if (t == 0) carry += s[255];
        __syncthreads();
    }
    if (t == 0) bucketTotal[bkt] = carry;
}

// K2b: exclusive scan of bucket totals (NB <= 128)
__global__ void bucket_scan_kernel(const int* __restrict__ bucketTotal,
                                   int* __restrict__ bucketBase, int NB) {
    __shared__ int s[128];
    int t = threadIdx.x;  // 128 threads
    int v = (t < NB) ? bucketTotal[t] : 0;
    s[t] = v;
    __syncthreads();
    for (int off = 1; off < 128; off <<= 1) {
        int x = (t >= off) ? s[t - off] : 0;
        __syncthreads();
        s[t] += x;
        __syncthreads();
    }
    if (t < NB) bucketBase[t] = s[t] - v;
}

// K3: scatter edges into bucket-partitioned temp as contiguous runs.
// payload: (src | dlocal<<16, bits(w fp32))
__global__ __launch_bounds__(256) void bucket_scatter_kernel(const int* __restrict__ idx,
                                                             const float* __restrict__ ew,
                                                             const int* __restrict__ flag,
                                                             const int* __restrict__ bucketBase,
                                                             const int* __restrict__ blockBase,
                                                             int2* __restrict__ temp,
                                                             int E, int NB) {
    __shared__ int base[MAXNB];
    __shared__ int fill[MAXNB];
    int t = threadIdx.x;
    if (t < NB) {
        base[t] = bucketBase[t] + blockBase[blockIdx.x * NB + t];
        fill[t] = 0;
    }
    __syncthreads();
    bool i64 = (*flag) != 0;
    int e0 = blockIdx.x * CHUNK;
    int e1 = min(e0 + CHUNK, E);
    for (int e = e0 + t; e < e1; e += 256) {
        int s_, d;
        if (i64) { s_ = idx[2 * e]; d = idx[2 * (E + e)]; }
        else     { s_ = idx[e];     d = idx[E + e]; }
        float w = ew[e];
        int b = d >> BSH;
        int pos = base[b] + atomicAdd(&fill[b], 1);
        temp[pos] = make_int2(s_ | ((d & (BNODES - 1)) << 16), __float_as_int(w));
    }
}

// K4: per-bucket counting sort into packed CSR + dinv + row (one block/bucket)
// csrw[p] = src(16b) | bf16(w)<<16
__global__ __launch_bounds__(256) void csr_build_kernel(const int2* __restrict__ temp,
                                                        const int* __restrict__ bucketBase,
                                                        unsigned* __restrict__ csrw,
                                                        int* __restrict__ row,
                                                        float* __restrict__ dinv,
                                                        int N, int NB, int E) {
    __shared__ int cnt[BNODES];
    __shared__ float dw[BNODES];
    __shared__ int offs[BNODES];
    __shared__ int sc[256];
    __shared__ int carry;
    int bkt = blockIdx.x;
    int t = threadIdx.x;
    int node0 = bkt << BSH;
    int nn = min(BNODES, N - node0);
    for (int i = t; i < nn; i += 256) { cnt[i] = 0; dw[i] = 0.f; }
    if (t == 0) carry = 0;
    __syncthreads();
    int p0 = bucketBase[bkt];
    int p1 = (bkt + 1 < NB) ? bucketBase[bkt + 1] : E;
    for (int p = p0 + t; p < p1; p += 256) {
        int2 v = temp[p];
        int dl = (v.x >> 16) & (BNODES - 1);
        atomicAdd(&cnt[dl], 1);
        atomicAdd(&dw[dl], __int_as_float(v.y));
    }
    __syncthreads();
    for (int base = 0; base < BNODES; base += 256) {
        int i = base + t;
        int v = (i < nn) ? cnt[i] : 0;
        sc[t] = v;
        __syncthreads();
        for (int off = 1; off < 256; off <<= 1) {
            int x = (t >= off) ? sc[t - off] : 0;
            __syncthreads();
            sc[t] += x;
            __syncthreads();
        }
        offs[i] = carry + sc[t] - v;
        __syncthreads();
        if (t == 0) carry += sc[255];
        __syncthreads();
    }
    for (int i = t; i < nn; i += 256) {
        row[node0 + i] = p0 + offs[i];
        dinv[node0 + i] = rsqrtf(1.f + dw[i]);
    }
    if (bkt == NB - 1 && t == 0) row[N] = E;
    __syncthreads();
    for (int i = t; i < nn; i += 256) cnt[i] = 0;  // reuse as fill
    __syncthreads();
    for (int p = p0 + t; p < p1; p += 256) {
        int2 v = temp[p];
        int dl = (v.x >> 16) & (BNODES - 1);
        int pos = p0 + offs[dl] + atomicAdd(&cnt[dl], 1);
        unsigned wb = (unsigned)v.y;
        wb += 0x7FFFu + ((wb >> 16) & 1u);
        csrw[pos] = ((unsigned)v.x & 0xFFFFu) | (wb & 0xFFFF0000u);
    }
}

// K5: fold dinv[src] into packed bf16 edge weight
__global__ void norm_kernel(unsigned* __restrict__ csrw, const float* __restrict__ dinv, int E) {
    int e = blockIdx.x * BLK + threadIdx.x;
    if (e >= E) return;
    unsigned pe = csrw[e];
    float w = __uint_as_float(pe & 0xFFFF0000u) * dinv[pe & 0xFFFFu];
    unsigned wb = __float_as_uint(w);
    wb += 0x7FFFu + ((wb >> 16) & 1u);
    csrw[e] = (pe & 0xFFFFu) | (wb & 0xFFFF0000u);
}

// ---------------------------------------------------------------------------
// gathers: out[n,o] = bias[o] + dinv[n]*(dinv[n]*h[n,o] + sum w'*h[src,o])
// h is bf16 (ushort); out fp32. 8x-unrolled: padded edge counts (pe=0 -> w=0)
// keep 8 independent row loads in flight per wave.
__global__ __launch_bounds__(256) void gather64_kernel(const int* __restrict__ row,
                                                       const unsigned* __restrict__ csrw,
                                                       const unsigned short* __restrict__ h,
                                                       const float* __restrict__ dinv,
                                                       const float* __restrict__ bias,
                                                       float* __restrict__ out, int N) {
    int wid = (blockIdx.x * 256 + threadIdx.x) >> 6;
    int o = threadIdx.x & 63;
    if (wid >= N) return;
    float di = dinv[wid];
    int p0 = row[wid], p1 = row[wid + 1];
    const unsigned short* hb = h + o;
    float es0 = 0.f, es1 = 0.f;
    for (int p = p0; p < p1; p += 64) {
        int q = p + o;
        unsigned pe = (q < p1) ? csrw[q] : 0u;
        int m = min(64, p1 - p);
        int mp = (m + 7) & ~7;
        for (int j = 0; j < mp; j += 8) {
            unsigned e0 = (unsigned)__shfl((int)pe, j + 0, 64);
            unsigned e1 = (unsigned)__shfl((int)pe, j + 1, 64);
            unsigned e2 = (unsigned)__shfl((int)pe, j + 2, 64);
            unsigned e3 = (unsigned)__shfl((int)pe, j + 3, 64);
            unsigned e4 = (unsigned)__shfl((int)pe, j + 4, 64);
            unsigned e5 = (unsigned)__shfl((int)pe, j + 5, 64);
            unsigned e6 = (unsigned)__shfl((int)pe, j + 6, 64);
            unsigned e7 = (unsigned)__shfl((int)pe, j + 7, 64);
            float h0 = bf2f(hb[(e0 & 0xFFFFu) * 64]);
            float h1 = bf2f(hb[(e1 & 0xFFFFu) * 64]);
            float h2 = bf2f(hb[(e2 & 0xFFFFu) * 64]);
            float h3 = bf2f(hb[(e3 & 0xFFFFu) * 64]);
            float h4 = bf2f(hb[(e4 & 0xFFFFu) * 64]);
            float h5 = bf2f(hb[(e5 & 0xFFFFu) * 64]);
            float h6 = bf2f(hb[(e6 & 0xFFFFu) * 64]);
            float h7 = bf2f(hb[(e7 & 0xFFFFu) * 64]);
            es0 = fmaf(__uint_as_float(e0 & 0xFFFF0000u), h0, es0);
            es1 = fmaf(__uint_as_float(e1 & 0xFFFF0000u), h1, es1);
            es0 = fmaf(__uint_as_float(e2 & 0xFFFF0000u), h2, es0);
            es1 = fmaf(__uint_as_float(e3 & 0xFFFF0000u), h3, es1);
            es0 = fmaf(__uint_as_float(e4 & 0xFFFF0000u), h4, es0);
            es1 = fmaf(__uint_as_float(e5 & 0xFFFF0000u), h5, es1);
            es0 = fmaf(__uint_as_float(e6 & 0xFFFF0000u), h6, es0);
            es1 = fmaf(__uint_as_float(e7 & 0xFFFF0000u), h7, es1);
        }
    }
    out[wid * 64 + o] = bias[o] + di * (di * bf2f(h[(size_t)wid * 64 + o]) + es0 + es1);
}

// WD=32: lanes 0..31 = even edges, 32..63 = odd edges; 4 loads in flight/group
__global__ __launch_bounds__(256) void gather32_kernel(const int* __restrict__ row,
                                                       const unsigned* __restrict__ csrw,
                                                       const unsigned short* __restrict__ h,
                                                       const float* __restrict__ dinv,
                                                       const float* __restrict__ bias,
                                                       float* __restrict__ out, int N) {
    int wid = (blockIdx.x * 256 + threadIdx.x) >> 6;
    int lane = threadIdx.x & 63;
    int o = lane & 31;
    int g = lane >> 5;
    if (wid >= N) return;
    float di = dinv[wid];
    int p0 = row[wid], p1 = row[wid + 1];
    const unsigned short* hb = h + o;
    float es0 = 0.f, es1 = 0.f;
    for (int p = p0; p < p1; p += 64) {
        int q = p + lane;
        unsigned pe = (q < p1) ? csrw[q] : 0u;
        int m = min(64, p1 - p);
        int mp = (m + 7) & ~7;
        for (int j = g; j < mp; j += 8) {
            unsigned e0 = (unsigned)__shfl((int)pe, j + 0, 64);
            unsigned e1 = (unsigned)__shfl((int)pe, j + 2, 64);
            unsigned e2 = (unsigned)__shfl((int)pe, j + 4, 64);
            unsigned e3 = (unsigned)__shfl((int)pe, j + 6, 64);
            float h0 = bf2f(hb[(e0 & 0xFFFFu) * 32]);
            float h1 = bf2f(hb[(e1 & 0xFFFFu) * 32]);
            float h2 = bf2f(hb[(e2 & 0xFFFFu) * 32]);
            float h3 = bf2f(hb[(e3 & 0xFFFFu) * 32]);
            es0 = fmaf(__uint_as_float(e0 & 0xFFFF0000u), h0, es0);
            es1 = fmaf(__uint_as_float(e1 & 0xFFFF0000u), h1, es1);
            es0 = fmaf(__uint_as_float(e2 & 0xFFFF0000u), h2, es0);
            es1 = fmaf(__uint_as_float(e3 & 0xFFFF0000u), h3, es1);
        }
    }
    float es = es0 + es1;
    es += __shfl_down(es, 32, 64);
    if (g == 0) out[wid * 32 + o] = bias[o] + di * (di * bf2f(h[wid * 32 + o]) + es);
}

// WD=2: one edge per lane; h row packed in one uint (2 bf16); 2x unroll
__global__ __launch_bounds__(256) void gather2_kernel(const int* __restrict__ row,
                                                      const unsigned* __restrict__ csrw,
                                                      const unsigned short* __restrict__ h,
                                                      const float* __restrict__ dinv,
                                                      const float* __restrict__ bias,
                                                      float* __restrict__ out, int N) {
    const unsigned* hp = (const unsigned*)h;
    int wid = (blockIdx.x * 256 + threadIdx.x) >> 6;
    int lane = threadIdx.x & 63;
    if (wid >= N) return;
    float di = dinv[wid];
    int p0 = row[wid], p1 = row[wid + 1];
    float a0 = 0.f, a1 = 0.f, b0 = 0.f, b1 = 0.f;
    int p = p0 + lane;
    for (; p + 64 < p1; p += 128) {
        unsigned pe0 = csrw[p];
        unsigned pe1 = csrw[p + 64];
        unsigned hw0 = hp[pe0 & 0xFFFFu];
        unsigned hw1 = hp[pe1 & 0xFFFFu];
        float w0 = __uint_as_float(pe0 & 0xFFFF0000u);
        float w1 = __uint_as_float(pe1 & 0xFFFF0000u);
        a0 = fmaf(w0, __uint_as_float(hw0 << 16), a0);
        a1 = fmaf(w0, __uint_as_float(hw0 & 0xFFFF0000u), a1);
        b0 = fmaf(w1, __uint_as_float(hw1 << 16), b0);
        b1 = fmaf(w1, __uint_as_float(hw1 & 0xFFFF0000u), b1);
    }
    if (p < p1) {
        unsigned pe0 = csrw[p];
        unsigned hw0 = hp[pe0 & 0xFFFFu];
        float w0 = __uint_as_float(pe0 & 0xFFFF0000u);
        a0 = fmaf(w0, __uint_as_float(hw0 << 16), a0);
        a1 = fmaf(w0, __uint_as_float(hw0 & 0xFFFF0000u), a1);
    }
    a0 += b0; a1 += b1;
#pragma unroll
    for (int off = 32; off > 0; off >>= 1) {
        a0 += __shfl_down(a0, off, 64);
        a1 += __shfl_down(a1, off, 64);
    }
    if (lane == 0) {
        unsigned hw = hp[wid];
        out[wid * 2 + 0] = bias[0] + di * (di * __uint_as_float(hw << 16) + a0);
        out[wid * 2 + 1] = bias[1] + di * (di * __uint_as_float(hw & 0xFFFF0000u) + a1);
    }
}

// ---------------------------------------------------------------------------
// Dense kernels: fp32 in, bf16 out
__global__ __launch_bounds__(256) void mm1_kernel(const float* __restrict__ X,
                                                  const float* __restrict__ W,
                                                  unsigned short* __restrict__ Y, int N) {
    __shared__ float Xs[16 * 132];
    __shared__ float4 Ws[128 * 16];
    const float4* Wg = (const float4*)W;
    for (int i = threadIdx.x; i < 128 * 16; i += 256) Ws[i] = Wg[i];
    int row0 = blockIdx.x * 16;
    for (int i = threadIdx.x; i < 16 * 128; i += 256) {
        int r = i >> 7, k = i & 127;
        int row = row0 + r;
        Xs[r * 132 + k] = (row < N) ? X[row * 128 + k] : 0.f;
    }
    __syncthreads();
    int r = threadIdx.x >> 4;
    int c4 = threadIdx.x & 15;
    int row = row0 + r;
    float4 acc = {0.f, 0.f, 0.f, 0.f};
#pragma unroll 4
    for (int k = 0; k < 128; ++k) {
        float xv = Xs[r * 132 + k];
        float4 wv = Ws[k * 16 + c4];
        acc.x = fmaf(xv, wv.x, acc.x);
        acc.y = fmaf(xv, wv.y, acc.y);
        acc.z = fmaf(xv, wv.z, acc.z);
        acc.w = fmaf(xv, wv.w, acc.w);
    }
    if (row < N) {
        ushort4 o;
        o.x = f2bf(acc.x); o.y = f2bf(acc.y); o.z = f2bf(acc.z); o.w = f2bf(acc.w);
        ((ushort4*)Y)[row * 16 + c4] = o;
    }
}

__global__ __launch_bounds__(256) void mm2_kernel(const float* __restrict__ H,
                                                  const float* __restrict__ W,
                                                  unsigned short* __restrict__ Y, int N) {
    __shared__ float Xs[32 * 68];
    __shared__ float4 Ws[64 * 8];
    const float4* Wg = (const float4*)W;
    for (int i = threadIdx.x; i < 64 * 8; i += 256) Ws[i] = Wg[i];
    int row0 = blockIdx.x * 32;
    for (int i = threadIdx.x; i < 32 * 64; i += 256) {
        int r = i >> 6, k = i & 63;
        int row = row0 + r;
        Xs[r * 68 + k] = (row < N) ? fmaxf(H[row * 64 + k], 0.f) : 0.f;
    }
    __syncthreads();
    int r = threadIdx.x >> 3;
    int c4 = threadIdx.x & 7;
    int row = row0 + r;
    float4 acc = {0.f, 0.f, 0.f, 0.f};
#pragma unroll 4
    for (int k = 0; k < 64; ++k) {
        float xv = Xs[r * 68 + k];
        float4 wv = Ws[k * 8 + c4];
        acc.x = fmaf(xv, wv.x, acc.x);
        acc.y = fmaf(xv, wv.y, acc.y);
        acc.z = fmaf(xv, wv.z, acc.z);
        acc.w = fmaf(xv, wv.w, acc.w);
    }
    if (row < N) {
        ushort4 o;
        o.x = f2bf(acc.x); o.y = f2bf(acc.y); o.z = f2bf(acc.z); o.w = f2bf(acc.w);
        ((ushort4*)Y)[row * 8 + c4] = o;
    }
}

__global__ __launch_bounds__(256) void disc_mm_kernel(const float* __restrict__ Z,
                                                      const float* __restrict__ F,
                                                      const float* __restrict__ Wd,
                                                      unsigned short* __restrict__ Y, int N) {
    __shared__ float Ws[256];
    if (threadIdx.x < 256) Ws[threadIdx.x] = Wd[threadIdx.x];
    __syncthreads();
    int n = blockIdx.x * 256 + threadIdx.x;
    if (n >= N) return;
    float zt[32];
#pragma unroll
    for (int j = 0; j < 32; ++j) zt[j] = tanhf(Z[n * 32 + j]);
    float a0 = 0.f, a1 = 0.f;
    const float* fr = F + (size_t)n * 128;
#pragma unroll 4
    for (int c = 0; c < 128; ++c) {
        float xv = zt[c & 31] + fr[c];
        a0 = fmaf(xv, Ws[c * 2 + 0], a0);
        a1 = fmaf(xv, Ws[c * 2 + 1], a1);
    }
    ushort2 o;
    o.x = f2bf(a0); o.y = f2bf(a1);
    ((ushort2*)Y)[n] = o;
}

// ---------------------------------------------------------------------------
// Fallback (atomic scatter) kernels — bf16 h
__global__ void init_deg_kernel(float* __restrict__ deg, int N) {
    int n = blockIdx.x * BLK + threadIdx.x;
    if (n < N) deg[n] = 1.0f;
}

__global__ void edge_deg_kernel(const int* __restrict__ idx, const float* __restrict__ ew,
                                const int* __restrict__ flag, float* __restrict__ deg, int E) {
    int e = blockIdx.x * BLK + threadIdx.x;
    if (e >= E) return;
    int d = (*flag) ? idx[2 * (E + e)] : idx[E + e];
    atomicAdd(&deg[d], ew[e]);
}

__global__ void dinv_kernel(float* __restrict__ deg, int N) {
    int n = blockIdx.x * BLK + threadIdx.x;
    if (n < N) deg[n] = rsqrtf(deg[n]);
}

template <int WD>
__global__ void init_agg_kernel(const unsigned short* __restrict__ h, const float* __restrict__ dinv,
                                const float* __restrict__ bias, float* __restrict__ agg, int N) {
    int i = blockIdx.x * BLK + threadIdx.x;
    if (i >= N * WD) return;
    int n = i / WD, o = i % WD;
    float di = dinv[n];
    agg[i] = bias[o] + di * di * bf2f(h[i]);
}

template <int WD>
__global__ void edge_agg_kernel(const int* __restrict__ idx, const float* __restrict__ ew,
                                const int* __restrict__ flag, const float* __restrict__ dinv,
                                const unsigned short* __restrict__ h, float* __restrict__ agg, int E) {
    int gid = blockIdx.x * BLK + threadIdx.x;
    if (gid >= E * WD) return;
    int e = gid / WD;
    int o = gid % WD;
    int s, d;
    if (*flag) { s = idx[2 * e]; d = idx[2 * (E + e)]; }
    else       { s = idx[e];     d = idx[E + e]; }
    float nrm = dinv[s] * ew[e] * dinv[d];
    atomicAdd(&agg[d * WD + o], nrm * bf2f(h[s * WD + o]));
}

// ---------------------------------------------------------------------------
__global__ void reduce_kernel(const float* __restrict__ dmat, const float* __restrict__ wfc,
                              float* __restrict__ acc, int M) {
    int i = blockIdx.x * BLK + threadIdx.x;
    float v = 0.f;
    if (i < M) v = fmaxf(dmat[i], 0.f) * wfc[i];
#pragma unroll
    for (int off = 32; off > 0; off >>= 1) v += __shfl_down(v, off, 64);
    if ((threadIdx.x & 63) == 0) atomicAdd(acc, v);
}

__global__ void final_kernel(const float* __restrict__ acc, const float* __restrict__ bfc,
                             float* __restrict__ out) {
    float x = *acc + *bfc;
    out[0] = 1.f / (1.f + expf(-x));
}

// ---------------------------------------------------------------------------
extern "C" void kernel_launch(void* const* d_in, const int* in_sizes, int n_in,
                              void* d_out, int out_size, void* d_ws, size_t ws_size,
                              hipStream_t stream) {
    const float* feat = (const float*)d_in[0];
    const int*   eidx = (const int*)d_in[1];
    const float* ew   = (const float*)d_in[2];
    const float* W1   = (const float*)d_in[3];
    const float* b1   = (const float*)d_in[4];
    const float* W2   = (const float*)d_in[5];
    const float* b2   = (const float*)d_in[6];
    const float* Wd   = (const float*)d_in[7];
    const float* bd   = (const float*)d_in[8];
    const float* wfc  = (const float*)d_in[9];
    const float* bfc  = (const float*)d_in[10];

    const int N = in_sizes[0] / 128;  // 50000
    const int E = in_sizes[2];        // 1600000

    const int NB   = (N + BNODES - 1) >> BSH;       // buckets (98)
    const int NBLK = (E + CHUNK - 1) / CHUNK;       // edge blocks (391)

    // workspace layout (units: 4B words)
    float* ws = (float*)d_ws;
    size_t u = 0;
    float* dinv = ws + u; u += N;
    if (u & 1) u++;
    // region1: temp(int2,E) aliases h(bf16, up to N*64 ushorts = N*32 words)
    size_t M1 = ((size_t)N * 32 > (size_t)E * 2) ? (size_t)N * 32 : (size_t)E * 2;
    unsigned short* h = (unsigned short*)(ws + u); int2* temp = (int2*)h; u += M1;
    if (u & 1) u++;
    float* agg = ws + u; u += (size_t)N * 64;
    float* acc = ws + u; u += 1;
    int* flag = (int*)(ws + u); u += 1;
    int* row  = (int*)(ws + u); u += (size_t)N + 1;
    int* bucketTotal = (int*)(ws + u); u += NB;
    int* bucketBase  = (int*)(ws + u); u += NB + 1;
    int* blockCnt    = (int*)(ws + u); u += (size_t)NBLK * NB;
    int* blockBase   = (int*)(ws + u); u += (size_t)NBLK * NB;
    unsigned* csrw   = (unsigned*)(ws + u); u += (size_t)E;
    size_t need = u * 4;

    float* out = (float*)d_out;

    const int gN = (N + BLK - 1) / BLK;
    const int gE = (E + BLK - 1) / BLK;
    const int gW = (N + 3) / 4;  // wave-per-node grids (4 nodes / 256-thr block)

    if (ws_size >= need && N <= 65536 && NB <= MAXNB) {
        // ---- deterministic bucket-sort CSR build ----
        hipLaunchKernelGGL(detect_kernel, dim3(1), dim3(64), 0, stream, eidx, E, flag, acc);
        hipLaunchKernelGGL(bucket_hist_kernel, dim3(NBLK), dim3(256), 0, stream,
                           eidx, flag, blockCnt, E, NB);
        hipLaunchKernelGGL(col_scan_kernel, dim3(NB), dim3(256), 0, stream,
                           blockCnt, blockBase, bucketTotal, NBLK, NB);
        hipLaunchKernelGGL(bucket_scan_kernel, dim3(1), dim3(128), 0, stream,
                           bucketTotal, bucketBase, NB);
        hipLaunchKernelGGL(bucket_scatter_kernel, dim3(NBLK), dim3(256), 0, stream,
                           eidx, ew, flag, bucketBase, blockBase, temp, E, NB);
        hipLaunchKernelGGL(csr_build_kernel, dim3(NB), dim3(256), 0, stream,
                           temp, bucketBase, csrw, row, dinv, N, NB, E);
        hipLaunchKernelGGL(norm_kernel, dim3(gE), dim3(BLK), 0, stream, csrw, dinv, E);

        // ---- layers ----
        hipLaunchKernelGGL(mm1_kernel, dim3((N + 15) / 16), dim3(256), 0, stream, feat, W1, h, N);
        hipLaunchKernelGGL(gather64_kernel, dim3(gW), dim3(256), 0, stream,
                           row, csrw, h, dinv, b1, agg, N);
        hipLaunchKernelGGL(mm2_kernel, dim3((N + 31) / 32), dim3(256), 0, stream, agg, W2, h, N);
        hipLaunchKernelGGL(gather32_kernel, dim3(gW), dim3(256), 0, stream,
                           row, csrw, h, dinv, b2, agg, N);
        hipLaunchKernelGGL(disc_mm_kernel, dim3((N + 255) / 256), dim3(256), 0, stream,
                           agg, feat, Wd, h, N);
        hipLaunchKernelGGL(gather2_kernel, dim3(gW), dim3(256), 0, stream,
                           row, csrw, h, dinv, bd, agg, N);
    } else {
        // ---- fallback: atomic scatter path ----
        hipLaunchKernelGGL(detect_kernel, dim3(1), dim3(64), 0, stream, eidx, E, flag, acc);
        hipLaunchKernelGGL(init_deg_kernel, dim3(gN), dim3(BLK), 0, stream, dinv, N);
        hipLaunchKernelGGL(edge_deg_kernel, dim3(gE), dim3(BLK), 0, stream, eidx, ew, flag, dinv, E);
        hipLaunchKernelGGL(dinv_kernel, dim3(gN), dim3(BLK), 0, stream, dinv, N);

        hipLaunchKernelGGL(mm1_kernel, dim3((N + 15) / 16), dim3(256), 0, stream, feat, W1, h, N);
        hipLaunchKernelGGL((init_agg_kernel<64>), dim3((N * 64 + BLK - 1) / BLK), dim3(BLK), 0, stream,
                           h, dinv, b1, agg, N);
        hipLaunchKernelGGL((edge_agg_kernel<64>), dim3((E / BLK) * 64 + 64), dim3(BLK), 0, stream,
                           eidx, ew, flag, dinv, h, agg, E);
        hipLaunchKernelGGL(mm2_kernel, dim3((N + 31) / 32), dim3(256), 0, stream, agg, W2, h, N);
        hipLaunchKernelGGL((init_agg_kernel<32>), dim3((N * 32 + BLK - 1) / BLK), dim3(BLK), 0, stream,
                           h, dinv, b2, agg, N);
        hipLaunchKernelGGL((edge_agg_kernel<32>), dim3((E / BLK) * 32 + 32), dim3(BLK), 0, stream,
                           eidx, ew, flag, dinv, h, agg, E);
        hipLaunchKernelGGL(disc_mm_kernel, dim3((N + 255) / 256), dim3(256), 0, stream,
                           agg, feat, Wd, h, N);
        hipLaunchKernelGGL((init_agg_kernel<2>), dim3((N * 2 + BLK - 1) / BLK), dim3(BLK), 0, stream,
                           h, dinv, bd, agg, N);
        hipLaunchKernelGGL((edge_agg_kernel<2>), dim3((E * 2 + BLK - 1) / BLK), dim3(BLK), 0, stream,
                           eidx, ew, flag, dinv, h, agg, E);
    }

    hipLaunchKernelGGL(reduce_kernel, dim3((N * 2 + BLK - 1) / BLK), dim3(BLK), 0, stream,
                       agg, wfc, acc, N * 2);
    hipLaunchKernelGGL(final_kernel, dim3(1), dim3(1), 0, stream, acc, bfc, out);
}

// Round 7
// 322.313 us; speedup vs baseline: 2.7140x; 1.0283x over previous
//
#include <hip/hip_runtime.h>
#include <math.h>

#define BLK 256
#define CHUNK 4096
#define BSH 9
#define BNODES 512
#define MAXNB 128

// ---------------------------------------------------------------------------
__device__ __forceinline__ unsigned short f2bf(float f) {
    unsigned u = __float_as_uint(f);
    u += 0x7FFFu + ((u >> 16) & 1u);
    return (unsigned short)(u >> 16);
}
__device__ __forceinline__ float bf2f(unsigned short b) {
    return __uint_as_float(((unsigned)b) << 16);
}

// ---------------------------------------------------------------------------
// Probe int64-vs-int32 edge_index layout; zero the scalar accumulator.
__global__ void detect_kernel(const int* __restrict__ idx, int E,
                              int* __restrict__ flag, float* __restrict__ acc) {
    int t = threadIdx.x;  // 64 threads
    long long j = (long long)t * (E / 64);
    int hi = idx[2 * j + 1];
    unsigned long long b = __ballot(hi != 0);
    if (t == 0) { *flag = (b == 0ULL) ? 1 : 0; *acc = 0.f; }
}

// ---------------------------------------------------------------------------
// K1: per-block bucket histogram (bucket = dst >> BSH), coalesced count rows.
__global__ __launch_bounds__(256) void bucket_hist_kernel(const int* __restrict__ idx,
                                                          const int* __restrict__ flag,
                                                          int* __restrict__ blockCnt,
                                                          int E, int NB) {
    __shared__ int hist[MAXNB];
    int t = threadIdx.x;
    if (t < NB) hist[t] = 0;
    __syncthreads();
    bool i64 = (*flag) != 0;
    int e0 = blockIdx.x * CHUNK;
    int e1 = min(e0 + CHUNK, E);
    for (int e = e0 + t; e < e1; e += 256) {
        int d = i64 ? idx[2 * (E + e)] : idx[E + e];
        atomicAdd(&hist[d >> BSH], 1);
    }
    __syncthreads();
    if (t < NB) blockCnt[blockIdx.x * NB + t] = hist[t];
}

// K2: column-wise exclusive scan over blocks (one block per bucket)
__global__ __launch_bounds__(256) void col_scan_kernel(const int* __restrict__ blockCnt,
                                                       int* __restrict__ blockBase,
                                                       int* __restrict__ bucketTotal,
                                                       int NBLK, int NB) {
    __shared__ int s[256];
    __shared__ int carry;
    int bkt = blockIdx.x;
    int t = threadIdx.x;
    if (t == 0) carry = 0;
    __syncthreads();
    for (int base = 0; base < NBLK; base += 256) {
        int i = base + t;
        int v = (i < NBLK) ? blockCnt[i * NB + bkt] : 0;
        s[t] = v;
        __syncthreads();
        for (int off = 1; off < 256; off <<= 1) {
            int x = (t >= off) ? s[t - off] : 0;
            __syncthreads();
            s[t] += x;
            __syncthreads();
        }
        if (i < NBLK) blockBase[i * NB + bkt] = carry + s[t] - v;
        __syncthreads();
        if (t == 0) carry += s[255];
        __syncthreads();
    }
    if (t == 0) bucketTotal[bkt] = carry;
}

// K2b: exclusive scan of bucket totals (NB <= 128)
__global__ void bucket_scan_kernel(const int* __restrict__ bucketTotal,
                                   int* __restrict__ bucketBase, int NB) {
    __shared__ int s[128];
    int t = threadIdx.x;  // 128 threads
    int v = (t < NB) ? bucketTotal[t] : 0;
    s[t] = v;
    __syncthreads();
    for (int off = 1; off < 128; off <<= 1) {
        int x = (t >= off) ? s[t - off] : 0;
        __syncthreads();
        s[t] += x;
        __syncthreads();
    }
    if (t < NB) bucketBase[t] = s[t] - v;
}

// K3: scatter edges into bucket-partitioned temp as contiguous runs.
// payload: (src | dlocal<<16, bits(w fp32))
__global__ __launch_bounds__(256) void bucket_scatter_kernel(const int* __restrict__ idx,
                                                             const float* __restrict__ ew,
                                                             const int* __restrict__ flag,
                                                             const int* __restrict__ bucketBase,
                                                             const int* __restrict__ blockBase,
                                                             int2* __restrict__ temp,
                                                             int E, int NB) {
    __shared__ int base[MAXNB];
    __shared__ int fill[MAXNB];
    int t = threadIdx.x;
    if (t < NB) {
        base[t] = bucketBase[t] + blockBase[blockIdx.x * NB + t];
        fill[t] = 0;
    }
    __syncthreads();
    bool i64 = (*flag) != 0;
    int e0 = blockIdx.x * CHUNK;
    int e1 = min(e0 + CHUNK, E);
    for (int e = e0 + t; e < e1; e += 256) {
        int s_, d;
        if (i64) { s_ = idx[2 * e]; d = idx[2 * (E + e)]; }
        else     { s_ = idx[e];     d = idx[E + e]; }
        float w = ew[e];
        int b = d >> BSH;
        int pos = base[b] + atomicAdd(&fill[b], 1);
        temp[pos] = make_int2(s_ | ((d & (BNODES - 1)) << 16), __float_as_int(w));
    }
}

// K4: per-bucket counting sort into packed CSR + dinv + row (one block/bucket)
// csrw[p] = src(16b) | bf16(w)<<16.  1024 threads: 16 waves/CU hide the
// L2-latency of the two temp passes (R6: 256 thr -> 3.4% occupancy, 50 us).
__global__ __launch_bounds__(1024) void csr_build_kernel(const int2* __restrict__ temp,
                                                         const int* __restrict__ bucketBase,
                                                         unsigned* __restrict__ csrw,
                                                         int* __restrict__ row,
                                                         float* __restrict__ dinv,
                                                         int N, int NB, int E) {
    __shared__ int cnt[BNODES];
    __shared__ float dw[BNODES];
    __shared__ int offs[BNODES];
    int bkt = blockIdx.x;
    int t = threadIdx.x;
    int node0 = bkt << BSH;
    int nn = min(BNODES, N - node0);
    for (int i = t; i < BNODES; i += 1024) { cnt[i] = 0; dw[i] = 0.f; }
    __syncthreads();
    int p0 = bucketBase[bkt];
    int p1 = (bkt + 1 < NB) ? bucketBase[bkt + 1] : E;
    for (int p = p0 + t; p < p1; p += 1024) {
        int2 v = temp[p];
        int dl = (v.x >> 16) & (BNODES - 1);
        atomicAdd(&cnt[dl], 1);
        atomicAdd(&dw[dl], __int_as_float(v.y));
    }
    __syncthreads();
    // Hillis-Steele inclusive scan of cnt[0..BNODES) on first 512 lanes
    int v = 0;
    if (t < BNODES) { v = cnt[t]; offs[t] = v; }
    __syncthreads();
    for (int off = 1; off < BNODES; off <<= 1) {
        int x = 0;
        if (t < BNODES && t >= off) x = offs[t - off];
        __syncthreads();
        if (t < BNODES) offs[t] += x;
        __syncthreads();
    }
    if (t < BNODES) {
        int excl = offs[t] - v;
        if (t < nn) {
            row[node0 + t] = p0 + excl;
            dinv[node0 + t] = rsqrtf(1.f + dw[t]);
        }
        offs[t] = excl;  // exclusive offsets for pass 2
    }
    if (bkt == NB - 1 && t == 0) row[N] = E;
    __syncthreads();
    for (int i = t; i < BNODES; i += 1024) cnt[i] = 0;  // reuse as fill
    __syncthreads();
    for (int p = p0 + t; p < p1; p += 1024) {
        int2 v2 = temp[p];
        int dl = (v2.x >> 16) & (BNODES - 1);
        int pos = p0 + offs[dl] + atomicAdd(&cnt[dl], 1);
        unsigned wb = (unsigned)v2.y;
        wb += 0x7FFFu + ((wb >> 16) & 1u);
        csrw[pos] = ((unsigned)v2.x & 0xFFFFu) | (wb & 0xFFFF0000u);
    }
}

// K5: fold dinv[src] into packed bf16 edge weight
__global__ void norm_kernel(unsigned* __restrict__ csrw, const float* __restrict__ dinv, int E) {
    int e = blockIdx.x * BLK + threadIdx.x;
    if (e >= E) return;
    unsigned pe = csrw[e];
    float w = __uint_as_float(pe & 0xFFFF0000u) * dinv[pe & 0xFFFFu];
    unsigned wb = __float_as_uint(w);
    wb += 0x7FFFu + ((wb >> 16) & 1u);
    csrw[e] = (pe & 0xFFFFu) | (wb & 0xFFFF0000u);
}

// ---------------------------------------------------------------------------
// gathers: out[n,o] = bias[o] + dinv[n]*(dinv[n]*h[n,o] + sum w'*h[src,o])
// h is bf16 (ushort); out fp32. 8x-unrolled: padded edge counts (pe=0 -> w=0)
// keep 8 independent row loads in flight per wave.
__global__ __launch_bounds__(256) void gather64_kernel(const int* __restrict__ row,
                                                       const unsigned* __restrict__ csrw,
                                                       const unsigned short* __restrict__ h,
                                                       const float* __restrict__ dinv,
                                                       const float* __restrict__ bias,
                                                       float* __restrict__ out, int N) {
    int wid = (blockIdx.x * 256 + threadIdx.x) >> 6;
    int o = threadIdx.x & 63;
    if (wid >= N) return;
    float di = dinv[wid];
    int p0 = row[wid], p1 = row[wid + 1];
    const unsigned short* hb = h + o;
    float es0 = 0.f, es1 = 0.f;
    for (int p = p0; p < p1; p += 64) {
        int q = p + o;
        unsigned pe = (q < p1) ? csrw[q] : 0u;
        int m = min(64, p1 - p);
        int mp = (m + 7) & ~7;
        for (int j = 0; j < mp; j += 8) {
            unsigned e0 = (unsigned)__shfl((int)pe, j + 0, 64);
            unsigned e1 = (unsigned)__shfl((int)pe, j + 1, 64);
            unsigned e2 = (unsigned)__shfl((int)pe, j + 2, 64);
            unsigned e3 = (unsigned)__shfl((int)pe, j + 3, 64);
            unsigned e4 = (unsigned)__shfl((int)pe, j + 4, 64);
            unsigned e5 = (unsigned)__shfl((int)pe, j + 5, 64);
            unsigned e6 = (unsigned)__shfl((int)pe, j + 6, 64);
            unsigned e7 = (unsigned)__shfl((int)pe, j + 7, 64);
            float h0 = bf2f(hb[(e0 & 0xFFFFu) * 64]);
            float h1 = bf2f(hb[(e1 & 0xFFFFu) * 64]);
            float h2 = bf2f(hb[(e2 & 0xFFFFu) * 64]);
            float h3 = bf2f(hb[(e3 & 0xFFFFu) * 64]);
            float h4 = bf2f(hb[(e4 & 0xFFFFu) * 64]);
            float h5 = bf2f(hb[(e5 & 0xFFFFu) * 64]);
            float h6 = bf2f(hb[(e6 & 0xFFFFu) * 64]);
            float h7 = bf2f(hb[(e7 & 0xFFFFu) * 64]);
            es0 = fmaf(__uint_as_float(e0 & 0xFFFF0000u), h0, es0);
            es1 = fmaf(__uint_as_float(e1 & 0xFFFF0000u), h1, es1);
            es0 = fmaf(__uint_as_float(e2 & 0xFFFF0000u), h2, es0);
            es1 = fmaf(__uint_as_float(e3 & 0xFFFF0000u), h3, es1);
            es0 = fmaf(__uint_as_float(e4 & 0xFFFF0000u), h4, es0);
            es1 = fmaf(__uint_as_float(e5 & 0xFFFF0000u), h5, es1);
            es0 = fmaf(__uint_as_float(e6 & 0xFFFF0000u), h6, es0);
            es1 = fmaf(__uint_as_float(e7 & 0xFFFF0000u), h7, es1);
        }
    }
    out[wid * 64 + o] = bias[o] + di * (di * bf2f(h[(size_t)wid * 64 + o]) + es0 + es1);
}

// WD=32: lanes 0..31 = even edges, 32..63 = odd edges; 4 loads in flight/group
__global__ __launch_bounds__(256) void gather32_kernel(const int* __restrict__ row,
                                                       const unsigned* __restrict__ csrw,
                                                       const unsigned short* __restrict__ h,
                                                       const float* __restrict__ dinv,
                                                       const float* __restrict__ bias,
                                                       float* __restrict__ out, int N) {
    int wid = (blockIdx.x * 256 + threadIdx.x) >> 6;
    int lane = threadIdx.x & 63;
    int o = lane & 31;
    int g = lane >> 5;
    if (wid >= N) return;
    float di = dinv[wid];
    int p0 = row[wid], p1 = row[wid + 1];
    const unsigned short* hb = h + o;
    float es0 = 0.f, es1 = 0.f;
    for (int p = p0; p < p1; p += 64) {
        int q = p + lane;
        unsigned pe = (q < p1) ? csrw[q] : 0u;
        int m = min(64, p1 - p);
        int mp = (m + 7) & ~7;
        for (int j = g; j < mp; j += 8) {
            unsigned e0 = (unsigned)__shfl((int)pe, j + 0, 64);
            unsigned e1 = (unsigned)__shfl((int)pe, j + 2, 64);
            unsigned e2 = (unsigned)__shfl((int)pe, j + 4, 64);
            unsigned e3 = (unsigned)__shfl((int)pe, j + 6, 64);
            float h0 = bf2f(hb[(e0 & 0xFFFFu) * 32]);
            float h1 = bf2f(hb[(e1 & 0xFFFFu) * 32]);
            float h2 = bf2f(hb[(e2 & 0xFFFFu) * 32]);
            float h3 = bf2f(hb[(e3 & 0xFFFFu) * 32]);
            es0 = fmaf(__uint_as_float(e0 & 0xFFFF0000u), h0, es0);
            es1 = fmaf(__uint_as_float(e1 & 0xFFFF0000u), h1, es1);
            es0 = fmaf(__uint_as_float(e2 & 0xFFFF0000u), h2, es0);
            es1 = fmaf(__uint_as_float(e3 & 0xFFFF0000u), h3, es1);
        }
    }
    float es = es0 + es1;
    es += __shfl_down(es, 32, 64);
    if (g == 0) out[wid * 32 + o] = bias[o] + di * (di * bf2f(h[wid * 32 + o]) + es);
}

// WD=2: one edge per lane; h row packed in one uint (2 bf16); 2x unroll
__global__ __launch_bounds__(256) void gather2_kernel(const int* __restrict__ row,
                                                      const unsigned* __restrict__ csrw,
                                                      const unsigned short* __restrict__ h,
                                                      const float* __restrict__ dinv,
                                                      const float* __restrict__ bias,
                                                      float* __restrict__ out, int N) {
    const unsigned* hp = (const unsigned*)h;
    int wid = (blockIdx.x * 256 + threadIdx.x) >> 6;
    int lane = threadIdx.x & 63;
    if (wid >= N) return;
    float di = dinv[wid];
    int p0 = row[wid], p1 = row[wid + 1];
    float a0 = 0.f, a1 = 0.f, b0 = 0.f, b1 = 0.f;
    int p = p0 + lane;
    for (; p + 64 < p1; p += 128) {
        unsigned pe0 = csrw[p];
        unsigned pe1 = csrw[p + 64];
        unsigned hw0 = hp[pe0 & 0xFFFFu];
        unsigned hw1 = hp[pe1 & 0xFFFFu];
        float w0 = __uint_as_float(pe0 & 0xFFFF0000u);
        float w1 = __uint_as_float(pe1 & 0xFFFF0000u);
        a0 = fmaf(w0, __uint_as_float(hw0 << 16), a0);
        a1 = fmaf(w0, __uint_as_float(hw0 & 0xFFFF0000u), a1);
        b0 = fmaf(w1, __uint_as_float(hw1 << 16), b0);
        b1 = fmaf(w1, __uint_as_float(hw1 & 0xFFFF0000u), b1);
    }
    if (p < p1) {
        unsigned pe0 = csrw[p];
        unsigned hw0 = hp[pe0 & 0xFFFFu];
        float w0 = __uint_as_float(pe0 & 0xFFFF0000u);
        a0 = fmaf(w0, __uint_as_float(hw0 << 16), a0);
        a1 = fmaf(w0, __uint_as_float(hw0 & 0xFFFF0000u), a1);
    }
    a0 += b0; a1 += b1;
#pragma unroll
    for (int off = 32; off > 0; off >>= 1) {
        a0 += __shfl_down(a0, off, 64);
        a1 += __shfl_down(a1, off, 64);
    }
    if (lane == 0) {
        unsigned hw = hp[wid];
        out[wid * 2 + 0] = bias[0] + di * (di * __uint_as_float(hw << 16) + a0);
        out[wid * 2 + 1] = bias[1] + di * (di * __uint_as_float(hw & 0xFFFF0000u) + a1);
    }
}

// ---------------------------------------------------------------------------
// Dense kernels: fp32 in, bf16 out
__global__ __launch_bounds__(256) void mm1_kernel(const float* __restrict__ X,
                                                  const float* __restrict__ W,
                                                  unsigned short* __restrict__ Y, int N) {
    __shared__ float Xs[16 * 132];
    __shared__ float4 Ws[128 * 16];
    const float4* Wg = (const float4*)W;
    for (int i = threadIdx.x; i < 128 * 16; i += 256) Ws[i] = Wg[i];
    int row0 = blockIdx.x * 16;
    for (int i = threadIdx.x; i < 16 * 128; i += 256) {
        int r = i >> 7, k = i & 127;
        int row = row0 + r;
        Xs[r * 132 + k] = (row < N) ? X[row * 128 + k] : 0.f;
    }
    __syncthreads();
    int r = threadIdx.x >> 4;
    int c4 = threadIdx.x & 15;
    int row = row0 + r;
    float4 acc = {0.f, 0.f, 0.f, 0.f};
#pragma unroll 4
    for (int k = 0; k < 128; ++k) {
        float xv = Xs[r * 132 + k];
        float4 wv = Ws[k * 16 + c4];
        acc.x = fmaf(xv, wv.x, acc.x);
        acc.y = fmaf(xv, wv.y, acc.y);
        acc.z = fmaf(xv, wv.z, acc.z);
        acc.w = fmaf(xv, wv.w, acc.w);
    }
    if (row < N) {
        ushort4 o;
        o.x = f2bf(acc.x); o.y = f2bf(acc.y); o.z = f2bf(acc.z); o.w = f2bf(acc.w);
        ((ushort4*)Y)[row * 16 + c4] = o;
    }
}

__global__ __launch_bounds__(256) void mm2_kernel(const float* __restrict__ H,
                                                  const float* __restrict__ W,
                                                  unsigned short* __restrict__ Y, int N) {
    __shared__ float Xs[32 * 68];
    __shared__ float4 Ws[64 * 8];
    const float4* Wg = (const float4*)W;
    for (int i = threadIdx.x; i < 64 * 8; i += 256) Ws[i] = Wg[i];
    int row0 = blockIdx.x * 32;
    for (int i = threadIdx.x; i < 32 * 64; i += 256) {
        int r = i >> 6, k = i & 63;
        int row = row0 + r;
        Xs[r * 68 + k] = (row < N) ? fmaxf(H[row * 64 + k], 0.f) : 0.f;
    }
    __syncthreads();
    int r = threadIdx.x >> 3;
    int c4 = threadIdx.x & 7;
    int row = row0 + r;
    float4 acc = {0.f, 0.f, 0.f, 0.f};
#pragma unroll 4
    for (int k = 0; k < 64; ++k) {
        float xv = Xs[r * 68 + k];
        float4 wv = Ws[k * 8 + c4];
        acc.x = fmaf(xv, wv.x, acc.x);
        acc.y = fmaf(xv, wv.y, acc.y);
        acc.z = fmaf(xv, wv.z, acc.z);
        acc.w = fmaf(xv, wv.w, acc.w);
    }
    if (row < N) {
        ushort4 o;
        o.x = f2bf(acc.x); o.y = f2bf(acc.y); o.z = f2bf(acc.z); o.w = f2bf(acc.w);
        ((ushort4*)Y)[row * 8 + c4] = o;
    }
}

__global__ __launch_bounds__(256) void disc_mm_kernel(const float* __restrict__ Z,
                                                      const float* __restrict__ F,
                                                      const float* __restrict__ Wd,
                                                      unsigned short* __restrict__ Y, int N) {
    __shared__ float Ws[256];
    if (threadIdx.x < 256) Ws[threadIdx.x] = Wd[threadIdx.x];
    __syncthreads();
    int n = blockIdx.x * 256 + threadIdx.x;
    if (n >= N) return;
    float zt[32];
#pragma unroll
    for (int j = 0; j < 32; ++j) zt[j] = tanhf(Z[n * 32 + j]);
    float a0 = 0.f, a1 = 0.f;
    const float* fr = F + (size_t)n * 128;
#pragma unroll 4
    for (int c = 0; c < 128; ++c) {
        float xv = zt[c & 31] + fr[c];
        a0 = fmaf(xv, Ws[c * 2 + 0], a0);
        a1 = fmaf(xv, Ws[c * 2 + 1], a1);
    }
    ushort2 o;
    o.x = f2bf(a0); o.y = f2bf(a1);
    ((ushort2*)Y)[n] = o;
}

// ---------------------------------------------------------------------------
// Fallback (atomic scatter) kernels — bf16 h
__global__ void init_deg_kernel(float* __restrict__ deg, int N) {
    int n = blockIdx.x * BLK + threadIdx.x;
    if (n < N) deg[n] = 1.0f;
}

__global__ void edge_deg_kernel(const int* __restrict__ idx, const float* __restrict__ ew,
                                const int* __restrict__ flag, float* __restrict__ deg, int E) {
    int e = blockIdx.x * BLK + threadIdx.x;
    if (e >= E) return;
    int d = (*flag) ? idx[2 * (E + e)] : idx[E + e];
    atomicAdd(&deg[d], ew[e]);
}

__global__ void dinv_kernel(float* __restrict__ deg, int N) {
    int n = blockIdx.x * BLK + threadIdx.x;
    if (n < N) deg[n] = rsqrtf(deg[n]);
}

template <int WD>
__global__ void init_agg_kernel(const unsigned short* __restrict__ h, const float* __restrict__ dinv,
                                const float* __restrict__ bias, float* __restrict__ agg, int N) {
    int i = blockIdx.x * BLK + threadIdx.x;
    if (i >= N * WD) return;
    int n = i / WD, o = i % WD;
    float di = dinv[n];
    agg[i] = bias[o] + di * di * bf2f(h[i]);
}

template <int WD>
__global__ void edge_agg_kernel(const int* __restrict__ idx, const float* __restrict__ ew,
                                const int* __restrict__ flag, const float* __restrict__ dinv,
                                const unsigned short* __restrict__ h, float* __restrict__ agg, int E) {
    int gid = blockIdx.x * BLK + threadIdx.x;
    if (gid >= E * WD) return;
    int e = gid / WD;
    int o = gid % WD;
    int s, d;
    if (*flag) { s = idx[2 * e]; d = idx[2 * (E + e)]; }
    else       { s = idx[e];     d = idx[E + e]; }
    float nrm = dinv[s] * ew[e] * dinv[d];
    atomicAdd(&agg[d * WD + o], nrm * bf2f(h[s * WD + o]));
}

// ---------------------------------------------------------------------------
__global__ void reduce_kernel(const float* __restrict__ dmat, const float* __restrict__ wfc,
                              float* __restrict__ acc, int M) {
    int i = blockIdx.x * BLK + threadIdx.x;
    float v = 0.f;
    if (i < M) v = fmaxf(dmat[i], 0.f) * wfc[i];
#pragma unroll
    for (int off = 32; off > 0; off >>= 1) v += __shfl_down(v, off, 64);
    if ((threadIdx.x & 63) == 0) atomicAdd(acc, v);
}

__global__ void final_kernel(const float* __restrict__ acc, const float* __restrict__ bfc,
                             float* __restrict__ out) {
    float x = *acc + *bfc;
    out[0] = 1.f / (1.f + expf(-x));
}

// ---------------------------------------------------------------------------
extern "C" void kernel_launch(void* const* d_in, const int* in_sizes, int n_in,
                              void* d_out, int out_size, void* d_ws, size_t ws_size,
                              hipStream_t stream) {
    const float* feat = (const float*)d_in[0];
    const int*   eidx = (const int*)d_in[1];
    const float* ew   = (const float*)d_in[2];
    const float* W1   = (const float*)d_in[3];
    const float* b1   = (const float*)d_in[4];
    const float* W2   = (const float*)d_in[5];
    const float* b2   = (const float*)d_in[6];
    const float* Wd   = (const float*)d_in[7];
    const float* bd   = (const float*)d_in[8];
    const float* wfc  = (const float*)d_in[9];
    const float* bfc  = (const float*)d_in[10];

    const int N = in_sizes[0] / 128;  // 50000
    const int E = in_sizes[2];        // 1600000

    const int NB   = (N + BNODES - 1) >> BSH;       // buckets (98)
    const int NBLK = (E + CHUNK - 1) / CHUNK;       // edge blocks (391)

    // workspace layout (units: 4B words)
    float* ws = (float*)d_ws;
    size_t u = 0;
    float* dinv = ws + u; u += N;
    if (u & 1) u++;
    // region1: temp(int2,E) aliases h(bf16, up to N*64 ushorts = N*32 words)
    size_t M1 = ((size_t)N * 32 > (size_t)E * 2) ? (size_t)N * 32 : (size_t)E * 2;
    unsigned short* h = (unsigned short*)(ws + u); int2* temp = (int2*)h; u += M1;
    if (u & 1) u++;
    float* agg = ws + u; u += (size_t)N * 64;
    float* acc = ws + u; u += 1;
    int* flag = (int*)(ws + u); u += 1;
    int* row  = (int*)(ws + u); u += (size_t)N + 1;
    int* bucketTotal = (int*)(ws + u); u += NB;
    int* bucketBase  = (int*)(ws + u); u += NB + 1;
    int* blockCnt    = (int*)(ws + u); u += (size_t)NBLK * NB;
    int* blockBase   = (int*)(ws + u); u += (size_t)NBLK * NB;
    unsigned* csrw   = (unsigned*)(ws + u); u += (size_t)E;
    size_t need = u * 4;

    float* out = (float*)d_out;

    const int gN = (N + BLK - 1) / BLK;
    const int gE = (E + BLK - 1) / BLK;
    const int gW = (N + 3) / 4;  // wave-per-node grids (4 nodes / 256-thr block)

    if (ws_size >= need && N <= 65536 && NB <= MAXNB) {
        // ---- deterministic bucket-sort CSR build ----
        hipLaunchKernelGGL(detect_kernel, dim3(1), dim3(64), 0, stream, eidx, E, flag, acc);
        hipLaunchKernelGGL(bucket_hist_kernel, dim3(NBLK), dim3(256), 0, stream,
                           eidx, flag, blockCnt, E, NB);
        hipLaunchKernelGGL(col_scan_kernel, dim3(NB), dim3(256), 0, stream,
                           blockCnt, blockBase, bucketTotal, NBLK, NB);
        hipLaunchKernelGGL(bucket_scan_kernel, dim3(1), dim3(128), 0, stream,
                           bucketTotal, bucketBase, NB);
        hipLaunchKernelGGL(bucket_scatter_kernel, dim3(NBLK), dim3(256), 0, stream,
                           eidx, ew, flag, bucketBase, blockBase, temp, E, NB);
        hipLaunchKernelGGL(csr_build_kernel, dim3(NB), dim3(1024), 0, stream,
                           temp, bucketBase, csrw, row, dinv, N, NB, E);
        hipLaunchKernelGGL(norm_kernel, dim3(gE), dim3(BLK), 0, stream, csrw, dinv, E);

        // ---- layers ----
        hipLaunchKernelGGL(mm1_kernel, dim3((N + 15) / 16), dim3(256), 0, stream, feat, W1, h, N);
        hipLaunchKernelGGL(gather64_kernel, dim3(gW), dim3(256), 0, stream,
                           row, csrw, h, dinv, b1, agg, N);
        hipLaunchKernelGGL(mm2_kernel, dim3((N + 31) / 32), dim3(256), 0, stream, agg, W2, h, N);
        hipLaunchKernelGGL(gather32_kernel, dim3(gW), dim3(256), 0, stream,
                           row, csrw, h, dinv, b2, agg, N);
        hipLaunchKernelGGL(disc_mm_kernel, dim3((N + 255) / 256), dim3(256), 0, stream,
                           agg, feat, Wd, h, N);
        hipLaunchKernelGGL(gather2_kernel, dim3(gW), dim3(256), 0, stream,
                           row, csrw, h, dinv, bd, agg, N);
    } else {
        // ---- fallback: atomic scatter path ----
        hipLaunchKernelGGL(detect_kernel, dim3(1), dim3(64), 0, stream, eidx, E, flag, acc);
        hipLaunchKernelGGL(init_deg_kernel, dim3(gN), dim3(BLK), 0, stream, dinv, N);
        hipLaunchKernelGGL(edge_deg_kernel, dim3(gE), dim3(BLK), 0, stream, eidx, ew, flag, dinv, E);
        hipLaunchKernelGGL(dinv_kernel, dim3(gN), dim3(BLK), 0, stream, dinv, N);

        hipLaunchKernelGGL(mm1_kernel, dim3((N + 15) / 16), dim3(256), 0, stream, feat, W1, h, N);
        hipLaunchKernelGGL((init_agg_kernel<64>), dim3((N * 64 + BLK - 1) / BLK), dim3(BLK), 0, stream,
                           h, dinv, b1, agg, N);
        hipLaunchKernelGGL((edge_agg_kernel<64>), dim3((E / BLK) * 64 + 64), dim3(BLK), 0, stream,
                           eidx, ew, flag, dinv, h, agg, E);
        hipLaunchKernelGGL(mm2_kernel, dim3((N + 31) / 32), dim3(256), 0, stream, agg, W2, h, N);
        hipLaunchKernelGGL((init_agg_kernel<32>), dim3((N * 32 + BLK - 1) / BLK), dim3(BLK), 0, stream,
                           h, dinv, b2, agg, N);
        hipLaunchKernelGGL((edge_agg_kernel<32>), dim3((E / BLK) * 32 + 32), dim3(BLK), 0, stream,
                           eidx, ew, flag, dinv, h, agg, E);
        hipLaunchKernelGGL(disc_mm_kernel, dim3((N + 255) / 256), dim3(256), 0, stream,
                           agg, feat, Wd, h, N);
        hipLaunchKernelGGL((init_agg_kernel<2>), dim3((N * 2 + BLK - 1) / BLK), dim3(BLK), 0, stream,
                           h, dinv, bd, agg, N);
        hipLaunchKernelGGL((edge_agg_kernel<2>), dim3((E * 2 + BLK - 1) / BLK), dim3(BLK), 0, stream,
                           eidx, ew, flag, dinv, h, agg, E);
    }

    hipLaunchKernelGGL(reduce_kernel, dim3((N * 2 + BLK - 1) / BLK), dim3(BLK), 0, stream,
                       agg, wfc, acc, N * 2);
    hipLaunchKernelGGL(final_kernel, dim3(1), dim3(1), 0, stream, acc, bfc, out);
}

// Round 9
// 310.569 us; speedup vs baseline: 2.8167x; 1.0378x over previous
//
#include <hip/hip_runtime.h>
#include <math.h>

#define BLK 256
#define CHUNK 4096
#define BSH 7
#define BNODES 128
#define MAXNB 512

// ---------------------------------------------------------------------------
__device__ __forceinline__ unsigned short f2bf(float f) {
    unsigned u = __float_as_uint(f);
    u += 0x7FFFu + ((u >> 16) & 1u);
    return (unsigned short)(u >> 16);
}
__device__ __forceinline__ float bf2f(unsigned short b) {
    return __uint_as_float(((unsigned)b) << 16);
}

// ---------------------------------------------------------------------------
// Probe int64-vs-int32 edge_index layout; zero the scalar accumulator.
__global__ void detect_kernel(const int* __restrict__ idx, int E,
                              int* __restrict__ flag, float* __restrict__ acc) {
    int t = threadIdx.x;  // 64 threads
    long long j = (long long)t * (E / 64);
    int hi = idx[2 * j + 1];
    unsigned long long b = __ballot(hi != 0);
    if (t == 0) { *flag = (b == 0ULL) ? 1 : 0; *acc = 0.f; }
}

// ---------------------------------------------------------------------------
// K1: per-block bucket histogram (bucket = dst >> BSH), coalesced count rows.
__global__ __launch_bounds__(256) void bucket_hist_kernel(const int* __restrict__ idx,
                                                          const int* __restrict__ flag,
                                                          int* __restrict__ blockCnt,
                                                          int E, int NB) {
    __shared__ int hist[MAXNB];
    int t = threadIdx.x;
    for (int i = t; i < NB; i += 256) hist[i] = 0;
    __syncthreads();
    bool i64 = (*flag) != 0;
    int e0 = blockIdx.x * CHUNK;
    int e1 = min(e0 + CHUNK, E);
    for (int e = e0 + t; e < e1; e += 256) {
        int d = i64 ? idx[2 * (E + e)] : idx[E + e];
        atomicAdd(&hist[d >> BSH], 1);
    }
    __syncthreads();
    for (int i = t; i < NB; i += 256) blockCnt[blockIdx.x * NB + i] = hist[i];
}

// K2: column-wise exclusive scan over blocks (one block per bucket)
__global__ __launch_bounds__(256) void col_scan_kernel(const int* __restrict__ blockCnt,
                                                       int* __restrict__ blockBase,
                                                       int* __restrict__ bucketTotal,
                                                       int NBLK, int NB) {
    __shared__ int s[256];
    __shared__ int carry;
    int bkt = blockIdx.x;
    int t = threadIdx.x;
    if (t == 0) carry = 0;
    __syncthreads();
    for (int base = 0; base < NBLK; base += 256) {
        int i = base + t;
        int v = (i < NBLK) ? blockCnt[i * NB + bkt] : 0;
        s[t] = v;
        __syncthreads();
        for (int off = 1; off < 256; off <<= 1) {
            int x = (t >= off) ? s[t - off] : 0;
            __syncthreads();
            s[t] += x;
            __syncthreads();
        }
        if (i < NBLK) blockBase[i * NB + bkt] = carry + s[t] - v;
        __syncthreads();
        if (t == 0) carry += s[255];
        __syncthreads();
    }
    if (t == 0) bucketTotal[bkt] = carry;
}

// K2b: exclusive scan of bucket totals (NB <= 512), 512 threads
__global__ __launch_bounds__(512) void bucket_scan_kernel(const int* __restrict__ bucketTotal,
                                                          int* __restrict__ bucketBase, int NB) {
    __shared__ int s[512];
    int t = threadIdx.x;
    int v = (t < NB) ? bucketTotal[t] : 0;
    s[t] = v;
    __syncthreads();
    for (int off = 1; off < 512; off <<= 1) {
        int x = (t >= off) ? s[t - off] : 0;
        __syncthreads();
        s[t] += x;
        __syncthreads();
    }
    if (t < NB) bucketBase[t] = s[t] - v;
}

// K3: scatter edges into bucket-partitioned temp as contiguous runs.
// payload: (src | dlocal<<16, bits(w fp32))
__global__ __launch_bounds__(256) void bucket_scatter_kernel(const int* __restrict__ idx,
                                                             const float* __restrict__ ew,
                                                             const int* __restrict__ flag,
                                                             const int* __restrict__ bucketBase,
                                                             const int* __restrict__ blockBase,
                                                             int2* __restrict__ temp,
                                                             int E, int NB) {
    __shared__ int base[MAXNB];
    __shared__ int fill[MAXNB];
    int t = threadIdx.x;
    for (int i = t; i < NB; i += 256) {
        base[i] = bucketBase[i] + blockBase[blockIdx.x * NB + i];
        fill[i] = 0;
    }
    __syncthreads();
    bool i64 = (*flag) != 0;
    int e0 = blockIdx.x * CHUNK;
    int e1 = min(e0 + CHUNK, E);
    for (int e = e0 + t; e < e1; e += 256) {
        int s_, d;
        if (i64) { s_ = idx[2 * e]; d = idx[2 * (E + e)]; }
        else     { s_ = idx[e];     d = idx[E + e]; }
        float w = ew[e];
        int b = d >> BSH;
        int pos = base[b] + atomicAdd(&fill[b], 1);
        temp[pos] = make_int2(s_ | ((d & (BNODES - 1)) << 16), __float_as_int(w));
    }
}

// K4: per-bucket counting sort into packed CSR + dinv + row (one block/bucket)
// csrw[p] = src(16b) | bf16(w)<<16.  391 small buckets spread the LDS-atomic
// load across all CUs (R7: 98 buckets -> per-CU atomic pipe saturated, 43 us).
__global__ __launch_bounds__(512) void csr_build_kernel(const int2* __restrict__ temp,
                                                        const int* __restrict__ bucketBase,
                                                        unsigned* __restrict__ csrw,
                                                        int* __restrict__ row,
                                                        float* __restrict__ dinv,
                                                        int N, int NB, int E) {
    __shared__ int cnt[BNODES];
    __shared__ float dw[BNODES];
    __shared__ int offs[BNODES];
    int bkt = blockIdx.x;
    int t = threadIdx.x;
    int node0 = bkt << BSH;
    int nn = min(BNODES, N - node0);
    if (t < BNODES) { cnt[t] = 0; dw[t] = 0.f; }
    __syncthreads();
    int p0 = bucketBase[bkt];
    int p1 = (bkt + 1 < NB) ? bucketBase[bkt + 1] : E;
    for (int p = p0 + t; p < p1; p += 512) {
        int2 v = temp[p];
        int dl = (v.x >> 16) & (BNODES - 1);
        atomicAdd(&cnt[dl], 1);
        atomicAdd(&dw[dl], __int_as_float(v.y));
    }
    __syncthreads();
    // Hillis-Steele inclusive scan of cnt[0..BNODES) on first BNODES lanes
    int v = 0;
    if (t < BNODES) { v = cnt[t]; offs[t] = v; }
    __syncthreads();
    for (int off = 1; off < BNODES; off <<= 1) {
        int x = 0;
        if (t < BNODES && t >= off) x = offs[t - off];
        __syncthreads();
        if (t < BNODES) offs[t] += x;
        __syncthreads();
    }
    if (t < BNODES) {
        int excl = offs[t] - v;
        if (t < nn) {
            row[node0 + t] = p0 + excl;
            dinv[node0 + t] = rsqrtf(1.f + dw[t]);
        }
        offs[t] = excl;  // exclusive offsets for pass 2
    }
    if (bkt == NB - 1 && t == 0) row[N] = E;
    __syncthreads();
    if (t < BNODES) cnt[t] = 0;  // reuse as fill
    __syncthreads();
    for (int p = p0 + t; p < p1; p += 512) {
        int2 v2 = temp[p];
        int dl = (v2.x >> 16) & (BNODES - 1);
        int pos = p0 + offs[dl] + atomicAdd(&cnt[dl], 1);
        unsigned wb = (unsigned)v2.y;
        wb += 0x7FFFu + ((wb >> 16) & 1u);
        csrw[pos] = ((unsigned)v2.x & 0xFFFFu) | (wb & 0xFFFF0000u);
    }
}

// K5: fold dinv[src] into packed bf16 edge weight
__global__ void norm_kernel(unsigned* __restrict__ csrw, const float* __restrict__ dinv, int E) {
    int e = blockIdx.x * BLK + threadIdx.x;
    if (e >= E) return;
    unsigned pe = csrw[e];
    float w = __uint_as_float(pe & 0xFFFF0000u) * dinv[pe & 0xFFFFu];
    unsigned wb = __float_as_uint(w);
    wb += 0x7FFFu + ((wb >> 16) & 1u);
    csrw[e] = (pe & 0xFFFFu) | (wb & 0xFFFF0000u);
}

// ---------------------------------------------------------------------------
// gathers: out[n,o] = bias[o] + dinv[n]*(dinv[n]*h[n,o] + sum w'*h[src,o])
// h is bf16 (ushort); out fp32. 8x-unrolled: padded edge counts (pe=0 -> w=0)
// keep 8 independent row loads in flight per wave.
__global__ __launch_bounds__(256) void gather64_kernel(const int* __restrict__ row,
                                                       const unsigned* __restrict__ csrw,
                                                       const unsigned short* __restrict__ h,
                                                       const float* __restrict__ dinv,
                                                       const float* __restrict__ bias,
                                                       float* __restrict__ out, int N) {
    int wid = (blockIdx.x * 256 + threadIdx.x) >> 6;
    int o = threadIdx.x & 63;
    if (wid >= N) return;
    float di = dinv[wid];
    int p0 = row[wid], p1 = row[wid + 1];
    const unsigned short* hb = h + o;
    float es0 = 0.f, es1 = 0.f;
    for (int p = p0; p < p1; p += 64) {
        int q = p + o;
        unsigned pe = (q < p1) ? csrw[q] : 0u;
        int m = min(64, p1 - p);
        int mp = (m + 7) & ~7;
        for (int j = 0; j < mp; j += 8) {
            unsigned e0 = (unsigned)__shfl((int)pe, j + 0, 64);
            unsigned e1 = (unsigned)__shfl((int)pe, j + 1, 64);
            unsigned e2 = (unsigned)__shfl((int)pe, j + 2, 64);
            unsigned e3 = (unsigned)__shfl((int)pe, j + 3, 64);
            unsigned e4 = (unsigned)__shfl((int)pe, j + 4, 64);
            unsigned e5 = (unsigned)__shfl((int)pe, j + 5, 64);
            unsigned e6 = (unsigned)__shfl((int)pe, j + 6, 64);
            unsigned e7 = (unsigned)__shfl((int)pe, j + 7, 64);
            float h0 = bf2f(hb[(e0 & 0xFFFFu) * 64]);
            float h1 = bf2f(hb[(e1 & 0xFFFFu) * 64]);
            float h2 = bf2f(hb[(e2 & 0xFFFFu) * 64]);
            float h3 = bf2f(hb[(e3 & 0xFFFFu) * 64]);
            float h4 = bf2f(hb[(e4 & 0xFFFFu) * 64]);
            float h5 = bf2f(hb[(e5 & 0xFFFFu) * 64]);
            float h6 = bf2f(hb[(e6 & 0xFFFFu) * 64]);
            float h7 = bf2f(hb[(e7 & 0xFFFFu) * 64]);
            es0 = fmaf(__uint_as_float(e0 & 0xFFFF0000u), h0, es0);
            es1 = fmaf(__uint_as_float(e1 & 0xFFFF0000u), h1, es1);
            es0 = fmaf(__uint_as_float(e2 & 0xFFFF0000u), h2, es0);
            es1 = fmaf(__uint_as_float(e3 & 0xFFFF0000u), h3, es1);
            es0 = fmaf(__uint_as_float(e4 & 0xFFFF0000u), h4, es0);
            es1 = fmaf(__uint_as_float(e5 & 0xFFFF0000u), h5, es1);
            es0 = fmaf(__uint_as_float(e6 & 0xFFFF0000u), h6, es0);
            es1 = fmaf(__uint_as_float(e7 & 0xFFFF0000u), h7, es1);
        }
    }
    out[wid * 64 + o] = bias[o] + di * (di * bf2f(h[(size_t)wid * 64 + o]) + es0 + es1);
}

// WD=32: lanes 0..31 = even edges, 32..63 = odd edges; 4 loads in flight/group
__global__ __launch_bounds__(256) void gather32_kernel(const int* __restrict__ row,
                                                       const unsigned* __restrict__ csrw,
                                                       const unsigned short* __restrict__ h,
                                                       const float* __restrict__ dinv,
                                                       const float* __restrict__ bias,
                                                       float* __restrict__ out, int N) {
    int wid = (blockIdx.x * 256 + threadIdx.x) >> 6;
    int lane = threadIdx.x & 63;
    int o = lane & 31;
    int g = lane >> 5;
    if (wid >= N) return;
    float di = dinv[wid];
    int p0 = row[wid], p1 = row[wid + 1];
    const unsigned short* hb = h + o;
    float es0 = 0.f, es1 = 0.f;
    for (int p = p0; p < p1; p += 64) {
        int q = p + lane;
        unsigned pe = (q < p1) ? csrw[q] : 0u;
        int m = min(64, p1 - p);
        int mp = (m + 7) & ~7;
        for (int j = g; j < mp; j += 8) {
            unsigned e0 = (unsigned)__shfl((int)pe, j + 0, 64);
            unsigned e1 = (unsigned)__shfl((int)pe, j + 2, 64);
            unsigned e2 = (unsigned)__shfl((int)pe, j + 4, 64);
            unsigned e3 = (unsigned)__shfl((int)pe, j + 6, 64);
            float h0 = bf2f(hb[(e0 & 0xFFFFu) * 32]);
            float h1 = bf2f(hb[(e1 & 0xFFFFu) * 32]);
            float h2 = bf2f(hb[(e2 & 0xFFFFu) * 32]);
            float h3 = bf2f(hb[(e3 & 0xFFFFu) * 32]);
            es0 = fmaf(__uint_as_float(e0 & 0xFFFF0000u), h0, es0);
            es1 = fmaf(__uint_as_float(e1 & 0xFFFF0000u), h1, es1);
            es0 = fmaf(__uint_as_float(e2 & 0xFFFF0000u), h2, es0);
            es1 = fmaf(__uint_as_float(e3 & 0xFFFF0000u), h3, es1);
        }
    }
    float es = es0 + es1;
    es += __shfl_down(es, 32, 64);
    if (g == 0) out[wid * 32 + o] = bias[o] + di * (di * bf2f(h[wid * 32 + o]) + es);
}

// WD=2: one edge per lane; h row packed in one uint (2 bf16); 2x unroll
__global__ __launch_bounds__(256) void gather2_kernel(const int* __restrict__ row,
                                                      const unsigned* __restrict__ csrw,
                                                      const unsigned short* __restrict__ h,
                                                      const float* __restrict__ dinv,
                                                      const float* __restrict__ bias,
                                                      float* __restrict__ out, int N) {
    const unsigned* hp = (const unsigned*)h;
    int wid = (blockIdx.x * 256 + threadIdx.x) >> 6;
    int lane = threadIdx.x & 63;
    if (wid >= N) return;
    float di = dinv[wid];
    int p0 = row[wid], p1 = row[wid + 1];
    float a0 = 0.f, a1 = 0.f, b0 = 0.f, b1 = 0.f;
    int p = p0 + lane;
    for (; p + 64 < p1; p += 128) {
        unsigned pe0 = csrw[p];
        unsigned pe1 = csrw[p + 64];
        unsigned hw0 = hp[pe0 & 0xFFFFu];
        unsigned hw1 = hp[pe1 & 0xFFFFu];
        float w0 = __uint_as_float(pe0 & 0xFFFF0000u);
        float w1 = __uint_as_float(pe1 & 0xFFFF0000u);
        a0 = fmaf(w0, __uint_as_float(hw0 << 16), a0);
        a1 = fmaf(w0, __uint_as_float(hw0 & 0xFFFF0000u), a1);
        b0 = fmaf(w1, __uint_as_float(hw1 << 16), b0);
        b1 = fmaf(w1, __uint_as_float(hw1 & 0xFFFF0000u), b1);
    }
    if (p < p1) {
        unsigned pe0 = csrw[p];
        unsigned hw0 = hp[pe0 & 0xFFFFu];
        float w0 = __uint_as_float(pe0 & 0xFFFF0000u);
        a0 = fmaf(w0, __uint_as_float(hw0 << 16), a0);
        a1 = fmaf(w0, __uint_as_float(hw0 & 0xFFFF0000u), a1);
    }
    a0 += b0; a1 += b1;
#pragma unroll
    for (int off = 32; off > 0; off >>= 1) {
        a0 += __shfl_down(a0, off, 64);
        a1 += __shfl_down(a1, off, 64);
    }
    if (lane == 0) {
        unsigned hw = hp[wid];
        out[wid * 2 + 0] = bias[0] + di * (di * __uint_as_float(hw << 16) + a0);
        out[wid * 2 + 1] = bias[1] + di * (di * __uint_as_float(hw & 0xFFFF0000u) + a1);
    }
}

// ---------------------------------------------------------------------------
// mm1: Y[N,64] = X[N,128] @ W[128,64], bf16 out.
// 32 rows/block, 2 rows/thread register blocking; W staged as packed bf16
// (ds_read_b64) -> 2x flops per LDS cycle vs R7, LDS 33KB -> 4 blocks/CU.
__global__ __launch_bounds__(256) void mm1_kernel(const float* __restrict__ X,
                                                  const float* __restrict__ W,
                                                  unsigned short* __restrict__ Y, int N) {
    __shared__ float Xs[32 * 132];
    __shared__ uint2 Wsb[128 * 16];
    const float4* Wg = (const float4*)W;
    for (int i = threadIdx.x; i < 128 * 16; i += 256) {
        float4 wv = Wg[i];
        unsigned lo = ((unsigned)f2bf(wv.x)) | (((unsigned)f2bf(wv.y)) << 16);
        unsigned hi = ((unsigned)f2bf(wv.z)) | (((unsigned)f2bf(wv.w)) << 16);
        Wsb[i] = make_uint2(lo, hi);
    }
    int row0 = blockIdx.x * 32;
    for (int i = threadIdx.x; i < 32 * 128; i += 256) {
        int r = i >> 7, k = i & 127;
        int rr = row0 + r;
        Xs[r * 132 + k] = (rr < N) ? X[(size_t)rr * 128 + k] : 0.f;
    }
    __syncthreads();
    int r0 = (threadIdx.x >> 4) * 2;
    int c4 = threadIdx.x & 15;
    float4 a0 = {0.f, 0.f, 0.f, 0.f};
    float4 a1 = {0.f, 0.f, 0.f, 0.f};
#pragma unroll 4
    for (int k = 0; k < 128; ++k) {
        float x0 = Xs[r0 * 132 + k];
        float x1 = Xs[(r0 + 1) * 132 + k];
        uint2 wp = Wsb[k * 16 + c4];
        float w0 = __uint_as_float(wp.x << 16);
        float w1 = __uint_as_float(wp.x & 0xFFFF0000u);
        float w2 = __uint_as_float(wp.y << 16);
        float w3 = __uint_as_float(wp.y & 0xFFFF0000u);
        a0.x = fmaf(x0, w0, a0.x); a0.y = fmaf(x0, w1, a0.y);
        a0.z = fmaf(x0, w2, a0.z); a0.w = fmaf(x0, w3, a0.w);
        a1.x = fmaf(x1, w0, a1.x); a1.y = fmaf(x1, w1, a1.y);
        a1.z = fmaf(x1, w2, a1.z); a1.w = fmaf(x1, w3, a1.w);
    }
    int row = row0 + r0;
    if (row < N) {
        ushort4 o;
        o.x = f2bf(a0.x); o.y = f2bf(a0.y); o.z = f2bf(a0.z); o.w = f2bf(a0.w);
        ((ushort4*)Y)[(size_t)row * 16 + c4] = o;
    }
    if (row + 1 < N) {
        ushort4 o;
        o.x = f2bf(a1.x); o.y = f2bf(a1.y); o.z = f2bf(a1.z); o.w = f2bf(a1.w);
        ((ushort4*)Y)[(size_t)(row + 1) * 16 + c4] = o;
    }
}

__global__ __launch_bounds__(256) void mm2_kernel(const float* __restrict__ H,
                                                  const float* __restrict__ W,
                                                  unsigned short* __restrict__ Y, int N) {
    __shared__ float Xs[32 * 68];
    __shared__ float4 Ws[64 * 8];
    const float4* Wg = (const float4*)W;
    for (int i = threadIdx.x; i < 64 * 8; i += 256) Ws[i] = Wg[i];
    int row0 = blockIdx.x * 32;
    for (int i = threadIdx.x; i < 32 * 64; i += 256) {
        int r = i >> 6, k = i & 63;
        int row = row0 + r;
        Xs[r * 68 + k] = (row < N) ? fmaxf(H[row * 64 + k], 0.f) : 0.f;
    }
    __syncthreads();
    int r = threadIdx.x >> 3;
    int c4 = threadIdx.x & 7;
    int row = row0 + r;
    float4 acc = {0.f, 0.f, 0.f, 0.f};
#pragma unroll 4
    for (int k = 0; k < 64; ++k) {
        float xv = Xs[r * 68 + k];
        float4 wv = Ws[k * 8 + c4];
        acc.x = fmaf(xv, wv.x, acc.x);
        acc.y = fmaf(xv, wv.y, acc.y);
        acc.z = fmaf(xv, wv.z, acc.z);
        acc.w = fmaf(xv, wv.w, acc.w);
    }
    if (row < N) {
        ushort4 o;
        o.x = f2bf(acc.x); o.y = f2bf(acc.y); o.z = f2bf(acc.z); o.w = f2bf(acc.w);
        ((ushort4*)Y)[row * 8 + c4] = o;
    }
}

__global__ __launch_bounds__(256) void disc_mm_kernel(const float* __restrict__ Z,
                                                      const float* __restrict__ F,
                                                      const float* __restrict__ Wd,
                                                      unsigned short* __restrict__ Y, int N) {
    __shared__ float Ws[256];
    if (threadIdx.x < 256) Ws[threadIdx.x] = Wd[threadIdx.x];
    __syncthreads();
    int n = blockIdx.x * 256 + threadIdx.x;
    if (n >= N) return;
    float zt[32];
#pragma unroll
    for (int j = 0; j < 32; ++j) zt[j] = tanhf(Z[n * 32 + j]);
    float a0 = 0.f, a1 = 0.f;
    const float* fr = F + (size_t)n * 128;
#pragma unroll 4
    for (int c = 0; c < 128; ++c) {
        float xv = zt[c & 31] + fr[c];
        a0 = fmaf(xv, Ws[c * 2 + 0], a0);
        a1 = fmaf(xv, Ws[c * 2 + 1], a1);
    }
    ushort2 o;
    o.x = f2bf(a0); o.y = f2bf(a1);
    ((ushort2*)Y)[n] = o;
}

// ---------------------------------------------------------------------------
// Fallback (atomic scatter) kernels — bf16 h
__global__ void init_deg_kernel(float* __restrict__ deg, int N) {
    int n = blockIdx.x * BLK + threadIdx.x;
    if (n < N) deg[n] = 1.0f;
}

__global__ void edge_deg_kernel(const int* __restrict__ idx, const float* __restrict__ ew,
                                const int* __restrict__ flag, float* __restrict__ deg, int E) {
    int e = blockIdx.x * BLK + threadIdx.x;
    if (e >= E) return;
    int d = (*flag) ? idx[2 * (E + e)] : idx[E + e];
    atomicAdd(&deg[d], ew[e]);
}

__global__ void dinv_kernel(float* __restrict__ deg, int N) {
    int n = blockIdx.x * BLK + threadIdx.x;
    if (n < N) deg[n] = rsqrtf(deg[n]);
}

template <int WD>
__global__ void init_agg_kernel(const unsigned short* __restrict__ h, const float* __restrict__ dinv,
                                const float* __restrict__ bias, float* __restrict__ agg, int N) {
    int i = blockIdx.x * BLK + threadIdx.x;
    if (i >= N * WD) return;
    int n = i / WD, o = i % WD;
    float di = dinv[n];
    agg[i] = bias[o] + di * di * bf2f(h[i]);
}

template <int WD>
__global__ void edge_agg_kernel(const int* __restrict__ idx, const float* __restrict__ ew,
                                const int* __restrict__ flag, const float* __restrict__ dinv,
                                const unsigned short* __restrict__ h, float* __restrict__ agg, int E) {
    int gid = blockIdx.x * BLK + threadIdx.x;
    if (gid >= E * WD) return;
    int e = gid / WD;
    int o = gid % WD;
    int s, d;
    if (*flag) { s = idx[2 * e]; d = idx[2 * (E + e)]; }
    else       { s = idx[e];     d = idx[E + e]; }
    float nrm = dinv[s] * ew[e] * dinv[d];
    atomicAdd(&agg[d * WD + o], nrm * bf2f(h[s * WD + o]));
}

// ---------------------------------------------------------------------------
__global__ void reduce_kernel(const float* __restrict__ dmat, const float* __restrict__ wfc,
                              float* __restrict__ acc, int M) {
    int i = blockIdx.x * BLK + threadIdx.x;
    float v = 0.f;
    if (i < M) v = fmaxf(dmat[i], 0.f) * wfc[i];
#pragma unroll
    for (int off = 32; off > 0; off >>= 1) v += __shfl_down(v, off, 64);
    if ((threadIdx.x & 63) == 0) atomicAdd(acc, v);
}

__global__ void final_kernel(const float* __restrict__ acc, const float* __restrict__ bfc,
                             float* __restrict__ out) {
    float x = *acc + *bfc;
    out[0] = 1.f / (1.f + expf(-x));
}

// ---------------------------------------------------------------------------
extern "C" void kernel_launch(void* const* d_in, const int* in_sizes, int n_in,
                              void* d_out, int out_size, void* d_ws, size_t ws_size,
                              hipStream_t stream) {
    const float* feat = (const float*)d_in[0];
    const int*   eidx = (const int*)d_in[1];
    const float* ew   = (const float*)d_in[2];
    const float* W1   = (const float*)d_in[3];
    const float* b1   = (const float*)d_in[4];
    const float* W2   = (const float*)d_in[5];
    const float* b2   = (const float*)d_in[6];
    const float* Wd   = (const float*)d_in[7];
    const float* bd   = (const float*)d_in[8];
    const float* wfc  = (const float*)d_in[9];
    const float* bfc  = (const float*)d_in[10];

    const int N = in_sizes[0] / 128;  // 50000
    const int E = in_sizes[2];        // 1600000

    const int NB   = (N + BNODES - 1) >> BSH;       // buckets (391 @ BSH=7)
    const int NBLK = (E + CHUNK - 1) / CHUNK;       // edge blocks (391)

    // workspace layout (units: 4B words)
    float* ws = (float*)d_ws;
    size_t u = 0;
    float* dinv = ws + u; u += N;
    if (u & 1) u++;
    // region1: temp(int2,E) aliases h(bf16, up to N*64 ushorts = N*32 words)
    size_t M1 = ((size_t)N * 32 > (size_t)E * 2) ? (size_t)N * 32 : (size_t)E * 2;
    unsigned short* h = (unsigned short*)(ws + u); int2* temp = (int2*)h; u += M1;
    if (u & 1) u++;
    float* agg = ws + u; u += (size_t)N * 64;
    float* acc = ws + u; u += 1;
    int* flag = (int*)(ws + u); u += 1;
    int* row  = (int*)(ws + u); u += (size_t)N + 1;
    int* bucketTotal = (int*)(ws + u); u += NB;
    int* bucketBase  = (int*)(ws + u); u += NB + 1;
    int* blockCnt    = (int*)(ws + u); u += (size_t)NBLK * NB;
    int* blockBase   = (int*)(ws + u); u += (size_t)NBLK * NB;
    unsigned* csrw   = (unsigned*)(ws + u); u += (size_t)E;
    size_t need = u * 4;

    float* out = (float*)d_out;

    const int gN = (N + BLK - 1) / BLK;
    const int gE = (E + BLK - 1) / BLK;
    const int gW = (N + 3) / 4;  // wave-per-node grids (4 nodes / 256-thr block)

    if (ws_size >= need && N <= 65536 && NB <= MAXNB) {
        // ---- deterministic bucket-sort CSR build ----
        hipLaunchKernelGGL(detect_kernel, dim3(1), dim3(64), 0, stream, eidx, E, flag, acc);
        hipLaunchKernelGGL(bucket_hist_kernel, dim3(NBLK), dim3(256), 0, stream,
                           eidx, flag, blockCnt, E, NB);
        hipLaunchKernelGGL(col_scan_kernel, dim3(NB), dim3(256), 0, stream,
                           blockCnt, blockBase, bucketTotal, NBLK, NB);
        hipLaunchKernelGGL(bucket_scan_kernel, dim3(1), dim3(512), 0, stream,
                           bucketTotal, bucketBase, NB);
        hipLaunchKernelGGL(bucket_scatter_kernel, dim3(NBLK), dim3(256), 0, stream,
                           eidx, ew, flag, bucketBase, blockBase, temp, E, NB);
        hipLaunchKernelGGL(csr_build_kernel, dim3(NB), dim3(512), 0, stream,
                           temp, bucketBase, csrw, row, dinv, N, NB, E);
        hipLaunchKernelGGL(norm_kernel, dim3(gE), dim3(BLK), 0, stream, csrw, dinv, E);

        // ---- layers ----
        hipLaunchKernelGGL(mm1_kernel, dim3((N + 31) / 32), dim3(256), 0, stream, feat, W1, h, N);
        hipLaunchKernelGGL(gather64_kernel, dim3(gW), dim3(256), 0, stream,
                           row, csrw, h, dinv, b1, agg, N);
        hipLaunchKernelGGL(mm2_kernel, dim3((N + 31) / 32), dim3(256), 0, stream, agg, W2, h, N);
        hipLaunchKernelGGL(gather32_kernel, dim3(gW), dim3(256), 0, stream,
                           row, csrw, h, dinv, b2, agg, N);
        hipLaunchKernelGGL(disc_mm_kernel, dim3((N + 255) / 256), dim3(256), 0, stream,
                           agg, feat, Wd, h, N);
        hipLaunchKernelGGL(gather2_kernel, dim3(gW), dim3(256), 0, stream,
                           row, csrw, h, dinv, bd, agg, N);
    } else {
        // ---- fallback: atomic scatter path ----
        hipLaunchKernelGGL(detect_kernel, dim3(1), dim3(64), 0, stream, eidx, E, flag, acc);
        hipLaunchKernelGGL(init_deg_kernel, dim3(gN), dim3(BLK), 0, stream, dinv, N);
        hipLaunchKernelGGL(edge_deg_kernel, dim3(gE), dim3(BLK), 0, stream, eidx, ew, flag, dinv, E);
        hipLaunchKernelGGL(dinv_kernel, dim3(gN), dim3(BLK), 0, stream, dinv, N);

        hipLaunchKernelGGL(mm1_kernel, dim3((N + 31) / 32), dim3(256), 0, stream, feat, W1, h, N);
        hipLaunchKernelGGL((init_agg_kernel<64>), dim3((N * 64 + BLK - 1) / BLK), dim3(BLK), 0, stream,
                           h, dinv, b1, agg, N);
        hipLaunchKernelGGL((edge_agg_kernel<64>), dim3((E / BLK) * 64 + 64), dim3(BLK), 0, stream,
                           eidx, ew, flag, dinv, h, agg, E);
        hipLaunchKernelGGL(mm2_kernel, dim3((N + 31) / 32), dim3(256), 0, stream, agg, W2, h, N);
        hipLaunchKernelGGL((init_agg_kernel<32>), dim3((N * 32 + BLK - 1) / BLK), dim3(BLK), 0, stream,
                           h, dinv, b2, agg, N);
        hipLaunchKernelGGL((edge_agg_kernel<32>), dim3((E / BLK) * 32 + 32), dim3(BLK), 0, stream,
                           eidx, ew, flag, dinv, h, agg, E);
        hipLaunchKernelGGL(disc_mm_kernel, dim3((N + 255) / 256), dim3(256), 0, stream,
                           agg, feat, Wd, h, N);
        hipLaunchKernelGGL((init_agg_kernel<2>), dim3((N * 2 + BLK - 1) / BLK), dim3(BLK), 0, stream,
                           h, dinv, bd, agg, N);
        hipLaunchKernelGGL((edge_agg_kernel<2>), dim3((E * 2 + BLK - 1) / BLK), dim3(BLK), 0, stream,
                           eidx, ew, flag, dinv, h, agg, E);
    }

    hipLaunchKernelGGL(reduce_kernel, dim3((N * 2 + BLK - 1) / BLK), dim3(BLK), 0, stream,
                       agg, wfc, acc, N * 2);
    hipLaunchKernelGGL(final_kernel, dim3(1), dim3(1), 0, stream, acc, bfc, out);
}

// Round 10
// 298.458 us; speedup vs baseline: 2.9310x; 1.0406x over previous
//
#include <hip/hip_runtime.h>
#include <math.h>

#define BLK 256
#define CHUNK 4096
#define BSH 8
#define BNODES 256
#define MAXNB 256

// ---------------------------------------------------------------------------
__device__ __forceinline__ unsigned short f2bf(float f) {
    unsigned u = __float_as_uint(f);
    u += 0x7FFFu + ((u >> 16) & 1u);
    return (unsigned short)(u >> 16);
}
__device__ __forceinline__ float bf2f(unsigned short b) {
    return __uint_as_float(((unsigned)b) << 16);
}

// ---------------------------------------------------------------------------
// Fallback-path probe (CSR path inlines detection); zeroes acc/done.
__global__ void detect_kernel(const int* __restrict__ idx, int E,
                              int* __restrict__ flag, float* __restrict__ acc,
                              int* __restrict__ done) {
    int t = threadIdx.x;  // 64 threads
    long long j = (long long)t * (E / 64);
    int hi = idx[2 * j + 1];
    unsigned long long b = __ballot(hi != 0);
    if (t == 0) { *flag = (b == 0ULL) ? 1 : 0; *acc = 0.f; *done = 0; }
}

// ---------------------------------------------------------------------------
// K1: per-block bucket histogram (bucket = dst >> BSH); i64 detection inlined.
__global__ __launch_bounds__(256) void bucket_hist_kernel(const int* __restrict__ idx,
                                                          int* __restrict__ blockCnt,
                                                          int E, int NB) {
    __shared__ int hist[MAXNB];
    __shared__ int i64s;
    int t = threadIdx.x;
    for (int i = t; i < NB; i += 256) hist[i] = 0;
    if (t < 64) {  // wave 0 samples global positions (same for all blocks; L2-hot)
        long long j = (long long)t * (E / 64);
        int hi = idx[2 * j + 1];
        unsigned long long b = __ballot(hi != 0);
        if (t == 0) i64s = (b == 0ULL) ? 1 : 0;
    }
    __syncthreads();
    bool i64 = i64s != 0;
    int e0 = blockIdx.x * CHUNK;
    int e1 = min(e0 + CHUNK, E);
    for (int e = e0 + t; e < e1; e += 256) {
        int d = i64 ? idx[2 * (E + e)] : idx[E + e];
        atomicAdd(&hist[d >> BSH], 1);
    }
    __syncthreads();
    for (int i = t; i < NB; i += 256) blockCnt[blockIdx.x * NB + i] = hist[i];
}

// K2: column-wise exclusive scan over blocks (one block per bucket)
__global__ __launch_bounds__(256) void col_scan_kernel(const int* __restrict__ blockCnt,
                                                       int* __restrict__ blockBase,
                                                       int* __restrict__ bucketTotal,
                                                       int NBLK, int NB) {
    __shared__ int s[256];
    __shared__ int carry;
    int bkt = blockIdx.x;
    int t = threadIdx.x;
    if (t == 0) carry = 0;
    __syncthreads();
    for (int base = 0; base < NBLK; base += 256) {
        int i = base + t;
        int v = (i < NBLK) ? blockCnt[i * NB + bkt] : 0;
        s[t] = v;
        __syncthreads();
        for (int off = 1; off < 256; off <<= 1) {
            int x = (t >= off) ? s[t - off] : 0;
            __syncthreads();
            s[t] += x;
            __syncthreads();
        }
        if (i < NBLK) blockBase[i * NB + bkt] = carry + s[t] - v;
        __syncthreads();
        if (t == 0) carry += s[255];
        __syncthreads();
    }
    if (t == 0) bucketTotal[bkt] = carry;
}

// K2b: exclusive scan of bucket totals (NB <= 256); also zeroes acc/done.
__global__ __launch_bounds__(256) void bucket_scan_kernel(const int* __restrict__ bucketTotal,
                                                          int* __restrict__ bucketBase, int NB,
                                                          float* __restrict__ acc,
                                                          int* __restrict__ done) {
    __shared__ int s[256];
    int t = threadIdx.x;
    if (t == 0) { *acc = 0.f; *done = 0; }
    int v = (t < NB) ? bucketTotal[t] : 0;
    s[t] = v;
    __syncthreads();
    for (int off = 1; off < 256; off <<= 1) {
        int x = (t >= off) ? s[t - off] : 0;
        __syncthreads();
        s[t] += x;
        __syncthreads();
    }
    if (t < NB) bucketBase[t] = s[t] - v;
}

// K3: scatter edges into bucket-partitioned temp as contiguous runs.
// payload: (src | dlocal<<16, bits(w fp32)); i64 detection inlined.
__global__ __launch_bounds__(256) void bucket_scatter_kernel(const int* __restrict__ idx,
                                                             const float* __restrict__ ew,
                                                             const int* __restrict__ bucketBase,
                                                             const int* __restrict__ blockBase,
                                                             int2* __restrict__ temp,
                                                             int E, int NB) {
    __shared__ int base[MAXNB];
    __shared__ int fill[MAXNB];
    __shared__ int i64s;
    int t = threadIdx.x;
    for (int i = t; i < NB; i += 256) {
        base[i] = bucketBase[i] + blockBase[blockIdx.x * NB + i];
        fill[i] = 0;
    }
    if (t < 64) {
        long long j = (long long)t * (E / 64);
        int hi = idx[2 * j + 1];
        unsigned long long b = __ballot(hi != 0);
        if (t == 0) i64s = (b == 0ULL) ? 1 : 0;
    }
    __syncthreads();
    bool i64 = i64s != 0;
    int e0 = blockIdx.x * CHUNK;
    int e1 = min(e0 + CHUNK, E);
    for (int e = e0 + t; e < e1; e += 256) {
        int s_, d;
        if (i64) { s_ = idx[2 * e]; d = idx[2 * (E + e)]; }
        else     { s_ = idx[e];     d = idx[E + e]; }
        float w = ew[e];
        int b = d >> BSH;
        int pos = base[b] + atomicAdd(&fill[b], 1);
        temp[pos] = make_int2(s_ | ((d & (BNODES - 1)) << 16), __float_as_int(w));
    }
}

// K4: per-bucket counting sort into packed CSR + dinv + row (one block/bucket)
// csrw[p] = src(16b) | bf16(w)<<16.
__global__ __launch_bounds__(512) void csr_build_kernel(const int2* __restrict__ temp,
                                                        const int* __restrict__ bucketBase,
                                                        unsigned* __restrict__ csrw,
                                                        int* __restrict__ row,
                                                        float* __restrict__ dinv,
                                                        int N, int NB, int E) {
    __shared__ int cnt[BNODES];
    __shared__ float dw[BNODES];
    __shared__ int offs[BNODES];
    int bkt = blockIdx.x;
    int t = threadIdx.x;
    int node0 = bkt << BSH;
    int nn = min(BNODES, N - node0);
    if (t < BNODES) { cnt[t] = 0; dw[t] = 0.f; }
    __syncthreads();
    int p0 = bucketBase[bkt];
    int p1 = (bkt + 1 < NB) ? bucketBase[bkt + 1] : E;
    for (int p = p0 + t; p < p1; p += 512) {
        int2 v = temp[p];
        int dl = (v.x >> 16) & (BNODES - 1);
        atomicAdd(&cnt[dl], 1);
        atomicAdd(&dw[dl], __int_as_float(v.y));
    }
    __syncthreads();
    // Hillis-Steele inclusive scan of cnt[0..BNODES) on first BNODES lanes
    int v = 0;
    if (t < BNODES) { v = cnt[t]; offs[t] = v; }
    __syncthreads();
    for (int off = 1; off < BNODES; off <<= 1) {
        int x = 0;
        if (t < BNODES && t >= off) x = offs[t - off];
        __syncthreads();
        if (t < BNODES) offs[t] += x;
        __syncthreads();
    }
    if (t < BNODES) {
        int excl = offs[t] - v;
        if (t < nn) {
            row[node0 + t] = p0 + excl;
            dinv[node0 + t] = rsqrtf(1.f + dw[t]);
        }
        offs[t] = excl;  // exclusive offsets for pass 2
    }
    if (bkt == NB - 1 && t == 0) row[N] = E;
    __syncthreads();
    if (t < BNODES) cnt[t] = 0;  // reuse as fill
    __syncthreads();
    for (int p = p0 + t; p < p1; p += 512) {
        int2 v2 = temp[p];
        int dl = (v2.x >> 16) & (BNODES - 1);
        int pos = p0 + offs[dl] + atomicAdd(&cnt[dl], 1);
        unsigned wb = (unsigned)v2.y;
        wb += 0x7FFFu + ((wb >> 16) & 1u);
        csrw[pos] = ((unsigned)v2.x & 0xFFFFu) | (wb & 0xFFFF0000u);
    }
}

// K5: fold dinv[src] into packed bf16 edge weight
__global__ void norm_kernel(unsigned* __restrict__ csrw, const float* __restrict__ dinv, int E) {
    int e = blockIdx.x * BLK + threadIdx.x;
    if (e >= E) return;
    unsigned pe = csrw[e];
    float w = __uint_as_float(pe & 0xFFFF0000u) * dinv[pe & 0xFFFFu];
    unsigned wb = __float_as_uint(w);
    wb += 0x7FFFu + ((wb >> 16) & 1u);
    csrw[e] = (pe & 0xFFFFu) | (wb & 0xFFFF0000u);
}

// ---------------------------------------------------------------------------
// gathers: out[n,o] = bias[o] + dinv[n]*(dinv[n]*h[n,o] + sum w'*h[src,o])
// h is bf16 (ushort); out fp32. 16x-unrolled: padded edge counts (pe=0 -> w=0)
// keep 16 independent row loads in flight per wave.
__global__ __launch_bounds__(256) void gather64_kernel(const int* __restrict__ row,
                                                       const unsigned* __restrict__ csrw,
                                                       const unsigned short* __restrict__ h,
                                                       const float* __restrict__ dinv,
                                                       const float* __restrict__ bias,
                                                       float* __restrict__ out, int N) {
    int wid = (blockIdx.x * 256 + threadIdx.x) >> 6;
    int o = threadIdx.x & 63;
    if (wid >= N) return;
    float di = dinv[wid];
    int p0 = row[wid], p1 = row[wid + 1];
    const unsigned short* hb = h + o;
    float es[4] = {0.f, 0.f, 0.f, 0.f};
    for (int p = p0; p < p1; p += 64) {
        int q = p + o;
        unsigned pe = (q < p1) ? csrw[q] : 0u;
        int m = min(64, p1 - p);
        int mp = (m + 15) & ~15;
        for (int j = 0; j < mp; j += 16) {
            unsigned ee[16];
            float hh[16];
#pragma unroll
            for (int u = 0; u < 16; ++u) ee[u] = (unsigned)__shfl((int)pe, j + u, 64);
#pragma unroll
            for (int u = 0; u < 16; ++u) hh[u] = bf2f(hb[(ee[u] & 0xFFFFu) * 64]);
#pragma unroll
            for (int u = 0; u < 16; ++u)
                es[u & 3] = fmaf(__uint_as_float(ee[u] & 0xFFFF0000u), hh[u], es[u & 3]);
        }
    }
    float e01 = es[0] + es[1], e23 = es[2] + es[3];
    out[wid * 64 + o] = bias[o] + di * (di * bf2f(h[(size_t)wid * 64 + o]) + e01 + e23);
}

// WD=32: lanes 0..31 = even edges, 32..63 = odd edges; 8 loads in flight/group
__global__ __launch_bounds__(256) void gather32_kernel(const int* __restrict__ row,
                                                       const unsigned* __restrict__ csrw,
                                                       const unsigned short* __restrict__ h,
                                                       const float* __restrict__ dinv,
                                                       const float* __restrict__ bias,
                                                       float* __restrict__ out, int N) {
    int wid = (blockIdx.x * 256 + threadIdx.x) >> 6;
    int lane = threadIdx.x & 63;
    int o = lane & 31;
    int g = lane >> 5;
    if (wid >= N) return;
    float di = dinv[wid];
    int p0 = row[wid], p1 = row[wid + 1];
    const unsigned short* hb = h + o;
    float es[4] = {0.f, 0.f, 0.f, 0.f};
    for (int p = p0; p < p1; p += 64) {
        int q = p + lane;
        unsigned pe = (q < p1) ? csrw[q] : 0u;
        int m = min(64, p1 - p);
        int mp = (m + 15) & ~15;
        for (int j = g; j < mp; j += 16) {
            unsigned ee[8];
            float hh[8];
#pragma unroll
            for (int u = 0; u < 8; ++u) ee[u] = (unsigned)__shfl((int)pe, j + 2 * u, 64);
#pragma unroll
            for (int u = 0; u < 8; ++u) hh[u] = bf2f(hb[(ee[u] & 0xFFFFu) * 32]);
#pragma unroll
            for (int u = 0; u < 8; ++u)
                es[u & 3] = fmaf(__uint_as_float(ee[u] & 0xFFFF0000u), hh[u], es[u & 3]);
        }
    }
    float es_t = (es[0] + es[1]) + (es[2] + es[3]);
    es_t += __shfl_down(es_t, 32, 64);
    if (g == 0) out[wid * 32 + o] = bias[o] + di * (di * bf2f(h[wid * 32 + o]) + es_t);
}

// WD=2: one edge per lane; h row packed in one uint (2 bf16); 2x unroll
__global__ __launch_bounds__(256) void gather2_kernel(const int* __restrict__ row,
                                                      const unsigned* __restrict__ csrw,
                                                      const unsigned short* __restrict__ h,
                                                      const float* __restrict__ dinv,
                                                      const float* __restrict__ bias,
                                                      float* __restrict__ out, int N) {
    const unsigned* hp = (const unsigned*)h;
    int wid = (blockIdx.x * 256 + threadIdx.x) >> 6;
    int lane = threadIdx.x & 63;
    if (wid >= N) return;
    float di = dinv[wid];
    int p0 = row[wid], p1 = row[wid + 1];
    float a0 = 0.f, a1 = 0.f, b0 = 0.f, b1 = 0.f;
    int p = p0 + lane;
    for (; p + 64 < p1; p += 128) {
        unsigned pe0 = csrw[p];
        unsigned pe1 = csrw[p + 64];
        unsigned hw0 = hp[pe0 & 0xFFFFu];
        unsigned hw1 = hp[pe1 & 0xFFFFu];
        float w0 = __uint_as_float(pe0 & 0xFFFF0000u);
        float w1 = __uint_as_float(pe1 & 0xFFFF0000u);
        a0 = fmaf(w0, __uint_as_float(hw0 << 16), a0);
        a1 = fmaf(w0, __uint_as_float(hw0 & 0xFFFF0000u), a1);
        b0 = fmaf(w1, __uint_as_float(hw1 << 16), b0);
        b1 = fmaf(w1, __uint_as_float(hw1 & 0xFFFF0000u), b1);
    }
    if (p < p1) {
        unsigned pe0 = csrw[p];
        unsigned hw0 = hp[pe0 & 0xFFFFu];
        float w0 = __uint_as_float(pe0 & 0xFFFF0000u);
        a0 = fmaf(w0, __uint_as_float(hw0 << 16), a0);
        a1 = fmaf(w0, __uint_as_float(hw0 & 0xFFFF0000u), a1);
    }
    a0 += b0; a1 += b1;
#pragma unroll
    for (int off = 32; off > 0; off >>= 1) {
        a0 += __shfl_down(a0, off, 64);
        a1 += __shfl_down(a1, off, 64);
    }
    if (lane == 0) {
        unsigned hw = hp[wid];
        out[wid * 2 + 0] = bias[0] + di * (di * __uint_as_float(hw << 16) + a0);
        out[wid * 2 + 1] = bias[1] + di * (di * __uint_as_float(hw & 0xFFFF0000u) + a1);
    }
}

// ---------------------------------------------------------------------------
// mm1: Y[N,64] = X[N,128] @ W[128,64], bf16 out.
// 32 rows/block, 2 rows/thread register blocking; W staged as packed bf16.
__global__ __launch_bounds__(256) void mm1_kernel(const float* __restrict__ X,
                                                  const float* __restrict__ W,
                                                  unsigned short* __restrict__ Y, int N) {
    __shared__ float Xs[32 * 132];
    __shared__ uint2 Wsb[128 * 16];
    const float4* Wg = (const float4*)W;
    for (int i = threadIdx.x; i < 128 * 16; i += 256) {
        float4 wv = Wg[i];
        unsigned lo = ((unsigned)f2bf(wv.x)) | (((unsigned)f2bf(wv.y)) << 16);
        unsigned hi = ((unsigned)f2bf(wv.z)) | (((unsigned)f2bf(wv.w)) << 16);
        Wsb[i] = make_uint2(lo, hi);
    }
    int row0 = blockIdx.x * 32;
    for (int i = threadIdx.x; i < 32 * 128; i += 256) {
        int r = i >> 7, k = i & 127;
        int rr = row0 + r;
        Xs[r * 132 + k] = (rr < N) ? X[(size_t)rr * 128 + k] : 0.f;
    }
    __syncthreads();
    int r0 = (threadIdx.x >> 4) * 2;
    int c4 = threadIdx.x & 15;
    float4 a0 = {0.f, 0.f, 0.f, 0.f};
    float4 a1 = {0.f, 0.f, 0.f, 0.f};
#pragma unroll 4
    for (int k = 0; k < 128; ++k) {
        float x0 = Xs[r0 * 132 + k];
        float x1 = Xs[(r0 + 1) * 132 + k];
        uint2 wp = Wsb[k * 16 + c4];
        float w0 = __uint_as_float(wp.x << 16);
        float w1 = __uint_as_float(wp.x & 0xFFFF0000u);
        float w2 = __uint_as_float(wp.y << 16);
        float w3 = __uint_as_float(wp.y & 0xFFFF0000u);
        a0.x = fmaf(x0, w0, a0.x); a0.y = fmaf(x0, w1, a0.y);
        a0.z = fmaf(x0, w2, a0.z); a0.w = fmaf(x0, w3, a0.w);
        a1.x = fmaf(x1, w0, a1.x); a1.y = fmaf(x1, w1, a1.y);
        a1.z = fmaf(x1, w2, a1.z); a1.w = fmaf(x1, w3, a1.w);
    }
    int row = row0 + r0;
    if (row < N) {
        ushort4 o;
        o.x = f2bf(a0.x); o.y = f2bf(a0.y); o.z = f2bf(a0.z); o.w = f2bf(a0.w);
        ((ushort4*)Y)[(size_t)row * 16 + c4] = o;
    }
    if (row + 1 < N) {
        ushort4 o;
        o.x = f2bf(a1.x); o.y = f2bf(a1.y); o.z = f2bf(a1.z); o.w = f2bf(a1.w);
        ((ushort4*)Y)[(size_t)(row + 1) * 16 + c4] = o;
    }
}

__global__ __launch_bounds__(256) void mm2_kernel(const float* __restrict__ H,
                                                  const float* __restrict__ W,
                                                  unsigned short* __restrict__ Y, int N) {
    __shared__ float Xs[32 * 68];
    __shared__ float4 Ws[64 * 8];
    const float4* Wg = (const float4*)W;
    for (int i = threadIdx.x; i < 64 * 8; i += 256) Ws[i] = Wg[i];
    int row0 = blockIdx.x * 32;
    for (int i = threadIdx.x; i < 32 * 64; i += 256) {
        int r = i >> 6, k = i & 63;
        int row = row0 + r;
        Xs[r * 68 + k] = (row < N) ? fmaxf(H[row * 64 + k], 0.f) : 0.f;
    }
    __syncthreads();
    int r = threadIdx.x >> 3;
    int c4 = threadIdx.x & 7;
    int row = row0 + r;
    float4 acc = {0.f, 0.f, 0.f, 0.f};
#pragma unroll 4
    for (int k = 0; k < 64; ++k) {
        float xv = Xs[r * 68 + k];
        float4 wv = Ws[k * 8 + c4];
        acc.x = fmaf(xv, wv.x, acc.x);
        acc.y = fmaf(xv, wv.y, acc.y);
        acc.z = fmaf(xv, wv.z, acc.z);
        acc.w = fmaf(xv, wv.w, acc.w);
    }
    if (row < N) {
        ushort4 o;
        o.x = f2bf(acc.x); o.y = f2bf(acc.y); o.z = f2bf(acc.z); o.w = f2bf(acc.w);
        ((ushort4*)Y)[row * 8 + c4] = o;
    }
}

__global__ __launch_bounds__(256) void disc_mm_kernel(const float* __restrict__ Z,
                                                      const float* __restrict__ F,
                                                      const float* __restrict__ Wd,
                                                      unsigned short* __restrict__ Y, int N) {
    __shared__ float Ws[256];
    if (threadIdx.x < 256) Ws[threadIdx.x] = Wd[threadIdx.x];
    __syncthreads();
    int n = blockIdx.x * 256 + threadIdx.x;
    if (n >= N) return;
    float zt[32];
#pragma unroll
    for (int j = 0; j < 32; ++j) zt[j] = tanhf(Z[n * 32 + j]);
    float a0 = 0.f, a1 = 0.f;
    const float* fr = F + (size_t)n * 128;
#pragma unroll 4
    for (int c = 0; c < 128; ++c) {
        float xv = zt[c & 31] + fr[c];
        a0 = fmaf(xv, Ws[c * 2 + 0], a0);
        a1 = fmaf(xv, Ws[c * 2 + 1], a1);
    }
    ushort2 o;
    o.x = f2bf(a0); o.y = f2bf(a1);
    ((ushort2*)Y)[n] = o;
}

// ---------------------------------------------------------------------------
// Fallback (atomic scatter) kernels — bf16 h
__global__ void init_deg_kernel(float* __restrict__ deg, int N) {
    int n = blockIdx.x * BLK + threadIdx.x;
    if (n < N) deg[n] = 1.0f;
}

__global__ void edge_deg_kernel(const int* __restrict__ idx, const float* __restrict__ ew,
                                const int* __restrict__ flag, float* __restrict__ deg, int E) {
    int e = blockIdx.x * BLK + threadIdx.x;
    if (e >= E) return;
    int d = (*flag) ? idx[2 * (E + e)] : idx[E + e];
    atomicAdd(&deg[d], ew[e]);
}

__global__ void dinv_kernel(float* __restrict__ deg, int N) {
    int n = blockIdx.x * BLK + threadIdx.x;
    if (n < N) deg[n] = rsqrtf(deg[n]);
}

template <int WD>
__global__ void init_agg_kernel(const unsigned short* __restrict__ h, const float* __restrict__ dinv,
                                const float* __restrict__ bias, float* __restrict__ agg, int N) {
    int i = blockIdx.x * BLK + threadIdx.x;
    if (i >= N * WD) return;
    int n = i / WD, o = i % WD;
    float di = dinv[n];
    agg[i] = bias[o] + di * di * bf2f(h[i]);
}

template <int WD>
__global__ void edge_agg_kernel(const int* __restrict__ idx, const float* __restrict__ ew,
                                const int* __restrict__ flag, const float* __restrict__ dinv,
                                const unsigned short* __restrict__ h, float* __restrict__ agg, int E) {
    int gid = blockIdx.x * BLK + threadIdx.x;
    if (gid >= E * WD) return;
    int e = gid / WD;
    int o = gid % WD;
    int s, d;
    if (*flag) { s = idx[2 * e]; d = idx[2 * (E + e)]; }
    else       { s = idx[e];     d = idx[E + e]; }
    float nrm = dinv[s] * ew[e] * dinv[d];
    atomicAdd(&agg[d * WD + o], nrm * bf2f(h[s * WD + o]));
}

// ---------------------------------------------------------------------------
// logit partial sums + last-block sigmoid (acc/done pre-zeroed upstream)
__global__ void reduce_final_kernel(const float* __restrict__ dmat, const float* __restrict__ wfc,
                                    float* __restrict__ acc, int* __restrict__ done,
                                    const float* __restrict__ bfc, float* __restrict__ out,
                                    int M, int nblk) {
    int i = blockIdx.x * BLK + threadIdx.x;
    float v = 0.f;
    if (i < M) v = fmaxf(dmat[i], 0.f) * wfc[i];
#pragma unroll
    for (int off = 32; off > 0; off >>= 1) v += __shfl_down(v, off, 64);
    if ((threadIdx.x & 63) == 0) atomicAdd(acc, v);
    __syncthreads();
    if (threadIdx.x == 0) {
        __threadfence();
        int old = atomicAdd(done, 1);
        if (old == nblk - 1) {
            float x = atomicAdd(acc, 0.f) + *bfc;
            out[0] = 1.f / (1.f + expf(-x));
        }
    }
}

// ---------------------------------------------------------------------------
extern "C" void kernel_launch(void* const* d_in, const int* in_sizes, int n_in,
                              void* d_out, int out_size, void* d_ws, size_t ws_size,
                              hipStream_t stream) {
    const float* feat = (const float*)d_in[0];
    const int*   eidx = (const int*)d_in[1];
    const float* ew   = (const float*)d_in[2];
    const float* W1   = (const float*)d_in[3];
    const float* b1   = (const float*)d_in[4];
    const float* W2   = (const float*)d_in[5];
    const float* b2   = (const float*)d_in[6];
    const float* Wd   = (const float*)d_in[7];
    const float* bd   = (const float*)d_in[8];
    const float* wfc  = (const float*)d_in[9];
    const float* bfc  = (const float*)d_in[10];

    const int N = in_sizes[0] / 128;  // 50000
    const int E = in_sizes[2];        // 1600000

    const int NB   = (N + BNODES - 1) >> BSH;       // buckets (196 @ BSH=8)
    const int NBLK = (E + CHUNK - 1) / CHUNK;       // edge blocks (391)

    // workspace layout (units: 4B words)
    float* ws = (float*)d_ws;
    size_t u = 0;
    float* dinv = ws + u; u += N;
    if (u & 1) u++;
    // region1: temp(int2,E) aliases h(bf16, up to N*64 ushorts = N*32 words)
    size_t M1 = ((size_t)N * 32 > (size_t)E * 2) ? (size_t)N * 32 : (size_t)E * 2;
    unsigned short* h = (unsigned short*)(ws + u); int2* temp = (int2*)h; u += M1;
    if (u & 1) u++;
    float* agg = ws + u; u += (size_t)N * 64;
    float* acc = ws + u; u += 1;
    int* flag = (int*)(ws + u); u += 1;
    int* done = (int*)(ws + u); u += 1;
    int* row  = (int*)(ws + u); u += (size_t)N + 1;
    int* bucketTotal = (int*)(ws + u); u += NB;
    int* bucketBase  = (int*)(ws + u); u += NB + 1;
    int* blockCnt    = (int*)(ws + u); u += (size_t)NBLK * NB;
    int* blockBase   = (int*)(ws + u); u += (size_t)NBLK * NB;
    unsigned* csrw   = (unsigned*)(ws + u); u += (size_t)E;
    size_t need = u * 4;

    float* out = (float*)d_out;

    const int gN = (N + BLK - 1) / BLK;
    const int gE = (E + BLK - 1) / BLK;
    const int gW = (N + 3) / 4;   // wave-per-node grids (4 nodes / 256-thr block)
    const int gR = (N * 2 + BLK - 1) / BLK;

    if (ws_size >= need && N <= 65536 && NB <= MAXNB) {
        // ---- deterministic bucket-sort CSR build ----
        hipLaunchKernelGGL(bucket_hist_kernel, dim3(NBLK), dim3(256), 0, stream,
                           eidx, blockCnt, E, NB);
        hipLaunchKernelGGL(col_scan_kernel, dim3(NB), dim3(256), 0, stream,
                           blockCnt, blockBase, bucketTotal, NBLK, NB);
        hipLaunchKernelGGL(bucket_scan_kernel, dim3(1), dim3(256), 0, stream,
                           bucketTotal, bucketBase, NB, acc, done);
        hipLaunchKernelGGL(bucket_scatter_kernel, dim3(NBLK), dim3(256), 0, stream,
                           eidx, ew, bucketBase, blockBase, temp, E, NB);
        hipLaunchKernelGGL(csr_build_kernel, dim3(NB), dim3(512), 0, stream,
                           temp, bucketBase, csrw, row, dinv, N, NB, E);
        hipLaunchKernelGGL(norm_kernel, dim3(gE), dim3(BLK), 0, stream, csrw, dinv, E);

        // ---- layers ----
        hipLaunchKernelGGL(mm1_kernel, dim3((N + 31) / 32), dim3(256), 0, stream, feat, W1, h, N);
        hipLaunchKernelGGL(gather64_kernel, dim3(gW), dim3(256), 0, stream,
                           row, csrw, h, dinv, b1, agg, N);
        hipLaunchKernelGGL(mm2_kernel, dim3((N + 31) / 32), dim3(256), 0, stream, agg, W2, h, N);
        hipLaunchKernelGGL(gather32_kernel, dim3(gW), dim3(256), 0, stream,
                           row, csrw, h, dinv, b2, agg, N);
        hipLaunchKernelGGL(disc_mm_kernel, dim3((N + 255) / 256), dim3(256), 0, stream,
                           agg, feat, Wd, h, N);
        hipLaunchKernelGGL(gather2_kernel, dim3(gW), dim3(256), 0, stream,
                           row, csrw, h, dinv, bd, agg, N);
    } else {
        // ---- fallback: atomic scatter path ----
        hipLaunchKernelGGL(detect_kernel, dim3(1), dim3(64), 0, stream, eidx, E, flag, acc, done);
        hipLaunchKernelGGL(init_deg_kernel, dim3(gN), dim3(BLK), 0, stream, dinv, N);
        hipLaunchKernelGGL(edge_deg_kernel, dim3(gE), dim3(BLK), 0, stream, eidx, ew, flag, dinv, E);
        hipLaunchKernelGGL(dinv_kernel, dim3(gN), dim3(BLK), 0, stream, dinv, N);

        hipLaunchKernelGGL(mm1_kernel, dim3((N + 31) / 32), dim3(256), 0, stream, feat, W1, h, N);
        hipLaunchKernelGGL((init_agg_kernel<64>), dim3((N * 64 + BLK - 1) / BLK), dim3(BLK), 0, stream,
                           h, dinv, b1, agg, N);
        hipLaunchKernelGGL((edge_agg_kernel<64>), dim3((E / BLK) * 64 + 64), dim3(BLK), 0, stream,
                           eidx, ew, flag, dinv, h, agg, E);
        hipLaunchKernelGGL(mm2_kernel, dim3((N + 31) / 32), dim3(256), 0, stream, agg, W2, h, N);
        hipLaunchKernelGGL((init_agg_kernel<32>), dim3((N * 32 + BLK - 1) / BLK), dim3(BLK), 0, stream,
                           h, dinv, b2, agg, N);
        hipLaunchKernelGGL((edge_agg_kernel<32>), dim3((E / BLK) * 32 + 32), dim3(BLK), 0, stream,
                           eidx, ew, flag, dinv, h, agg, E);
        hipLaunchKernelGGL(disc_mm_kernel, dim3((N + 255) / 256), dim3(256), 0, stream,
                           agg, feat, Wd, h, N);
        hipLaunchKernelGGL((init_agg_kernel<2>), dim3((N * 2 + BLK - 1) / BLK), dim3(BLK), 0, stream,
                           h, dinv, bd, agg, N);
        hipLaunchKernelGGL((edge_agg_kernel<2>), dim3((E * 2 + BLK - 1) / BLK), dim3(BLK), 0, stream,
                           eidx, ew, flag, dinv, h, agg, E);
    }

    hipLaunchKernelGGL(reduce_final_kernel, dim3(gR), dim3(BLK), 0, stream,
                       agg, wfc, acc, done, bfc, out, N * 2, gR);
}

// Round 12
// 272.130 us; speedup vs baseline: 3.2145x; 1.0967x over previous
//
#include <hip/hip_runtime.h>
#include <math.h>

#define BLK 256
#define CHUNK 4096
#define BSH 8
#define BNODES 256
#define MAXNB 256

typedef __attribute__((ext_vector_type(8))) short bf8_t;   // 8 bf16
typedef __attribute__((ext_vector_type(4))) float f4_t;    // MFMA acc

// ---------------------------------------------------------------------------
__device__ __forceinline__ unsigned short f2bf(float f) {
    unsigned u = __float_as_uint(f);
    u += 0x7FFFu + ((u >> 16) & 1u);
    return (unsigned short)(u >> 16);
}
__device__ __forceinline__ float bf2f(unsigned short b) {
    return __uint_as_float(((unsigned)b) << 16);
}

// ---------------------------------------------------------------------------
// Fallback-path probe; zeroes acc/done.
__global__ void detect_kernel(const int* __restrict__ idx, int E,
                              int* __restrict__ flag, float* __restrict__ acc,
                              int* __restrict__ done) {
    int t = threadIdx.x;  // 64 threads
    long long j = (long long)t * (E / 64);
    int hi = idx[2 * j + 1];
    unsigned long long b = __ballot(hi != 0);
    if (t == 0) { *flag = (b == 0ULL) ? 1 : 0; *acc = 0.f; *done = 0; }
}

// ---------------------------------------------------------------------------
// K1: per-block bucket histogram (bucket = dst >> BSH); i64 detection inlined.
__global__ __launch_bounds__(256) void bucket_hist_kernel(const int* __restrict__ idx,
                                                          int* __restrict__ blockCnt,
                                                          int E, int NB) {
    __shared__ int hist[MAXNB];
    __shared__ int i64s;
    int t = threadIdx.x;
    for (int i = t; i < NB; i += 256) hist[i] = 0;
    if (t < 64) {
        long long j = (long long)t * (E / 64);
        int hi = idx[2 * j + 1];
        unsigned long long b = __ballot(hi != 0);
        if (t == 0) i64s = (b == 0ULL) ? 1 : 0;
    }
    __syncthreads();
    bool i64 = i64s != 0;
    int e0 = blockIdx.x * CHUNK;
    int e1 = min(e0 + CHUNK, E);
    for (int e = e0 + t; e < e1; e += 256) {
        int d = i64 ? idx[2 * (E + e)] : idx[E + e];
        atomicAdd(&hist[d >> BSH], 1);
    }
    __syncthreads();
    for (int i = t; i < NB; i += 256) blockCnt[blockIdx.x * NB + i] = hist[i];
}

// K2: column-wise exclusive scan over blocks (one block per bucket);
// block 0 zeroes acc/done.
__global__ __launch_bounds__(256) void col_scan_kernel(const int* __restrict__ blockCnt,
                                                       int* __restrict__ blockBase,
                                                       int* __restrict__ bucketTotal,
                                                       int NBLK, int NB,
                                                       float* __restrict__ acc,
                                                       int* __restrict__ done) {
    __shared__ int s[256];
    __shared__ int carry;
    int bkt = blockIdx.x;
    int t = threadIdx.x;
    if (bkt == 0 && t == 0) { *acc = 0.f; *done = 0; }
    if (t == 0) carry = 0;
    __syncthreads();
    for (int base = 0; base < NBLK; base += 256) {
        int i = base + t;
        int v = (i < NBLK) ? blockCnt[i * NB + bkt] : 0;
        s[t] = v;
        __syncthreads();
        for (int off = 1; off < 256; off <<= 1) {
            int x = (t >= off) ? s[t - off] : 0;
            __syncthreads();
            s[t] += x;
            __syncthreads();
        }
        if (i < NBLK) blockBase[i * NB + bkt] = carry + s[t] - v;
        __syncthreads();
        if (t == 0) carry += s[255];
        __syncthreads();
    }
    if (t == 0) bucketTotal[bkt] = carry;
}

// K3: scatter edges into bucket-partitioned temp as contiguous runs.
// bucketBase computed in-block from bucketTotal (256-scan).
__global__ __launch_bounds__(256) void bucket_scatter_kernel(const int* __restrict__ idx,
                                                             const float* __restrict__ ew,
                                                             const int* __restrict__ bucketTotal,
                                                             const int* __restrict__ blockBase,
                                                             int2* __restrict__ temp,
                                                             int E, int NB) {
    __shared__ int base[MAXNB];
    __shared__ int fill[MAXNB];
    __shared__ int s[256];
    __shared__ int i64s;
    int t = threadIdx.x;
    int v = (t < NB) ? bucketTotal[t] : 0;
    s[t] = v;
    if (t < 64) {
        long long j = (long long)t * (E / 64);
        int hi = idx[2 * j + 1];
        unsigned long long b = __ballot(hi != 0);
        if (t == 0) i64s = (b == 0ULL) ? 1 : 0;
    }
    __syncthreads();
    for (int off = 1; off < 256; off <<= 1) {
        int x = (t >= off) ? s[t - off] : 0;
        __syncthreads();
        s[t] += x;
        __syncthreads();
    }
    if (t < NB) {
        base[t] = (s[t] - v) + blockBase[blockIdx.x * NB + t];
        fill[t] = 0;
    }
    __syncthreads();
    bool i64 = i64s != 0;
    int e0 = blockIdx.x * CHUNK;
    int e1 = min(e0 + CHUNK, E);
    for (int e = e0 + t; e < e1; e += 256) {
        int s_, d;
        if (i64) { s_ = idx[2 * e]; d = idx[2 * (E + e)]; }
        else     { s_ = idx[e];     d = idx[E + e]; }
        float w = ew[e];
        int b = d >> BSH;
        int pos = base[b] + atomicAdd(&fill[b], 1);
        temp[pos] = make_int2(s_ | ((d & (BNODES - 1)) << 16), __float_as_int(w));
    }
}

// K4: per-bucket counting sort into packed CSR + dinv + row (one block/bucket)
// csrw[p] = src(16b) | raw bf16(w)<<16  (dinv folded into dense layers).
__global__ __launch_bounds__(512) void csr_build_kernel(const int2* __restrict__ temp,
                                                        const int* __restrict__ bucketTotal,
                                                        unsigned* __restrict__ csrw,
                                                        int* __restrict__ row,
                                                        float* __restrict__ dinv,
                                                        int N, int NB, int E) {
    __shared__ int cnt[BNODES];
    __shared__ float dw[BNODES];
    __shared__ int offs[BNODES];
    __shared__ int sb[256];
    int bkt = blockIdx.x;
    int t = threadIdx.x;
    int node0 = bkt << BSH;
    int nn = min(BNODES, N - node0);
    if (t < BNODES) { cnt[t] = 0; dw[t] = 0.f; }
    if (t < 256) sb[t] = (t < NB) ? bucketTotal[t] : 0;
    __syncthreads();
    for (int off = 1; off < 256; off <<= 1) {
        int x = 0;
        if (t < 256 && t >= off) x = sb[t - off];
        __syncthreads();
        if (t < 256) sb[t] += x;
        __syncthreads();
    }
    int p0 = (bkt > 0) ? sb[bkt - 1] : 0;
    int p1 = sb[bkt];
    for (int p = p0 + t; p < p1; p += 512) {
        int2 v = temp[p];
        int dl = (v.x >> 16) & (BNODES - 1);
        atomicAdd(&cnt[dl], 1);
        atomicAdd(&dw[dl], __int_as_float(v.y));
    }
    __syncthreads();
    int v = 0;
    if (t < BNODES) { v = cnt[t]; offs[t] = v; }
    __syncthreads();
    for (int off = 1; off < BNODES; off <<= 1) {
        int x = 0;
        if (t < BNODES && t >= off) x = offs[t - off];
        __syncthreads();
        if (t < BNODES) offs[t] += x;
        __syncthreads();
    }
    if (t < BNODES) {
        int excl = offs[t] - v;
        if (t < nn) {
            row[node0 + t] = p0 + excl;
            dinv[node0 + t] = rsqrtf(1.f + dw[t]);
        }
        offs[t] = excl;
    }
    if (bkt == NB - 1 && t == 0) row[N] = E;
    __syncthreads();
    if (t < BNODES) cnt[t] = 0;  // reuse as fill
    __syncthreads();
    for (int p = p0 + t; p < p1; p += 512) {
        int2 v2 = temp[p];
        int dl = (v2.x >> 16) & (BNODES - 1);
        int pos = p0 + offs[dl] + atomicAdd(&cnt[dl], 1);
        unsigned wb = (unsigned)v2.y;
        wb += 0x7FFFu + ((wb >> 16) & 1u);
        csrw[pos] = ((unsigned)v2.x & 0xFFFFu) | (wb & 0xFFFF0000u);
    }
}

// ---------------------------------------------------------------------------
// gathers with h' = dinv*h convention:
// out[n,o] = bias[o] + dinv[n]*( h'[n,o] + sum w_raw*h'[src,o] )
__global__ __launch_bounds__(256) void gather64_kernel(const int* __restrict__ row,
                                                       const unsigned* __restrict__ csrw,
                                                       const unsigned short* __restrict__ h,
                                                       const float* __restrict__ dinv,
                                                       const float* __restrict__ bias,
                                                       float* __restrict__ out, int N) {
    int wid = (blockIdx.x * 256 + threadIdx.x) >> 6;
    int o = threadIdx.x & 63;
    if (wid >= N) return;
    float di = dinv[wid];
    int p0 = row[wid], p1 = row[wid + 1];
    const unsigned short* hb = h + o;
    float es[4] = {0.f, 0.f, 0.f, 0.f};
    for (int p = p0; p < p1; p += 64) {
        int q = p + o;
        unsigned pe = (q < p1) ? csrw[q] : 0u;
        int m = min(64, p1 - p);
        int mp = (m + 15) & ~15;
        for (int j = 0; j < mp; j += 16) {
            unsigned ee[16];
            float hh[16];
#pragma unroll
            for (int u = 0; u < 16; ++u) ee[u] = (unsigned)__shfl((int)pe, j + u, 64);
#pragma unroll
            for (int u = 0; u < 16; ++u) hh[u] = bf2f(hb[(ee[u] & 0xFFFFu) * 64]);
#pragma unroll
            for (int u = 0; u < 16; ++u)
                es[u & 3] = fmaf(__uint_as_float(ee[u] & 0xFFFF0000u), hh[u], es[u & 3]);
        }
    }
    float e01 = es[0] + es[1], e23 = es[2] + es[3];
    out[wid * 64 + o] = bias[o] + di * (bf2f(h[(size_t)wid * 64 + o]) + e01 + e23);
}

__global__ __launch_bounds__(256) void gather32_kernel(const int* __restrict__ row,
                                                       const unsigned* __restrict__ csrw,
                                                       const unsigned short* __restrict__ h,
                                                       const float* __restrict__ dinv,
                                                       const float* __restrict__ bias,
                                                       float* __restrict__ out, int N) {
    int wid = (blockIdx.x * 256 + threadIdx.x) >> 6;
    int lane = threadIdx.x & 63;
    int o = lane & 31;
    int g = lane >> 5;
    if (wid >= N) return;
    float di = dinv[wid];
    int p0 = row[wid], p1 = row[wid + 1];
    const unsigned short* hb = h + o;
    float es[4] = {0.f, 0.f, 0.f, 0.f};
    for (int p = p0; p < p1; p += 64) {
        int q = p + lane;
        unsigned pe = (q < p1) ? csrw[q] : 0u;
        int m = min(64, p1 - p);
        int mp = (m + 15) & ~15;
        for (int j = g; j < mp; j += 16) {
            unsigned ee[8];
            float hh[8];
#pragma unroll
            for (int u = 0; u < 8; ++u) ee[u] = (unsigned)__shfl((int)pe, j + 2 * u, 64);
#pragma unroll
            for (int u = 0; u < 8; ++u) hh[u] = bf2f(hb[(ee[u] & 0xFFFFu) * 32]);
#pragma unroll
            for (int u = 0; u < 8; ++u)
                es[u & 3] = fmaf(__uint_as_float(ee[u] & 0xFFFF0000u), hh[u], es[u & 3]);
        }
    }
    float es_t = (es[0] + es[1]) + (es[2] + es[3]);
    es_t += __shfl_down(es_t, 32, 64);
    if (g == 0) out[wid * 32 + o] = bias[o] + di * (bf2f(h[wid * 32 + o]) + es_t);
}

__global__ __launch_bounds__(256) void gather2_kernel(const int* __restrict__ row,
                                                      const unsigned* __restrict__ csrw,
                                                      const unsigned short* __restrict__ h,
                                                      const float* __restrict__ dinv,
                                                      const float* __restrict__ bias,
                                                      float* __restrict__ out, int N) {
    const unsigned* hp = (const unsigned*)h;
    int wid = (blockIdx.x * 256 + threadIdx.x) >> 6;
    int lane = threadIdx.x & 63;
    if (wid >= N) return;
    float di = dinv[wid];
    int p0 = row[wid], p1 = row[wid + 1];
    float a0 = 0.f, a1 = 0.f, b0 = 0.f, b1 = 0.f;
    int p = p0 + lane;
    for (; p + 64 < p1; p += 128) {
        unsigned pe0 = csrw[p];
        unsigned pe1 = csrw[p + 64];
        unsigned hw0 = hp[pe0 & 0xFFFFu];
        unsigned hw1 = hp[pe1 & 0xFFFFu];
        float w0 = __uint_as_float(pe0 & 0xFFFF0000u);
        float w1 = __uint_as_float(pe1 & 0xFFFF0000u);
        a0 = fmaf(w0, __uint_as_float(hw0 << 16), a0);
        a1 = fmaf(w0, __uint_as_float(hw0 & 0xFFFF0000u), a1);
        b0 = fmaf(w1, __uint_as_float(hw1 << 16), b0);
        b1 = fmaf(w1, __uint_as_float(hw1 & 0xFFFF0000u), b1);
    }
    if (p < p1) {
        unsigned pe0 = csrw[p];
        unsigned hw0 = hp[pe0 & 0xFFFFu];
        float w0 = __uint_as_float(pe0 & 0xFFFF0000u);
        a0 = fmaf(w0, __uint_as_float(hw0 << 16), a0);
        a1 = fmaf(w0, __uint_as_float(hw0 & 0xFFFF0000u), a1);
    }
    a0 += b0; a1 += b1;
#pragma unroll
    for (int off = 32; off > 0; off >>= 1) {
        a0 += __shfl_down(a0, off, 64);
        a1 += __shfl_down(a1, off, 64);
    }
    if (lane == 0) {
        unsigned hw = hp[wid];
        out[wid * 2 + 0] = bias[0] + di * (__uint_as_float(hw << 16) + a0);
        out[wid * 2 + 1] = bias[1] + di * (__uint_as_float(hw & 0xFFFF0000u) + a1);
    }
}

// ---------------------------------------------------------------------------
// mm1 (MFMA): Y[N,64] = dinv[n] * (X[N,128] @ W[128,64]), bf16 out.
// A converted fp32->bf16 in-register; W pre-swizzled into frag order in LDS.
// Layouts (verified): A[m=lane&15][k=quad*8+j]; C/D col=lane&15,row=quad*4+reg.
__global__ __launch_bounds__(256) void mm1_mfma_kernel(const float* __restrict__ X,
                                                       const float* __restrict__ W,
                                                       const float* __restrict__ dinv,
                                                       unsigned short* __restrict__ Y, int N) {
    __shared__ unsigned short Wf[4 * 4 * 64 * 8];  // [kt][ct][lane][j], 16 KB
    int t = threadIdx.x;
    for (int i = t; i < 8192; i += 256) {
        int j = i & 7;
        int lane = (i >> 3) & 63;
        int ct = (i >> 9) & 3;
        int kt = i >> 11;
        int k = kt * 32 + (lane >> 4) * 8 + j;
        int c = ct * 16 + (lane & 15);
        Wf[i] = f2bf(W[k * 64 + c]);
    }
    __syncthreads();
    int wave = t >> 6, lane = t & 63;
    int row0 = blockIdx.x * 64 + wave * 16;
    if (row0 >= N) return;
    int r = row0 + (lane & 15);
    int kq = (lane >> 4) * 8;
    bool rv = r < N;
    f4_t acc0 = {0.f, 0.f, 0.f, 0.f}, acc1 = acc0, acc2 = acc0, acc3 = acc0;
    const bf8_t* wf = (const bf8_t*)Wf;
#pragma unroll
    for (int kt = 0; kt < 4; ++kt) {
        bf8_t a = {0, 0, 0, 0, 0, 0, 0, 0};
        if (rv) {
            const float4* ap = (const float4*)(X + (size_t)r * 128 + kt * 32 + kq);
            float4 lo = ap[0], hi = ap[1];
            a[0] = (short)f2bf(lo.x); a[1] = (short)f2bf(lo.y);
            a[2] = (short)f2bf(lo.z); a[3] = (short)f2bf(lo.w);
            a[4] = (short)f2bf(hi.x); a[5] = (short)f2bf(hi.y);
            a[6] = (short)f2bf(hi.z); a[7] = (short)f2bf(hi.w);
        }
        bf8_t b0 = wf[(kt * 4 + 0) * 64 + lane];
        bf8_t b1 = wf[(kt * 4 + 1) * 64 + lane];
        bf8_t b2 = wf[(kt * 4 + 2) * 64 + lane];
        bf8_t b3 = wf[(kt * 4 + 3) * 64 + lane];
        acc0 = __builtin_amdgcn_mfma_f32_16x16x32_bf16(a, b0, acc0, 0, 0, 0);
        acc1 = __builtin_amdgcn_mfma_f32_16x16x32_bf16(a, b1, acc1, 0, 0, 0);
        acc2 = __builtin_amdgcn_mfma_f32_16x16x32_bf16(a, b2, acc2, 0, 0, 0);
        acc3 = __builtin_amdgcn_mfma_f32_16x16x32_bf16(a, b3, acc3, 0, 0, 0);
    }
    int colb = lane & 15;
    int rbase = row0 + (lane >> 4) * 4;
#pragma unroll
    for (int reg = 0; reg < 4; ++reg) {
        int rr = rbase + reg;
        if (rr < N) {
            float dv = dinv[rr];
            Y[(size_t)rr * 64 + colb]      = f2bf(dv * acc0[reg]);
            Y[(size_t)rr * 64 + 16 + colb] = f2bf(dv * acc1[reg]);
            Y[(size_t)rr * 64 + 32 + colb] = f2bf(dv * acc2[reg]);
            Y[(size_t)rr * 64 + 48 + colb] = f2bf(dv * acc3[reg]);
        }
    }
}

// mm2 (MFMA): Y[N,32] = dinv[n] * (relu(A[N,64]) @ W[64,32]), bf16 out.
__global__ __launch_bounds__(256) void mm2_mfma_kernel(const float* __restrict__ A,
                                                       const float* __restrict__ W,
                                                       const float* __restrict__ dinv,
                                                       unsigned short* __restrict__ Y, int N) {
    __shared__ unsigned short Wf[2 * 2 * 64 * 8];  // [kt][ct][lane][j], 4 KB
    int t = threadIdx.x;
    for (int i = t; i < 2048; i += 256) {
        int j = i & 7;
        int lane = (i >> 3) & 63;
        int ct = (i >> 9) & 1;
        int kt = i >> 10;
        int k = kt * 32 + (lane >> 4) * 8 + j;
        int c = ct * 16 + (lane & 15);
        Wf[i] = f2bf(W[k * 32 + c]);
    }
    __syncthreads();
    int wave = t >> 6, lane = t & 63;
    int row0 = blockIdx.x * 64 + wave * 16;
    if (row0 >= N) return;
    int r = row0 + (lane & 15);
    int kq = (lane >> 4) * 8;
    bool rv = r < N;
    f4_t acc0 = {0.f, 0.f, 0.f, 0.f}, acc1 = acc0;
    const bf8_t* wf = (const bf8_t*)Wf;
#pragma unroll
    for (int kt = 0; kt < 2; ++kt) {
        bf8_t a = {0, 0, 0, 0, 0, 0, 0, 0};
        if (rv) {
            const float4* ap = (const float4*)(A + (size_t)r * 64 + kt * 32 + kq);
            float4 lo = ap[0], hi = ap[1];
            a[0] = (short)f2bf(fmaxf(lo.x, 0.f)); a[1] = (short)f2bf(fmaxf(lo.y, 0.f));
            a[2] = (short)f2bf(fmaxf(lo.z, 0.f)); a[3] = (short)f2bf(fmaxf(lo.w, 0.f));
            a[4] = (short)f2bf(fmaxf(hi.x, 0.f)); a[5] = (short)f2bf(fmaxf(hi.y, 0.f));
            a[6] = (short)f2bf(fmaxf(hi.z, 0.f)); a[7] = (short)f2bf(fmaxf(hi.w, 0.f));
        }
        bf8_t b0 = wf[(kt * 2 + 0) * 64 + lane];
        bf8_t b1 = wf[(kt * 2 + 1) * 64 + lane];
        acc0 = __builtin_amdgcn_mfma_f32_16x16x32_bf16(a, b0, acc0, 0, 0, 0);
        acc1 = __builtin_amdgcn_mfma_f32_16x16x32_bf16(a, b1, acc1, 0, 0, 0);
    }
    int colb = lane & 15;
    int rbase = row0 + (lane >> 4) * 4;
#pragma unroll
    for (int reg = 0; reg < 4; ++reg) {
        int rr = rbase + reg;
        if (rr < N) {
            float dv = dinv[rr];
            Y[(size_t)rr * 32 + colb]      = f2bf(dv * acc0[reg]);
            Y[(size_t)rr * 32 + 16 + colb] = f2bf(dv * acc1[reg]);
        }
    }
}

// disc: dpre'[n] = dinv[n] * ((tile(tanh(Z),4)+F) @ Wd), bf16 out
__global__ __launch_bounds__(256) void disc_mm_kernel(const float* __restrict__ Z,
                                                      const float* __restrict__ F,
                                                      const float* __restrict__ Wd,
                                                      const float* __restrict__ dinv,
                                                      unsigned short* __restrict__ Y, int N) {
    __shared__ float Ws[256];
    if (threadIdx.x < 256) Ws[threadIdx.x] = Wd[threadIdx.x];
    __syncthreads();
    int n = blockIdx.x * 256 + threadIdx.x;
    if (n >= N) return;
    float zt[32];
#pragma unroll
    for (int j = 0; j < 32; ++j) zt[j] = tanhf(Z[n * 32 + j]);
    float a0 = 0.f, a1 = 0.f;
    const float* fr = F + (size_t)n * 128;
#pragma unroll 4
    for (int c = 0; c < 128; ++c) {
        float xv = zt[c & 31] + fr[c];
        a0 = fmaf(xv, Ws[c * 2 + 0], a0);
        a1 = fmaf(xv, Ws[c * 2 + 1], a1);
    }
    float dv = dinv[n];
    ushort2 o;
    o.x = f2bf(dv * a0); o.y = f2bf(dv * a1);
    ((ushort2*)Y)[n] = o;
}

// ---------------------------------------------------------------------------
// Fallback (atomic scatter) kernels — h' = dinv*h convention
__global__ void init_deg_kernel(float* __restrict__ deg, int N) {
    int n = blockIdx.x * BLK + threadIdx.x;
    if (n < N) deg[n] = 1.0f;
}

__global__ void edge_deg_kernel(const int* __restrict__ idx, const float* __restrict__ ew,
                                const int* __restrict__ flag, float* __restrict__ deg, int E) {
    int e = blockIdx.x * BLK + threadIdx.x;
    if (e >= E) return;
    int d = (*flag) ? idx[2 * (E + e)] : idx[E + e];
    atomicAdd(&deg[d], ew[e]);
}

__global__ void dinv_kernel(float* __restrict__ deg, int N) {
    int n = blockIdx.x * BLK + threadIdx.x;
    if (n < N) deg[n] = rsqrtf(deg[n]);
}

template <int WD>
__global__ void init_agg_kernel(const unsigned short* __restrict__ h, const float* __restrict__ dinv,
                                const float* __restrict__ bias, float* __restrict__ agg, int N) {
    int i = blockIdx.x * BLK + threadIdx.x;
    if (i >= N * WD) return;
    int n = i / WD, o = i % WD;
    float di = dinv[n];
    agg[i] = bias[o] + di * bf2f(h[i]);  // h is h' = dinv*h_true
}

template <int WD>
__global__ void edge_agg_kernel(const int* __restrict__ idx, const float* __restrict__ ew,
                                const int* __restrict__ flag, const float* __restrict__ dinv,
                                const unsigned short* __restrict__ h, float* __restrict__ agg, int E) {
    int gid = blockIdx.x * BLK + threadIdx.x;
    if (gid >= E * WD) return;
    int e = gid / WD;
    int o = gid % WD;
    int s, d;
    if (*flag) { s = idx[2 * e]; d = idx[2 * (E + e)]; }
    else       { s = idx[e];     d = idx[E + e]; }
    float nrm = ew[e] * dinv[d];  // dinv[s] already folded into h'
    atomicAdd(&agg[d * WD + o], nrm * bf2f(h[s * WD + o]));
}

// ---------------------------------------------------------------------------
// logit partial sums + last-block sigmoid (acc/done pre-zeroed upstream)
__global__ void reduce_final_kernel(const float* __restrict__ dmat, const float* __restrict__ wfc,
                                    float* __restrict__ acc, int* __restrict__ done,
                                    const float* __restrict__ bfc, float* __restrict__ out,
                                    int M, int nblk) {
    int i = blockIdx.x * BLK + threadIdx.x;
    float v = 0.f;
    if (i < M) v = fmaxf(dmat[i], 0.f) * wfc[i];
#pragma unroll
    for (int off = 32; off > 0; off >>= 1) v += __shfl_down(v, off, 64);
    if ((threadIdx.x & 63) == 0) atomicAdd(acc, v);
    __syncthreads();
    if (threadIdx.x == 0) {
        __threadfence();
        int old = atomicAdd(done, 1);
        if (old == nblk - 1) {
            float x = atomicAdd(acc, 0.f) + *bfc;
            out[0] = 1.f / (1.f + expf(-x));
        }
    }
}

// ---------------------------------------------------------------------------
extern "C" void kernel_launch(void* const* d_in, const int* in_sizes, int n_in,
                              void* d_out, int out_size, void* d_ws, size_t ws_size,
                              hipStream_t stream) {
    const float* feat = (const float*)d_in[0];
    const int*   eidx = (const int*)d_in[1];
    const float* ew   = (const float*)d_in[2];
    const float* W1   = (const float*)d_in[3];
    const float* b1   = (const float*)d_in[4];
    const float* W2   = (const float*)d_in[5];
    const float* b2   = (const float*)d_in[6];
    const float* Wd   = (const float*)d_in[7];
    const float* bd   = (const float*)d_in[8];
    const float* wfc  = (const float*)d_in[9];
    const float* bfc  = (const float*)d_in[10];

    const int N = in_sizes[0] / 128;  // 50000
    const int E = in_sizes[2];        // 1600000

    const int NB   = (N + BNODES - 1) >> BSH;       // buckets (196 @ BSH=8)
    const int NBLK = (E + CHUNK - 1) / CHUNK;       // edge blocks (391)

    // workspace layout (units: 4B words)
    float* ws = (float*)d_ws;
    size_t u = 0;
    float* dinv = ws + u; u += N;
    if (u & 1) u++;
    size_t M1 = ((size_t)N * 32 > (size_t)E * 2) ? (size_t)N * 32 : (size_t)E * 2;
    unsigned short* h = (unsigned short*)(ws + u); int2* temp = (int2*)h; u += M1;
    if (u & 1) u++;
    float* agg = ws + u; u += (size_t)N * 64;
    float* acc = ws + u; u += 1;
    int* flag = (int*)(ws + u); u += 1;
    int* done = (int*)(ws + u); u += 1;
    int* row  = (int*)(ws + u); u += (size_t)N + 1;
    int* bucketTotal = (int*)(ws + u); u += NB;
    int* blockCnt    = (int*)(ws + u); u += (size_t)NBLK * NB;
    int* blockBase   = (int*)(ws + u); u += (size_t)NBLK * NB;
    unsigned* csrw   = (unsigned*)(ws + u); u += (size_t)E;
    size_t need = u * 4;

    float* out = (float*)d_out;

    const int gN = (N + BLK - 1) / BLK;
    const int gE = (E + BLK - 1) / BLK;
    const int gW = (N + 3) / 4;
    const int gM = (N + 63) / 64;
    const int gR = (N * 2 + BLK - 1) / BLK;

    if (ws_size >= need && N <= 65536 && NB <= MAXNB) {
        // ---- deterministic bucket-sort CSR build ----
        hipLaunchKernelGGL(bucket_hist_kernel, dim3(NBLK), dim3(256), 0, stream,
                           eidx, blockCnt, E, NB);
        hipLaunchKernelGGL(col_scan_kernel, dim3(NB), dim3(256), 0, stream,
                           blockCnt, blockBase, bucketTotal, NBLK, NB, acc, done);
        hipLaunchKernelGGL(bucket_scatter_kernel, dim3(NBLK), dim3(256), 0, stream,
                           eidx, ew, bucketTotal, blockBase, temp, E, NB);
        hipLaunchKernelGGL(csr_build_kernel, dim3(NB), dim3(512), 0, stream,
                           temp, bucketTotal, csrw, row, dinv, N, NB, E);

        // ---- layers ----
        hipLaunchKernelGGL(mm1_mfma_kernel, dim3(gM), dim3(256), 0, stream,
                           feat, W1, dinv, h, N);
        hipLaunchKernelGGL(gather64_kernel, dim3(gW), dim3(256), 0, stream,
                           row, csrw, h, dinv, b1, agg, N);
        hipLaunchKernelGGL(mm2_mfma_kernel, dim3(gM), dim3(256), 0, stream,
                           agg, W2, dinv, h, N);
        hipLaunchKernelGGL(gather32_kernel, dim3(gW), dim3(256), 0, stream,
                           row, csrw, h, dinv, b2, agg, N);
        hipLaunchKernelGGL(disc_mm_kernel, dim3((N + 255) / 256), dim3(256), 0, stream,
                           agg, feat, Wd, dinv, h, N);
        hipLaunchKernelGGL(gather2_kernel, dim3(gW), dim3(256), 0, stream,
                           row, csrw, h, dinv, bd, agg, N);
    } else {
        // ---- fallback: atomic scatter path ----
        hipLaunchKernelGGL(detect_kernel, dim3(1), dim3(64), 0, stream, eidx, E, flag, acc, done);
        hipLaunchKernelGGL(init_deg_kernel, dim3(gN), dim3(BLK), 0, stream, dinv, N);
        hipLaunchKernelGGL(edge_deg_kernel, dim3(gE), dim3(BLK), 0, stream, eidx, ew, flag, dinv, E);
        hipLaunchKernelGGL(dinv_kernel, dim3(gN), dim3(BLK), 0, stream, dinv, N);

        hipLaunchKernelGGL(mm1_mfma_kernel, dim3(gM), dim3(256), 0, stream, feat, W1, dinv, h, N);
        hipLaunchKernelGGL((init_agg_kernel<64>), dim3((N * 64 + BLK - 1) / BLK), dim3(BLK), 0, stream,
                           h, dinv, b1, agg, N);
        hipLaunchKernelGGL((edge_agg_kernel<64>), dim3((E / BLK) * 64 + 64), dim3(BLK), 0, stream,
                           eidx, ew, flag, dinv, h, agg, E);
        hipLaunchKernelGGL(mm2_mfma_kernel, dim3(gM), dim3(256), 0, stream, agg, W2, dinv, h, N);
        hipLaunchKernelGGL((init_agg_kernel<32>), dim3((N * 32 + BLK - 1) / BLK), dim3(BLK), 0, stream,
                           h, dinv, b2, agg, N);
        hipLaunchKernelGGL((edge_agg_kernel<32>), dim3((E / BLK) * 32 + 32), dim3(BLK), 0, stream,
                           eidx, ew, flag, dinv, h, agg, E);
        hipLaunchKernelGGL(disc_mm_kernel, dim3((N + 255) / 256), dim3(256), 0, stream,
                           agg, feat, Wd, dinv, h, N);
        hipLaunchKernelGGL((init_agg_kernel<2>), dim3((N * 2 + BLK - 1) / BLK), dim3(BLK), 0, stream,
                           h, dinv, bd, agg, N);
        hipLaunchKernelGGL((edge_agg_kernel<2>), dim3((E * 2 + BLK - 1) / BLK), dim3(BLK), 0, stream,
                           eidx, ew, flag, dinv, h, agg, E);
    }

    hipLaunchKernelGGL(reduce_final_kernel, dim3(gR), dim3(BLK), 0, stream,
                       agg, wfc, acc, done, bfc, out, N * 2, gR);
}